// Round 4
// baseline (1511.672 us; speedup 1.0000x reference)
//
#include <hip/hip_runtime.h>
#include <math.h>

#define NB 2
#define NN 2048
#define NC 512
#define NH 8
#define DK 64
#define DFF 2048
#define NTOP 512
#define NPOOL 1024
#define QT 32

// =============== generic 128xN tiled GEMM, 8x(4*TNQ) per lane, fp32 ===============
// A: [4096, lda], B: [K, ldb] (row-major), C: [4096, ldc]. Grid: (N/(64*TNQ), 32).
// CIRC: A-row n-index circularly shifted by `shift` within each batch of 2048 rows.
template<int TNQ, bool CIRC>
__global__ __launch_bounds__(256) void gemm_t(const float* __restrict__ A, int lda,
    const float* __restrict__ B, int ldb, const float* __restrict__ bias,
    float* __restrict__ C, int ldc, int K, int act, int accum, int shift)
{
    __shared__ float As[16][132];
    __shared__ float Bs[16][TNQ * 64 + 4];
    int tid = threadIdx.x;
    int n0 = blockIdx.x * (TNQ * 64), m0 = blockIdx.y * 128;
    int tx = tid & 15, ty = tid >> 4;
    float acc[8][TNQ * 4] = {};
    for (int k0 = 0; k0 < K; k0 += 16) {
        // stage A: 128x16, transposed into As[k][m]; 2 float4 per lane
        #pragma unroll
        for (int i = 0; i < 2; i++) {
            int t = tid + i * 256;
            int m = t >> 2, kq = t & 3;
            int grow = m0 + m;
            int arow = CIRC ? ((grow & ~(NN - 1)) | ((grow + shift) & (NN - 1))) : grow;
            float4 a4 = *(const float4*)&A[(size_t)arow * lda + k0 + kq * 4];
            As[kq * 4 + 0][m] = a4.x; As[kq * 4 + 1][m] = a4.y;
            As[kq * 4 + 2][m] = a4.z; As[kq * 4 + 3][m] = a4.w;
        }
        // stage B: 16 x (64*TNQ); float4 rows
        #pragma unroll
        for (int i = 0; i < TNQ; i++) {
            int t = tid + i * 256;
            int k = t / (TNQ * 16), nq = t % (TNQ * 16);
            *(float4*)&Bs[k][nq * 4] = *(const float4*)&B[(size_t)(k0 + k) * ldb + n0 + nq * 4];
        }
        __syncthreads();
        #pragma unroll
        for (int kk = 0; kk < 16; kk++) {
            float av[8], bv[TNQ * 4];
            *(float4*)&av[0] = *(const float4*)&As[kk][ty * 4];
            *(float4*)&av[4] = *(const float4*)&As[kk][64 + ty * 4];
            #pragma unroll
            for (int jq = 0; jq < TNQ; jq++)
                *(float4*)&bv[jq * 4] = *(const float4*)&Bs[kk][jq * 64 + tx * 4];
            #pragma unroll
            for (int i = 0; i < 8; i++)
                #pragma unroll
                for (int j = 0; j < TNQ * 4; j++)
                    acc[i][j] += av[i] * bv[j];
        }
        __syncthreads();
    }
    #pragma unroll
    for (int jq = 0; jq < TNQ; jq++) {
        int ncol = n0 + jq * 64 + tx * 4;
        float4 b4 = bias ? *(const float4*)&bias[ncol] : make_float4(0.f, 0.f, 0.f, 0.f);
        #pragma unroll
        for (int i = 0; i < 8; i++) {
            int m = m0 + (i >> 2) * 64 + ty * 4 + (i & 3);
            float* cp = &C[(size_t)m * ldc + ncol];
            float4 c4;
            c4.x = acc[i][jq * 4 + 0] + b4.x;
            c4.y = acc[i][jq * 4 + 1] + b4.y;
            c4.z = acc[i][jq * 4 + 2] + b4.z;
            c4.w = acc[i][jq * 4 + 3] + b4.w;
            if (act == 1) {
                c4.x = 0.5f * c4.x * (1.0f + erff(c4.x * 0.70710678118654752f));
                c4.y = 0.5f * c4.y * (1.0f + erff(c4.y * 0.70710678118654752f));
                c4.z = 0.5f * c4.z * (1.0f + erff(c4.z * 0.70710678118654752f));
                c4.w = 0.5f * c4.w * (1.0f + erff(c4.w * 0.70710678118654752f));
            }
            if (accum) {
                float4 o = *(const float4*)cp;
                c4.x += o.x; c4.y += o.y; c4.z += o.z; c4.w += o.w;
            }
            *(float4*)cp = c4;
        }
    }
}

// =============== QKV GEMM (128x128 tile) with head-major scatter epilogue ===============
__global__ __launch_bounds__(256) void gemm_qkv_k(const float* __restrict__ A,
    const float* __restrict__ B, const float* __restrict__ bias,
    float* __restrict__ Qh, float* __restrict__ Kh, float* __restrict__ Vh)
{
    __shared__ float As[16][132];
    __shared__ float Bs[16][132];
    int tid = threadIdx.x;
    int n0 = blockIdx.x * 128, m0 = blockIdx.y * 128;
    int tx = tid & 15, ty = tid >> 4;
    float acc[8][8] = {};
    for (int k0 = 0; k0 < NC; k0 += 16) {
        #pragma unroll
        for (int i = 0; i < 2; i++) {
            int t = tid + i * 256;
            int m = t >> 2, kq = t & 3;
            float4 a4 = *(const float4*)&A[(size_t)(m0 + m) * NC + k0 + kq * 4];
            As[kq * 4 + 0][m] = a4.x; As[kq * 4 + 1][m] = a4.y;
            As[kq * 4 + 2][m] = a4.z; As[kq * 4 + 3][m] = a4.w;
        }
        #pragma unroll
        for (int i = 0; i < 2; i++) {
            int t = tid + i * 256;
            int k = t >> 5, nq = t & 31;
            *(float4*)&Bs[k][nq * 4] = *(const float4*)&B[(size_t)(k0 + k) * 1536 + n0 + nq * 4];
        }
        __syncthreads();
        #pragma unroll
        for (int kk = 0; kk < 16; kk++) {
            float av[8], bv[8];
            *(float4*)&av[0] = *(const float4*)&As[kk][ty * 4];
            *(float4*)&av[4] = *(const float4*)&As[kk][64 + ty * 4];
            *(float4*)&bv[0] = *(const float4*)&Bs[kk][tx * 4];
            *(float4*)&bv[4] = *(const float4*)&Bs[kk][64 + tx * 4];
            #pragma unroll
            for (int i = 0; i < 8; i++)
                #pragma unroll
                for (int j = 0; j < 8; j++) acc[i][j] += av[i] * bv[j];
        }
        __syncthreads();
    }
    int which = n0 >> 9;
    float* outb = which == 0 ? Qh : (which == 1 ? Kh : Vh);
    #pragma unroll
    for (int jq = 0; jq < 2; jq++) {
        int colq = n0 + jq * 64;
        int h = (colq >> 6) & 7;
        float4 b4 = *(const float4*)&bias[colq + tx * 4];
        #pragma unroll
        for (int i = 0; i < 8; i++) {
            int m = m0 + (i >> 2) * 64 + ty * 4 + (i & 3);
            int b = m >> 11, row = m & (NN - 1);
            float4 c4;
            c4.x = acc[i][jq * 4 + 0] + b4.x;
            c4.y = acc[i][jq * 4 + 1] + b4.y;
            c4.z = acc[i][jq * 4 + 2] + b4.z;
            c4.w = acc[i][jq * 4 + 3] + b4.w;
            *(float4*)&outb[((size_t)((b << 3) + h) * NN + row) * DK + tx * 4] = c4;
        }
    }
}

// =============== mean of V over sequence, per (b,h,d) ===============
__global__ void meanv_k(const float* __restrict__ Vh, float* __restrict__ meanv)
{
    int bh = blockIdx.x;
    int tid = threadIdx.x;
    int d = tid & 63, seg = tid >> 6;
    const float* vb = Vh + (size_t)bh * NN * DK;
    float s = 0.f;
    for (int m = seg * 512; m < seg * 512 + 512; m++) s += vb[(size_t)m * DK + d];
    __shared__ float red[256];
    red[tid] = s;
    __syncthreads();
    if (seg == 0)
        meanv[bh * DK + d] = (red[d] + red[64 + d] + red[128 + d] + red[192 + d]) * (1.0f / (float)NN);
}

// =============== pass A: M[bh,n] = max - mean of score row; 64 q-rows/block ===============
__global__ __launch_bounds__(256) void rowstat_k(const float* __restrict__ Qh,
    const float* __restrict__ Kh, float* __restrict__ Marr)
{
    int bh = blockIdx.y;
    int n0 = blockIdx.x * 64;
    __shared__ float Qs[64][68];
    __shared__ float Ks[64][68];
    int tid = threadIdx.x, tx = tid & 15, ty = tid >> 4;
    const float* qb = Qh + ((size_t)bh * NN + n0) * DK;
    const float* kb = Kh + (size_t)bh * NN * DK;
    #pragma unroll
    for (int i = 0; i < 4; i++) {
        int t = tid + i * 256;
        int r = t >> 4, dq = t & 15;
        *(float4*)&Qs[r][dq * 4] = *(const float4*)&qb[(size_t)r * DK + dq * 4];
    }
    float rmax[4], rsum[4];
    #pragma unroll
    for (int i = 0; i < 4; i++) { rmax[i] = -INFINITY; rsum[i] = 0.f; }
    for (int mc = 0; mc < NN; mc += 64) {
        __syncthreads();
        #pragma unroll
        for (int i = 0; i < 4; i++) {
            int t = tid + i * 256;
            int r = t >> 4, dq = t & 15;
            *(float4*)&Ks[r][dq * 4] = *(const float4*)&kb[(size_t)(mc + r) * DK + dq * 4];
        }
        __syncthreads();
        float S[4][4] = {};
        #pragma unroll
        for (int dq = 0; dq < 16; dq++) {
            float4 qv[4], kv[4];
            #pragma unroll
            for (int i = 0; i < 4; i++)
                qv[i] = *(const float4*)&Qs[ty * 4 + i][dq * 4];
            #pragma unroll
            for (int j = 0; j < 4; j++)
                kv[j] = *(const float4*)&Ks[tx * 4 + j][dq * 4];
            #pragma unroll
            for (int i = 0; i < 4; i++)
                #pragma unroll
                for (int j = 0; j < 4; j++)
                    S[i][j] += qv[i].x * kv[j].x + qv[i].y * kv[j].y
                             + qv[i].z * kv[j].z + qv[i].w * kv[j].w;
        }
        #pragma unroll
        for (int i = 0; i < 4; i++)
            #pragma unroll
            for (int j = 0; j < 4; j++) {
                float s = S[i][j] * 0.125f;
                rmax[i] = fmaxf(rmax[i], s);
                rsum[i] += s;
            }
    }
    #pragma unroll
    for (int off = 1; off < 16; off <<= 1)
        #pragma unroll
        for (int i = 0; i < 4; i++) {
            rmax[i] = fmaxf(rmax[i], __shfl_xor(rmax[i], off));
            rsum[i] += __shfl_xor(rsum[i], off);
        }
    if (tx == 0)
        #pragma unroll
        for (int i = 0; i < 4; i++)
            Marr[(size_t)bh * NN + n0 + ty * 4 + i] = rmax[i] - rsum[i] * (1.0f / (float)NN);
}

// =============== top-512 per (b,h): sorted compact index list ===============
__global__ __launch_bounds__(256) void topk_k(const float* __restrict__ Marr,
                                              int* __restrict__ idx)
{
    int bh = blockIdx.x;
    const float* Mr = Marr + (size_t)bh * NN;
    int* idxr = idx + (size_t)bh * NTOP;
    __shared__ float s[NN];
    __shared__ int sg[256], se[256];
    int tid = threadIdx.x;
    for (int i = tid; i < NN; i += 256) s[i] = Mr[i];
    __syncthreads();
    for (int k = 2; k <= NN; k <<= 1)
        for (int j = k >> 1; j > 0; j >>= 1) {
            for (int t = tid; t < NN / 2; t += 256) {
                int i = ((t & ~(j - 1)) << 1) | (t & (j - 1));
                int ixj = i | j;
                float a = s[i], bb = s[ixj];
                bool up = ((i & k) == 0);
                if ((a > bb) == up) { s[i] = bb; s[ixj] = a; }
            }
            __syncthreads();
        }
    float thr = s[NN - NTOP];
    int lg = 0, le = 0;
    #pragma unroll
    for (int k = 0; k < 8; k++) {
        float v = Mr[tid * 8 + k];
        lg += (v > thr) ? 1 : 0;
        le += (v == thr) ? 1 : 0;
    }
    sg[tid] = lg; se[tid] = le;
    __syncthreads();
    for (int off = 1; off < 256; off <<= 1) {
        int ag = (tid >= off) ? sg[tid - off] : 0;
        int ae = (tid >= off) ? se[tid - off] : 0;
        __syncthreads();
        sg[tid] += ag; se[tid] += ae;
        __syncthreads();
    }
    int cnt_gt = sg[255];
    int needed = NTOP - cnt_gt;
    int gpre = sg[tid] - lg, epre = se[tid] - le;
    #pragma unroll
    for (int k = 0; k < 8; k++) {
        int p = tid * 8 + k;
        float v = Mr[p];
        bool isgt = v > thr, iseq = v == thr;
        bool selv = isgt || (iseq && epre < needed);
        if (selv) idxr[gpre + (epre < needed ? epre : needed)] = p;
        gpre += isgt ? 1 : 0;
        epre += iseq ? 1 : 0;
    }
}

// =============== fill all ctx rows with uniform-attention result ===============
__global__ void fill_k(const float* __restrict__ meanv, float* __restrict__ ctx)
{
    int i = blockIdx.x * 256 + threadIdx.x;
    if (i >= NB * NN * NC) return;
    int c = i & (NC - 1);
    int m = i >> 9;
    int b = m >> 11;
    int h = c >> 6, d = c & 63;
    ctx[i] = meanv[(((b << 3) + h) << 6) + d];
}

// =============== flash-style attention over 32 selected rows/block ===============
__global__ __launch_bounds__(256) void attn_sel_k(const float* __restrict__ Qh,
    const float* __restrict__ Kh, const float* __restrict__ Vh,
    const int* __restrict__ idx, float* __restrict__ ctx)
{
    int bh = blockIdx.y;
    int t0 = blockIdx.x * QT;
    int h = bh & 7, b = bh >> 3;
    int tid = threadIdx.x, tx = tid & 15, ty = tid >> 4;
    __shared__ float Qs[QT][68];
    __shared__ float Ks[64][68];
    __shared__ float Vs[64][68];
    __shared__ float Ps[QT][68];
    __shared__ int rows[QT];
    if (tid < QT) rows[tid] = idx[bh * NTOP + t0 + tid];
    __syncthreads();
    #pragma unroll
    for (int i = 0; i < 2; i++) {
        int t = tid + i * 256;
        int r = t >> 4, dq = t & 15;
        *(float4*)&Qs[r][dq * 4] =
            *(const float4*)&Qh[((size_t)bh * NN + rows[r]) * DK + dq * 4];
    }
    float O[2][4] = {};
    float rmax[2] = {-INFINITY, -INFINITY};
    float rsum[2] = {0.f, 0.f};
    const float* kb = Kh + (size_t)bh * NN * DK;
    const float* vb = Vh + (size_t)bh * NN * DK;
    for (int mc = 0; mc < NN; mc += 64) {
        __syncthreads();
        #pragma unroll
        for (int i = 0; i < 4; i++) {
            int t = tid + i * 256;
            int r = t >> 4, dq = t & 15;
            *(float4*)&Ks[r][dq * 4] = *(const float4*)&kb[(size_t)(mc + r) * DK + dq * 4];
            *(float4*)&Vs[r][dq * 4] = *(const float4*)&vb[(size_t)(mc + r) * DK + dq * 4];
        }
        __syncthreads();
        float S[2][4] = {};
        #pragma unroll
        for (int dq = 0; dq < 16; dq++) {
            float4 qv[2], kv[4];
            qv[0] = *(const float4*)&Qs[ty * 2][dq * 4];
            qv[1] = *(const float4*)&Qs[ty * 2 + 1][dq * 4];
            #pragma unroll
            for (int j = 0; j < 4; j++)
                kv[j] = *(const float4*)&Ks[tx * 4 + j][dq * 4];
            #pragma unroll
            for (int i = 0; i < 2; i++)
                #pragma unroll
                for (int j = 0; j < 4; j++)
                    S[i][j] += qv[i].x * kv[j].x + qv[i].y * kv[j].y
                             + qv[i].z * kv[j].z + qv[i].w * kv[j].w;
        }
        float mloc[2], ssum[2];
        #pragma unroll
        for (int i = 0; i < 2; i++) {
            #pragma unroll
            for (int j = 0; j < 4; j++) S[i][j] *= 0.125f;
            mloc[i] = fmaxf(fmaxf(S[i][0], S[i][1]), fmaxf(S[i][2], S[i][3]));
        }
        #pragma unroll
        for (int off = 1; off < 16; off <<= 1)
            #pragma unroll
            for (int i = 0; i < 2; i++)
                mloc[i] = fmaxf(mloc[i], __shfl_xor(mloc[i], off));
        #pragma unroll
        for (int i = 0; i < 2; i++) {
            float mnew = fmaxf(rmax[i], mloc[i]);
            float alpha = expf(rmax[i] - mnew);
            rmax[i] = mnew;
            ssum[i] = 0.f;
            #pragma unroll
            for (int j = 0; j < 4; j++) {
                float p = expf(S[i][j] - mnew);
                S[i][j] = p;
                ssum[i] += p;
            }
            #pragma unroll
            for (int j = 0; j < 4; j++) O[i][j] *= alpha;
            rsum[i] *= alpha;
        }
        #pragma unroll
        for (int off = 1; off < 16; off <<= 1)
            #pragma unroll
            for (int i = 0; i < 2; i++) ssum[i] += __shfl_xor(ssum[i], off);
        #pragma unroll
        for (int i = 0; i < 2; i++) {
            rsum[i] += ssum[i];
            *(float4*)&Ps[ty * 2 + i][tx * 4] =
                make_float4(S[i][0], S[i][1], S[i][2], S[i][3]);
        }
        // P rows are written and read only by this wave -> no barrier needed
        #pragma unroll
        for (int m = 0; m < 64; m += 4) {
            float4 p4[2];
            p4[0] = *(const float4*)&Ps[ty * 2][m];
            p4[1] = *(const float4*)&Ps[ty * 2 + 1][m];
            float pa[2][4] = {{p4[0].x, p4[0].y, p4[0].z, p4[0].w},
                              {p4[1].x, p4[1].y, p4[1].z, p4[1].w}};
            #pragma unroll
            for (int mm = 0; mm < 4; mm++) {
                float4 vv = *(const float4*)&Vs[m + mm][tx * 4];
                #pragma unroll
                for (int i = 0; i < 2; i++) {
                    O[i][0] += pa[i][mm] * vv.x;
                    O[i][1] += pa[i][mm] * vv.y;
                    O[i][2] += pa[i][mm] * vv.z;
                    O[i][3] += pa[i][mm] * vv.w;
                }
            }
        }
    }
    #pragma unroll
    for (int i = 0; i < 2; i++) {
        int n = rows[ty * 2 + i];
        float inv = 1.0f / rsum[i];
        float4 o = make_float4(O[i][0] * inv, O[i][1] * inv, O[i][2] * inv, O[i][3] * inv);
        *(float4*)&ctx[((size_t)(b * NN + n)) * NC + h * DK + tx * 4] = o;
    }
}

// =============== layernorm over residual sum ===============
__global__ __launch_bounds__(256) void ln_k(const float* __restrict__ A,
    const float* __restrict__ Bv, const float* __restrict__ g,
    const float* __restrict__ bb, float* __restrict__ out)
{
    int row = blockIdx.x;
    int tid = threadIdx.x;
    __shared__ float v[NC];
    __shared__ float red[256];
    size_t base = (size_t)row * NC;
    for (int i = tid; i < NC; i += 256) v[i] = A[base + i] + Bv[base + i];
    __syncthreads();
    float ls = 0.f;
    for (int i = tid; i < NC; i += 256) ls += v[i];
    red[tid] = ls; __syncthreads();
    for (int off = 128; off > 0; off >>= 1) {
        if (tid < off) red[tid] += red[tid + off];
        __syncthreads();
    }
    float mu = red[0] / (float)NC;
    __syncthreads();
    float lv = 0.f;
    for (int i = tid; i < NC; i += 256) { float d = v[i] - mu; lv += d * d; }
    red[tid] = lv; __syncthreads();
    for (int off = 128; off > 0; off >>= 1) {
        if (tid < off) red[tid] += red[tid + off];
        __syncthreads();
    }
    float rstd = rsqrtf(red[0] / (float)NC + 1e-5f);
    for (int i = tid; i < NC; i += 256)
        out[base + i] = (v[i] - mu) * rstd * g[i] + bb[i];
}

// =============== conv weight transpose: [co][ci][t] -> [t][ci][co] ===============
__global__ void convw_k(const float* __restrict__ cw, float* __restrict__ wt)
{
    int idx = blockIdx.x * 256 + threadIdx.x;
    if (idx >= NC * NC * 3) return;
    int t = idx % 3; int ci = (idx / 3) % NC; int co = idx / (3 * NC);
    wt[(size_t)t * NC * NC + ci * NC + co] = cw[idx];
}

// =============== maxpool(3,2,1) + ELU + LN -> out ===============
__global__ __launch_bounds__(256) void pool_ln_k(const float* __restrict__ y,
    const float* __restrict__ g, const float* __restrict__ bb,
    float* __restrict__ outp)
{
    int row = blockIdx.x;
    int j = row & (NPOOL - 1), b = row / NPOOL;
    int tid = threadIdx.x;
    __shared__ float v[NC];
    __shared__ float red[256];
    const float* ybase = y + (size_t)b * NN * NC;
    for (int i = tid; i < NC; i += 256) {
        float m = -INFINITY;
        int p0 = 2 * j - 1;
        #pragma unroll
        for (int t = 0; t < 3; t++) {
            int p = p0 + t;
            if (p >= 0 && p < NN) m = fmaxf(m, ybase[(size_t)p * NC + i]);
        }
        v[i] = m > 0.f ? m : expm1f(m);
    }
    __syncthreads();
    float ls = 0.f;
    for (int i = tid; i < NC; i += 256) ls += v[i];
    red[tid] = ls; __syncthreads();
    for (int off = 128; off > 0; off >>= 1) {
        if (tid < off) red[tid] += red[tid + off];
        __syncthreads();
    }
    float mu = red[0] / (float)NC;
    __syncthreads();
    float lv = 0.f;
    for (int i = tid; i < NC; i += 256) { float d = v[i] - mu; lv += d * d; }
    red[tid] = lv; __syncthreads();
    for (int off = 128; off > 0; off >>= 1) {
        if (tid < off) red[tid] += red[tid + off];
        __syncthreads();
    }
    float rstd = rsqrtf(red[0] / (float)NC + 1e-5f);
    for (int i = tid; i < NC; i += 256)
        outp[(size_t)row * NC + i] = (v[i] - mu) * rstd * g[i] + bb[i];
}

extern "C" void kernel_launch(void* const* d_in, const int* in_sizes, int n_in,
                              void* d_out, int out_size, void* d_ws, size_t ws_size,
                              hipStream_t stream)
{
    (void)in_sizes; (void)n_in; (void)out_size; (void)ws_size;
    const float* x      = (const float*)d_in[0];
    const float* qkv_w  = (const float*)d_in[1];
    const float* qkv_b  = (const float*)d_in[2];
    const float* out_w  = (const float*)d_in[3];
    const float* out_b  = (const float*)d_in[4];
    const float* ffn_w1 = (const float*)d_in[5];
    const float* ffn_b1 = (const float*)d_in[6];
    const float* ffn_w2 = (const float*)d_in[7];
    const float* ffn_b2 = (const float*)d_in[8];
    const float* n1_g   = (const float*)d_in[9];
    const float* n1_b   = (const float*)d_in[10];
    const float* n2_g   = (const float*)d_in[11];
    const float* n2_b   = (const float*)d_in[12];
    const float* conv_w = (const float*)d_in[13];
    const float* conv_b = (const float*)d_in[14];
    const float* cn_g   = (const float*)d_in[15];
    const float* cn_b   = (const float*)d_in[16];

    const size_t R = (size_t)NB * NN * NC;     // 2097152
    float* ws = (float*)d_ws;
    float* x1    = ws;                // R
    float* ctx   = ws + R;            // R  (later x2)
    float* Qh    = ws + 2 * R;        // R  (later attn_out, then ffn_out)
    float* Kh    = ws + 3 * R;        // R  (hbuf lo, later convy)
    float* Vh    = ws + 4 * R;        // R  (hbuf hi)
    float* Marr  = ws + 5 * R;                       // 32K
    float* meanv = Marr + (size_t)NB * NH * NN;      // 1K
    float* wt    = meanv + (size_t)NB * NH * DK;     // 786K
    int*   idx   = (int*)(wt + (size_t)3 * NC * NC); // 8K ints
    float* attn_out = Qh;
    float* hbuf     = Kh;             // 2R contiguous (Kh+Vh)
    float* ffn_out  = Qh;
    float* x2       = ctx;
    float* convy    = Kh;

    convw_k<<<(NC * NC * 3 + 255) / 256, 256, 0, stream>>>(conv_w, wt);

    // qkv = x @ qkv_w + qkv_b -> head-major Q/K/V
    gemm_qkv_k<<<dim3(12, 32), 256, 0, stream>>>(x, qkv_w, qkv_b, Qh, Kh, Vh);

    meanv_k<<<NB * NH, 256, 0, stream>>>(Vh, meanv);
    rowstat_k<<<dim3(NN / 64, NB * NH), 256, 0, stream>>>(Qh, Kh, Marr);
    topk_k<<<NB * NH, 256, 0, stream>>>(Marr, idx);
    fill_k<<<((int)R + 255) / 256, 256, 0, stream>>>(meanv, ctx);
    attn_sel_k<<<dim3(NTOP / QT, NB * NH), 256, 0, stream>>>(Qh, Kh, Vh, idx, ctx);

    // attn_out = ctx @ out_w + out_b   (N=512 -> 64-wide tile, 256 blocks)
    gemm_t<1, false><<<dim3(8, 32), 256, 0, stream>>>(
        ctx, NC, out_w, NC, out_b, attn_out, NC, NC, 0, 0, 0);

    ln_k<<<NB * NN, 256, 0, stream>>>(x, attn_out, n1_g, n1_b, x1);

    // FFN in 2 column-chunks of 1024
    for (int c = 0; c < 2; c++) {
        gemm_t<2, false><<<dim3(8, 32), 256, 0, stream>>>(
            x1, NC, ffn_w1 + c * 1024, DFF, ffn_b1 + c * 1024, hbuf, 1024,
            NC, 1, 0, 0);
        gemm_t<1, false><<<dim3(8, 32), 256, 0, stream>>>(
            hbuf, 1024, ffn_w2 + (size_t)c * 1024 * NC, NC,
            (c == 0 ? ffn_b2 : (const float*)nullptr), ffn_out, NC,
            1024, 0, (c == 0 ? 0 : 1), 0);
    }

    ln_k<<<NB * NN, 256, 0, stream>>>(x1, ffn_out, n2_g, n2_b, x2);

    // circular conv1d(k=3) as 3 accumulating GEMMs with shifted A-rows
    for (int t = 0; t < 3; t++) {
        gemm_t<1, true><<<dim3(8, 32), 256, 0, stream>>>(
            x2, NC, wt + (size_t)t * NC * NC, NC,
            (t == 0 ? conv_b : (const float*)nullptr), convy, NC,
            NC, 0, (t == 0 ? 0 : 1), t - 1);
    }

    pool_ln_k<<<NB * NPOOL, 256, 0, stream>>>(convy, cn_g, cn_b, (float*)d_out);
}

// Round 5
// 1300.560 us; speedup vs baseline: 1.1623x; 1.1623x over previous
//
#include <hip/hip_runtime.h>
#include <math.h>

#define NB 2
#define NN 2048
#define NC 512
#define NH 8
#define DK 64
#define DFF 2048
#define NTOP 512
#define NPOOL 1024
#define QT 32

// =============== generic 128xN tiled GEMM, 8x(4*TNQ) per lane, fp32 ===============
// A: [4096, lda], B: [K, ldb] (row-major), C: [4096, ldc]. Grid: (N/(64*TNQ), 32).
// CIRC: A-row n-index circularly shifted by `shift` within each batch of 2048 rows.
template<int TNQ, bool CIRC>
__global__ __launch_bounds__(256) void gemm_t(const float* __restrict__ A, int lda,
    const float* __restrict__ B, int ldb, const float* __restrict__ bias,
    float* __restrict__ C, int ldc, int K, int act, int accum, int shift)
{
    __shared__ float As[16][132];
    __shared__ float Bs[16][TNQ * 64 + 4];
    int tid = threadIdx.x;
    int n0 = blockIdx.x * (TNQ * 64), m0 = blockIdx.y * 128;
    int tx = tid & 15, ty = tid >> 4;
    float acc[8][TNQ * 4] = {};
    for (int k0 = 0; k0 < K; k0 += 16) {
        #pragma unroll
        for (int i = 0; i < 2; i++) {
            int t = tid + i * 256;
            int m = t >> 2, kq = t & 3;
            int grow = m0 + m;
            int arow = CIRC ? ((grow & ~(NN - 1)) | ((grow + shift) & (NN - 1))) : grow;
            float4 a4 = *(const float4*)&A[(size_t)arow * lda + k0 + kq * 4];
            As[kq * 4 + 0][m] = a4.x; As[kq * 4 + 1][m] = a4.y;
            As[kq * 4 + 2][m] = a4.z; As[kq * 4 + 3][m] = a4.w;
        }
        #pragma unroll
        for (int i = 0; i < TNQ; i++) {
            int t = tid + i * 256;
            int k = t / (TNQ * 16), nq = t % (TNQ * 16);
            *(float4*)&Bs[k][nq * 4] = *(const float4*)&B[(size_t)(k0 + k) * ldb + n0 + nq * 4];
        }
        __syncthreads();
        #pragma unroll
        for (int kk = 0; kk < 16; kk++) {
            float av[8], bv[TNQ * 4];
            *(float4*)&av[0] = *(const float4*)&As[kk][ty * 4];
            *(float4*)&av[4] = *(const float4*)&As[kk][64 + ty * 4];
            #pragma unroll
            for (int jq = 0; jq < TNQ; jq++)
                *(float4*)&bv[jq * 4] = *(const float4*)&Bs[kk][jq * 64 + tx * 4];
            #pragma unroll
            for (int i = 0; i < 8; i++)
                #pragma unroll
                for (int j = 0; j < TNQ * 4; j++)
                    acc[i][j] += av[i] * bv[j];
        }
        __syncthreads();
    }
    #pragma unroll
    for (int jq = 0; jq < TNQ; jq++) {
        int ncol = n0 + jq * 64 + tx * 4;
        float4 b4 = bias ? *(const float4*)&bias[ncol] : make_float4(0.f, 0.f, 0.f, 0.f);
        #pragma unroll
        for (int i = 0; i < 8; i++) {
            int m = m0 + (i >> 2) * 64 + ty * 4 + (i & 3);
            float* cp = &C[(size_t)m * ldc + ncol];
            float4 c4;
            c4.x = acc[i][jq * 4 + 0] + b4.x;
            c4.y = acc[i][jq * 4 + 1] + b4.y;
            c4.z = acc[i][jq * 4 + 2] + b4.z;
            c4.w = acc[i][jq * 4 + 3] + b4.w;
            if (act == 1) {
                c4.x = 0.5f * c4.x * (1.0f + erff(c4.x * 0.70710678118654752f));
                c4.y = 0.5f * c4.y * (1.0f + erff(c4.y * 0.70710678118654752f));
                c4.z = 0.5f * c4.z * (1.0f + erff(c4.z * 0.70710678118654752f));
                c4.w = 0.5f * c4.w * (1.0f + erff(c4.w * 0.70710678118654752f));
            }
            if (accum) {
                float4 o = *(const float4*)cp;
                c4.x += o.x; c4.y += o.y; c4.z += o.z; c4.w += o.w;
            }
            *(float4*)cp = c4;
        }
    }
}

// =============== QKV GEMM (128x128 tile) with head-major scatter epilogue ===============
__global__ __launch_bounds__(256) void gemm_qkv_k(const float* __restrict__ A,
    const float* __restrict__ B, const float* __restrict__ bias,
    float* __restrict__ Qh, float* __restrict__ Kh, float* __restrict__ Vh)
{
    __shared__ float As[16][132];
    __shared__ float Bs[16][132];
    int tid = threadIdx.x;
    int n0 = blockIdx.x * 128, m0 = blockIdx.y * 128;
    int tx = tid & 15, ty = tid >> 4;
    float acc[8][8] = {};
    for (int k0 = 0; k0 < NC; k0 += 16) {
        #pragma unroll
        for (int i = 0; i < 2; i++) {
            int t = tid + i * 256;
            int m = t >> 2, kq = t & 3;
            float4 a4 = *(const float4*)&A[(size_t)(m0 + m) * NC + k0 + kq * 4];
            As[kq * 4 + 0][m] = a4.x; As[kq * 4 + 1][m] = a4.y;
            As[kq * 4 + 2][m] = a4.z; As[kq * 4 + 3][m] = a4.w;
        }
        #pragma unroll
        for (int i = 0; i < 2; i++) {
            int t = tid + i * 256;
            int k = t >> 5, nq = t & 31;
            *(float4*)&Bs[k][nq * 4] = *(const float4*)&B[(size_t)(k0 + k) * 1536 + n0 + nq * 4];
        }
        __syncthreads();
        #pragma unroll
        for (int kk = 0; kk < 16; kk++) {
            float av[8], bv[8];
            *(float4*)&av[0] = *(const float4*)&As[kk][ty * 4];
            *(float4*)&av[4] = *(const float4*)&As[kk][64 + ty * 4];
            *(float4*)&bv[0] = *(const float4*)&Bs[kk][tx * 4];
            *(float4*)&bv[4] = *(const float4*)&Bs[kk][64 + tx * 4];
            #pragma unroll
            for (int i = 0; i < 8; i++)
                #pragma unroll
                for (int j = 0; j < 8; j++) acc[i][j] += av[i] * bv[j];
        }
        __syncthreads();
    }
    int which = n0 >> 9;
    float* outb = which == 0 ? Qh : (which == 1 ? Kh : Vh);
    #pragma unroll
    for (int jq = 0; jq < 2; jq++) {
        int colq = n0 + jq * 64;
        int h = (colq >> 6) & 7;
        float4 b4 = *(const float4*)&bias[colq + tx * 4];
        #pragma unroll
        for (int i = 0; i < 8; i++) {
            int m = m0 + (i >> 2) * 64 + ty * 4 + (i & 3);
            int b = m >> 11, row = m & (NN - 1);
            float4 c4;
            c4.x = acc[i][jq * 4 + 0] + b4.x;
            c4.y = acc[i][jq * 4 + 1] + b4.y;
            c4.z = acc[i][jq * 4 + 2] + b4.z;
            c4.w = acc[i][jq * 4 + 3] + b4.w;
            *(float4*)&outb[((size_t)((b << 3) + h) * NN + row) * DK + tx * 4] = c4;
        }
    }
}

// =============== mean of V over sequence, per (b,h,d) ===============
__global__ void meanv_k(const float* __restrict__ Vh, float* __restrict__ meanv)
{
    int bh = blockIdx.x;
    int tid = threadIdx.x;
    int d = tid & 63, seg = tid >> 6;
    const float* vb = Vh + (size_t)bh * NN * DK;
    float s = 0.f;
    for (int m = seg * 512; m < seg * 512 + 512; m++) s += vb[(size_t)m * DK + d];
    __shared__ float red[256];
    red[tid] = s;
    __syncthreads();
    if (seg == 0)
        meanv[bh * DK + d] = (red[d] + red[64 + d] + red[128 + d] + red[192 + d]) * (1.0f / (float)NN);
}

// =============== pass A: M[bh,n] = max - mean; outer-product form ===============
// 128 q-rows per block, transposed LDS staging -> conflict-free fragment reads.
__global__ __launch_bounds__(256) void rowstat_k(const float* __restrict__ Qh,
    const float* __restrict__ Kh, float* __restrict__ Marr)
{
    int bh = blockIdx.y;
    int m0 = blockIdx.x * 128;
    __shared__ float Qs[64][132];   // [d][m]
    __shared__ float Ks[64][132];   // [d][n]
    int tid = threadIdx.x, tx = tid & 15, ty = tid >> 4;
    const float* qb = Qh + ((size_t)bh * NN + m0) * DK;
    const float* kb = Kh + (size_t)bh * NN * DK;
    #pragma unroll
    for (int i = 0; i < 8; i++) {
        int t = tid + i * 256;          // 0..2047
        int m = t >> 4, dq = t & 15;
        float4 q4 = *(const float4*)&qb[(size_t)m * DK + dq * 4];
        Qs[dq * 4 + 0][m] = q4.x; Qs[dq * 4 + 1][m] = q4.y;
        Qs[dq * 4 + 2][m] = q4.z; Qs[dq * 4 + 3][m] = q4.w;
    }
    float rmax[8], rsum[8];
    #pragma unroll
    for (int i = 0; i < 8; i++) { rmax[i] = -INFINITY; rsum[i] = 0.f; }
    for (int nc = 0; nc < NN; nc += 128) {
        __syncthreads();
        #pragma unroll
        for (int i = 0; i < 8; i++) {
            int t = tid + i * 256;
            int n = t >> 4, dq = t & 15;
            float4 k4 = *(const float4*)&kb[(size_t)(nc + n) * DK + dq * 4];
            Ks[dq * 4 + 0][n] = k4.x; Ks[dq * 4 + 1][n] = k4.y;
            Ks[dq * 4 + 2][n] = k4.z; Ks[dq * 4 + 3][n] = k4.w;
        }
        __syncthreads();
        float S[8][8] = {};
        #pragma unroll 8
        for (int d = 0; d < 64; d++) {
            float av[8], bv[8];
            *(float4*)&av[0] = *(const float4*)&Qs[d][ty * 4];
            *(float4*)&av[4] = *(const float4*)&Qs[d][64 + ty * 4];
            *(float4*)&bv[0] = *(const float4*)&Ks[d][tx * 4];
            *(float4*)&bv[4] = *(const float4*)&Ks[d][64 + tx * 4];
            #pragma unroll
            for (int i = 0; i < 8; i++)
                #pragma unroll
                for (int j = 0; j < 8; j++) S[i][j] += av[i] * bv[j];
        }
        #pragma unroll
        for (int i = 0; i < 8; i++)
            #pragma unroll
            for (int j = 0; j < 8; j++) {
                rmax[i] = fmaxf(rmax[i], S[i][j]);
                rsum[i] += S[i][j];
            }
    }
    #pragma unroll
    for (int off = 1; off < 16; off <<= 1)
        #pragma unroll
        for (int i = 0; i < 8; i++) {
            rmax[i] = fmaxf(rmax[i], __shfl_xor(rmax[i], off));
            rsum[i] += __shfl_xor(rsum[i], off);
        }
    if (tx == 0)
        #pragma unroll
        for (int i = 0; i < 8; i++) {
            int m = m0 + (i >> 2) * 64 + ty * 4 + (i & 3);
            Marr[(size_t)bh * NN + m] =
                (rmax[i] - rsum[i] * (1.0f / (float)NN)) * 0.125f;
        }
}

// =============== top-512 per (b,h): sorted compact index list ===============
__global__ __launch_bounds__(256) void topk_k(const float* __restrict__ Marr,
                                              int* __restrict__ idx)
{
    int bh = blockIdx.x;
    const float* Mr = Marr + (size_t)bh * NN;
    int* idxr = idx + (size_t)bh * NTOP;
    __shared__ float s[NN];
    __shared__ int sg[256], se[256];
    int tid = threadIdx.x;
    for (int i = tid; i < NN; i += 256) s[i] = Mr[i];
    __syncthreads();
    for (int k = 2; k <= NN; k <<= 1)
        for (int j = k >> 1; j > 0; j >>= 1) {
            for (int t = tid; t < NN / 2; t += 256) {
                int i = ((t & ~(j - 1)) << 1) | (t & (j - 1));
                int ixj = i | j;
                float a = s[i], bb = s[ixj];
                bool up = ((i & k) == 0);
                if ((a > bb) == up) { s[i] = bb; s[ixj] = a; }
            }
            __syncthreads();
        }
    float thr = s[NN - NTOP];
    int lg = 0, le = 0;
    #pragma unroll
    for (int k = 0; k < 8; k++) {
        float v = Mr[tid * 8 + k];
        lg += (v > thr) ? 1 : 0;
        le += (v == thr) ? 1 : 0;
    }
    sg[tid] = lg; se[tid] = le;
    __syncthreads();
    for (int off = 1; off < 256; off <<= 1) {
        int ag = (tid >= off) ? sg[tid - off] : 0;
        int ae = (tid >= off) ? se[tid - off] : 0;
        __syncthreads();
        sg[tid] += ag; se[tid] += ae;
        __syncthreads();
    }
    int cnt_gt = sg[255];
    int needed = NTOP - cnt_gt;
    int gpre = sg[tid] - lg, epre = se[tid] - le;
    #pragma unroll
    for (int k = 0; k < 8; k++) {
        int p = tid * 8 + k;
        float v = Mr[p];
        bool isgt = v > thr, iseq = v == thr;
        bool selv = isgt || (iseq && epre < needed);
        if (selv) idxr[gpre + (epre < needed ? epre : needed)] = p;
        gpre += isgt ? 1 : 0;
        epre += iseq ? 1 : 0;
    }
}

// =============== fill all ctx rows with uniform-attention result ===============
__global__ void fill_k(const float* __restrict__ meanv, float* __restrict__ ctx)
{
    int i = blockIdx.x * 256 + threadIdx.x;
    if (i >= NB * NN * NC) return;
    int c = i & (NC - 1);
    int m = i >> 9;
    int b = m >> 11;
    int h = c >> 6, d = c & 63;
    ctx[i] = meanv[(((b << 3) + h) << 6) + d];
}

// =============== flash-style attention over 32 selected rows/block ===============
__global__ __launch_bounds__(256) void attn_sel_k(const float* __restrict__ Qh,
    const float* __restrict__ Kh, const float* __restrict__ Vh,
    const int* __restrict__ idx, float* __restrict__ ctx)
{
    int bh = blockIdx.y;
    int t0 = blockIdx.x * QT;
    int h = bh & 7, b = bh >> 3;
    int tid = threadIdx.x, tx = tid & 15, ty = tid >> 4;
    __shared__ float Qs[QT][68];
    __shared__ float Ks[64][68];
    __shared__ float Vs[64][68];
    __shared__ float Ps[QT][68];
    __shared__ int rows[QT];
    if (tid < QT) rows[tid] = idx[bh * NTOP + t0 + tid];
    __syncthreads();
    #pragma unroll
    for (int i = 0; i < 2; i++) {
        int t = tid + i * 256;
        int r = t >> 4, dq = t & 15;
        *(float4*)&Qs[r][dq * 4] =
            *(const float4*)&Qh[((size_t)bh * NN + rows[r]) * DK + dq * 4];
    }
    float O[2][4] = {};
    float rmax[2] = {-INFINITY, -INFINITY};
    float rsum[2] = {0.f, 0.f};
    const float* kb = Kh + (size_t)bh * NN * DK;
    const float* vb = Vh + (size_t)bh * NN * DK;
    for (int mc = 0; mc < NN; mc += 64) {
        __syncthreads();
        #pragma unroll
        for (int i = 0; i < 4; i++) {
            int t = tid + i * 256;
            int r = t >> 4, dq = t & 15;
            *(float4*)&Ks[r][dq * 4] = *(const float4*)&kb[(size_t)(mc + r) * DK + dq * 4];
            *(float4*)&Vs[r][dq * 4] = *(const float4*)&vb[(size_t)(mc + r) * DK + dq * 4];
        }
        __syncthreads();
        float S[2][4] = {};
        #pragma unroll
        for (int dq = 0; dq < 16; dq++) {
            float4 qv[2], kv[4];
            qv[0] = *(const float4*)&Qs[ty * 2][dq * 4];
            qv[1] = *(const float4*)&Qs[ty * 2 + 1][dq * 4];
            #pragma unroll
            for (int j = 0; j < 4; j++)
                kv[j] = *(const float4*)&Ks[tx * 4 + j][dq * 4];
            #pragma unroll
            for (int i = 0; i < 2; i++)
                #pragma unroll
                for (int j = 0; j < 4; j++)
                    S[i][j] += qv[i].x * kv[j].x + qv[i].y * kv[j].y
                             + qv[i].z * kv[j].z + qv[i].w * kv[j].w;
        }
        float mloc[2], ssum[2];
        #pragma unroll
        for (int i = 0; i < 2; i++) {
            #pragma unroll
            for (int j = 0; j < 4; j++) S[i][j] *= 0.125f;
            mloc[i] = fmaxf(fmaxf(S[i][0], S[i][1]), fmaxf(S[i][2], S[i][3]));
        }
        #pragma unroll
        for (int off = 1; off < 16; off <<= 1)
            #pragma unroll
            for (int i = 0; i < 2; i++)
                mloc[i] = fmaxf(mloc[i], __shfl_xor(mloc[i], off));
        #pragma unroll
        for (int i = 0; i < 2; i++) {
            float mnew = fmaxf(rmax[i], mloc[i]);
            float alpha = expf(rmax[i] - mnew);
            rmax[i] = mnew;
            ssum[i] = 0.f;
            #pragma unroll
            for (int j = 0; j < 4; j++) {
                float p = expf(S[i][j] - mnew);
                S[i][j] = p;
                ssum[i] += p;
            }
            #pragma unroll
            for (int j = 0; j < 4; j++) O[i][j] *= alpha;
            rsum[i] *= alpha;
        }
        #pragma unroll
        for (int off = 1; off < 16; off <<= 1)
            #pragma unroll
            for (int i = 0; i < 2; i++) ssum[i] += __shfl_xor(ssum[i], off);
        #pragma unroll
        for (int i = 0; i < 2; i++) {
            rsum[i] += ssum[i];
            *(float4*)&Ps[ty * 2 + i][tx * 4] =
                make_float4(S[i][0], S[i][1], S[i][2], S[i][3]);
        }
        #pragma unroll
        for (int m = 0; m < 64; m += 4) {
            float4 p4[2];
            p4[0] = *(const float4*)&Ps[ty * 2][m];
            p4[1] = *(const float4*)&Ps[ty * 2 + 1][m];
            float pa[2][4] = {{p4[0].x, p4[0].y, p4[0].z, p4[0].w},
                              {p4[1].x, p4[1].y, p4[1].z, p4[1].w}};
            #pragma unroll
            for (int mm = 0; mm < 4; mm++) {
                float4 vv = *(const float4*)&Vs[m + mm][tx * 4];
                #pragma unroll
                for (int i = 0; i < 2; i++) {
                    O[i][0] += pa[i][mm] * vv.x;
                    O[i][1] += pa[i][mm] * vv.y;
                    O[i][2] += pa[i][mm] * vv.z;
                    O[i][3] += pa[i][mm] * vv.w;
                }
            }
        }
    }
    #pragma unroll
    for (int i = 0; i < 2; i++) {
        int n = rows[ty * 2 + i];
        float inv = 1.0f / rsum[i];
        float4 o = make_float4(O[i][0] * inv, O[i][1] * inv, O[i][2] * inv, O[i][3] * inv);
        *(float4*)&ctx[((size_t)(b * NN + n)) * NC + h * DK + tx * 4] = o;
    }
}

// =============== layernorm over residual sum ===============
__global__ __launch_bounds__(256) void ln_k(const float* __restrict__ A,
    const float* __restrict__ Bv, const float* __restrict__ g,
    const float* __restrict__ bb, float* __restrict__ out)
{
    int row = blockIdx.x;
    int tid = threadIdx.x;
    __shared__ float v[NC];
    __shared__ float red[256];
    size_t base = (size_t)row * NC;
    for (int i = tid; i < NC; i += 256) v[i] = A[base + i] + Bv[base + i];
    __syncthreads();
    float ls = 0.f;
    for (int i = tid; i < NC; i += 256) ls += v[i];
    red[tid] = ls; __syncthreads();
    for (int off = 128; off > 0; off >>= 1) {
        if (tid < off) red[tid] += red[tid + off];
        __syncthreads();
    }
    float mu = red[0] / (float)NC;
    __syncthreads();
    float lv = 0.f;
    for (int i = tid; i < NC; i += 256) { float d = v[i] - mu; lv += d * d; }
    red[tid] = lv; __syncthreads();
    for (int off = 128; off > 0; off >>= 1) {
        if (tid < off) red[tid] += red[tid + off];
        __syncthreads();
    }
    float rstd = rsqrtf(red[0] / (float)NC + 1e-5f);
    for (int i = tid; i < NC; i += 256)
        out[base + i] = (v[i] - mu) * rstd * g[i] + bb[i];
}

// =============== conv weight transpose: [co][ci][t] -> [t][ci][co] ===============
__global__ void convw_k(const float* __restrict__ cw, float* __restrict__ wt)
{
    int idx = blockIdx.x * 256 + threadIdx.x;
    if (idx >= NC * NC * 3) return;
    int t = idx % 3; int ci = (idx / 3) % NC; int co = idx / (3 * NC);
    wt[(size_t)t * NC * NC + ci * NC + co] = cw[idx];
}

// =============== maxpool(3,2,1) + ELU + LN -> out ===============
__global__ __launch_bounds__(256) void pool_ln_k(const float* __restrict__ y,
    const float* __restrict__ g, const float* __restrict__ bb,
    float* __restrict__ outp)
{
    int row = blockIdx.x;
    int j = row & (NPOOL - 1), b = row / NPOOL;
    int tid = threadIdx.x;
    __shared__ float v[NC];
    __shared__ float red[256];
    const float* ybase = y + (size_t)b * NN * NC;
    for (int i = tid; i < NC; i += 256) {
        float m = -INFINITY;
        int p0 = 2 * j - 1;
        #pragma unroll
        for (int t = 0; t < 3; t++) {
            int p = p0 + t;
            if (p >= 0 && p < NN) m = fmaxf(m, ybase[(size_t)p * NC + i]);
        }
        v[i] = m > 0.f ? m : expm1f(m);
    }
    __syncthreads();
    float ls = 0.f;
    for (int i = tid; i < NC; i += 256) ls += v[i];
    red[tid] = ls; __syncthreads();
    for (int off = 128; off > 0; off >>= 1) {
        if (tid < off) red[tid] += red[tid + off];
        __syncthreads();
    }
    float mu = red[0] / (float)NC;
    __syncthreads();
    float lv = 0.f;
    for (int i = tid; i < NC; i += 256) { float d = v[i] - mu; lv += d * d; }
    red[tid] = lv; __syncthreads();
    for (int off = 128; off > 0; off >>= 1) {
        if (tid < off) red[tid] += red[tid + off];
        __syncthreads();
    }
    float rstd = rsqrtf(red[0] / (float)NC + 1e-5f);
    for (int i = tid; i < NC; i += 256)
        outp[(size_t)row * NC + i] = (v[i] - mu) * rstd * g[i] + bb[i];
}

extern "C" void kernel_launch(void* const* d_in, const int* in_sizes, int n_in,
                              void* d_out, int out_size, void* d_ws, size_t ws_size,
                              hipStream_t stream)
{
    (void)in_sizes; (void)n_in; (void)out_size; (void)ws_size;
    const float* x      = (const float*)d_in[0];
    const float* qkv_w  = (const float*)d_in[1];
    const float* qkv_b  = (const float*)d_in[2];
    const float* out_w  = (const float*)d_in[3];
    const float* out_b  = (const float*)d_in[4];
    const float* ffn_w1 = (const float*)d_in[5];
    const float* ffn_b1 = (const float*)d_in[6];
    const float* ffn_w2 = (const float*)d_in[7];
    const float* ffn_b2 = (const float*)d_in[8];
    const float* n1_g   = (const float*)d_in[9];
    const float* n1_b   = (const float*)d_in[10];
    const float* n2_g   = (const float*)d_in[11];
    const float* n2_b   = (const float*)d_in[12];
    const float* conv_w = (const float*)d_in[13];
    const float* conv_b = (const float*)d_in[14];
    const float* cn_g   = (const float*)d_in[15];
    const float* cn_b   = (const float*)d_in[16];

    const size_t R = (size_t)NB * NN * NC;     // 2097152
    float* ws = (float*)d_ws;
    float* x1    = ws;                // R
    float* ctx   = ws + R;            // R  (later x2)
    float* Qh    = ws + 2 * R;        // R  (later attn_out, then ffn_out)
    float* Kh    = ws + 3 * R;        // R  (hbuf lo, later convy)
    float* Vh    = ws + 4 * R;        // R  (hbuf hi)
    float* Marr  = ws + 5 * R;                       // 32K
    float* meanv = Marr + (size_t)NB * NH * NN;      // 1K
    float* wt    = meanv + (size_t)NB * NH * DK;     // 786K
    int*   idx   = (int*)(wt + (size_t)3 * NC * NC); // 8K ints
    float* attn_out = Qh;
    float* hbuf     = Kh;             // 2R contiguous (Kh+Vh)
    float* ffn_out  = Qh;
    float* x2       = ctx;
    float* convy    = Kh;

    convw_k<<<(NC * NC * 3 + 255) / 256, 256, 0, stream>>>(conv_w, wt);

    // qkv = x @ qkv_w + qkv_b -> head-major Q/K/V
    gemm_qkv_k<<<dim3(12, 32), 256, 0, stream>>>(x, qkv_w, qkv_b, Qh, Kh, Vh);

    meanv_k<<<NB * NH, 256, 0, stream>>>(Vh, meanv);
    rowstat_k<<<dim3(NN / 128, NB * NH), 256, 0, stream>>>(Qh, Kh, Marr);
    topk_k<<<NB * NH, 256, 0, stream>>>(Marr, idx);
    fill_k<<<((int)R + 255) / 256, 256, 0, stream>>>(meanv, ctx);
    attn_sel_k<<<dim3(NTOP / QT, NB * NH), 256, 0, stream>>>(Qh, Kh, Vh, idx, ctx);

    // attn_out = ctx @ out_w + out_b
    gemm_t<1, false><<<dim3(8, 32), 256, 0, stream>>>(
        ctx, NC, out_w, NC, out_b, attn_out, NC, NC, 0, 0, 0);

    ln_k<<<NB * NN, 256, 0, stream>>>(x, attn_out, n1_g, n1_b, x1);

    // FFN in 2 column-chunks of 1024
    for (int c = 0; c < 2; c++) {
        gemm_t<2, false><<<dim3(8, 32), 256, 0, stream>>>(
            x1, NC, ffn_w1 + c * 1024, DFF, ffn_b1 + c * 1024, hbuf, 1024,
            NC, 1, 0, 0);
        gemm_t<1, false><<<dim3(8, 32), 256, 0, stream>>>(
            hbuf, 1024, ffn_w2 + (size_t)c * 1024 * NC, NC,
            (c == 0 ? ffn_b2 : (const float*)nullptr), ffn_out, NC,
            1024, 0, (c == 0 ? 0 : 1), 0);
    }

    ln_k<<<NB * NN, 256, 0, stream>>>(x1, ffn_out, n2_g, n2_b, x2);

    // circular conv1d(k=3) as 3 accumulating GEMMs with shifted A-rows
    for (int t = 0; t < 3; t++) {
        gemm_t<1, true><<<dim3(8, 32), 256, 0, stream>>>(
            x2, NC, wt + (size_t)t * NC * NC, NC,
            (t == 0 ? conv_b : (const float*)nullptr), convy, NC,
            NC, 0, (t == 0 ? 0 : 1), t - 1);
    }

    pool_ln_k<<<NB * NPOOL, 256, 0, stream>>>(convy, cn_g, cn_b, (float*)d_out);
}

// Round 6
// 878.323 us; speedup vs baseline: 1.7211x; 1.4807x over previous
//
#include <hip/hip_runtime.h>
#include <math.h>

#define NB 2
#define NN 2048
#define NC 512
#define NH 8
#define DK 64
#define DFF 2048
#define NTOP 512
#define NPOOL 1024
#define QT 32

typedef unsigned short u16;
typedef __attribute__((ext_vector_type(8))) short frag8;
typedef __attribute__((ext_vector_type(4))) float f32x4;

static __device__ __forceinline__ u16 f2b(float f) {
    union { float f; unsigned int u; } v; v.f = f;
    unsigned int r = (v.u + 0x7fffu + ((v.u >> 16) & 1u)) >> 16;
    return (u16)r;
}

// =============== bf16 MFMA GEMM: C = A @ Bt^T (+bias)(+gelu)(+accum) ===============
// A: [4096][lda] bf16 row-major. Bt: [N][K] bf16 (pre-transposed weights).
// C fp32 [4096][ldc] or Cb bf16. Tile 128x128, BK=64, 4 waves in 2x2.
template<bool CIRC>
__global__ __launch_bounds__(256) void mfma_gemm(const u16* __restrict__ A, int lda,
    const u16* __restrict__ Bt, const float* __restrict__ bias,
    float* __restrict__ C, u16* __restrict__ Cb, int ldc,
    int K, int act, int accum, int shift)
{
    __shared__ u16 As[128][72];
    __shared__ u16 Bs[128][72];
    int tid = threadIdx.x;
    int n0 = blockIdx.x * 128, m0 = blockIdx.y * 128;
    int wave = tid >> 6, lane = tid & 63;
    int ln = lane & 15, quad = lane >> 4;
    int wm = (wave >> 1) * 64, wn = (wave & 1) * 64;
    f32x4 acc[4][4] = {};
    for (int k0 = 0; k0 < K; k0 += 64) {
        #pragma unroll
        for (int i = 0; i < 4; i++) {
            int t = tid + i * 256;
            int m = t >> 3, kq = t & 7;
            int grow = m0 + m;
            int arow = CIRC ? ((grow & ~(NN - 1)) | ((grow + shift) & (NN - 1))) : grow;
            *(uint4*)&As[m][kq * 8] = *(const uint4*)&A[(size_t)arow * lda + k0 + kq * 8];
            *(uint4*)&Bs[m][kq * 8] = *(const uint4*)&Bt[(size_t)(n0 + m) * K + k0 + kq * 8];
        }
        __syncthreads();
        #pragma unroll
        for (int kk = 0; kk < 2; kk++) {
            frag8 af[4], bf[4];
            #pragma unroll
            for (int i = 0; i < 4; i++) {
                af[i] = *(const frag8*)&As[wm + i * 16 + ln][kk * 32 + quad * 8];
                bf[i] = *(const frag8*)&Bs[wn + i * 16 + ln][kk * 32 + quad * 8];
            }
            #pragma unroll
            for (int i = 0; i < 4; i++)
                #pragma unroll
                for (int j = 0; j < 4; j++)
                    acc[i][j] = __builtin_amdgcn_mfma_f32_16x16x32_bf16(
                        af[i], bf[j], acc[i][j], 0, 0, 0);
        }
        __syncthreads();
    }
    #pragma unroll
    for (int i = 0; i < 4; i++) {
        #pragma unroll
        for (int j = 0; j < 4; j++) {
            int col = n0 + wn + j * 16 + ln;
            float bv = bias ? bias[col] : 0.f;
            #pragma unroll
            for (int r = 0; r < 4; r++) {
                int row = m0 + wm + i * 16 + quad * 4 + r;
                float v = acc[i][j][r] + bv;
                if (act == 1) v = 0.5f * v * (1.0f + erff(v * 0.70710678118654752f));
                if (Cb) {
                    Cb[(size_t)row * ldc + col] = f2b(v);
                } else {
                    size_t co = (size_t)row * ldc + col;
                    if (accum) v += C[co];
                    C[co] = v;
                }
            }
        }
    }
}

// =============== weight cast+transpose: fp32 [R][C] -> bf16 [C][R] ===============
__global__ __launch_bounds__(256) void castw_t(const float* __restrict__ in,
    u16* __restrict__ out, int R, int C)
{
    __shared__ float t[32][33];
    int c0 = blockIdx.x * 32, r0 = blockIdx.y * 32;
    int lx = threadIdx.x & 31, ly = threadIdx.x >> 5;
    #pragma unroll
    for (int i = 0; i < 4; i++)
        t[ly + i * 8][lx] = in[(size_t)(r0 + ly + i * 8) * C + c0 + lx];
    __syncthreads();
    #pragma unroll
    for (int i = 0; i < 4; i++)
        out[(size_t)(c0 + ly + i * 8) * R + r0 + lx] = f2b(t[lx][ly + i * 8]);
}

// =============== conv weight cast: [co][ci][t] fp32 -> [t][co][ci] bf16 ===============
__global__ void castconvw_k(const float* __restrict__ cw, u16* __restrict__ out)
{
    int i = blockIdx.x * 256 + threadIdx.x;
    if (i >= 3 * NC * NC) return;
    int ci = i & (NC - 1), co = (i >> 9) & (NC - 1), t = i >> 18;
    out[i] = f2b(cw[(co * NC + ci) * 3 + t]);
}

// =============== elementwise fp32 -> bf16 ===============
__global__ void castact_k(const float* __restrict__ in, u16* __restrict__ out, int n4)
{
    int i = blockIdx.x * 256 + threadIdx.x;
    if (i >= n4) return;
    float4 v = ((const float4*)in)[i];
    ushort4 o;
    o.x = f2b(v.x); o.y = f2b(v.y); o.z = f2b(v.z); o.w = f2b(v.w);
    ((ushort4*)out)[i] = o;
}

// =============== QKV GEMM fp32 (128x128 tile) with head-major scatter ===============
__global__ __launch_bounds__(256) void gemm_qkv_k(const float* __restrict__ A,
    const float* __restrict__ B, const float* __restrict__ bias,
    float* __restrict__ Qh, float* __restrict__ Kh, float* __restrict__ Vh)
{
    __shared__ float As[16][132];
    __shared__ float Bs[16][132];
    int tid = threadIdx.x;
    int n0 = blockIdx.x * 128, m0 = blockIdx.y * 128;
    int tx = tid & 15, ty = tid >> 4;
    float acc[8][8] = {};
    for (int k0 = 0; k0 < NC; k0 += 16) {
        #pragma unroll
        for (int i = 0; i < 2; i++) {
            int t = tid + i * 256;
            int m = t >> 2, kq = t & 3;
            float4 a4 = *(const float4*)&A[(size_t)(m0 + m) * NC + k0 + kq * 4];
            As[kq * 4 + 0][m] = a4.x; As[kq * 4 + 1][m] = a4.y;
            As[kq * 4 + 2][m] = a4.z; As[kq * 4 + 3][m] = a4.w;
        }
        #pragma unroll
        for (int i = 0; i < 2; i++) {
            int t = tid + i * 256;
            int k = t >> 5, nq = t & 31;
            *(float4*)&Bs[k][nq * 4] = *(const float4*)&B[(size_t)(k0 + k) * 1536 + n0 + nq * 4];
        }
        __syncthreads();
        #pragma unroll
        for (int kk = 0; kk < 16; kk++) {
            float av[8], bv[8];
            *(float4*)&av[0] = *(const float4*)&As[kk][ty * 4];
            *(float4*)&av[4] = *(const float4*)&As[kk][64 + ty * 4];
            *(float4*)&bv[0] = *(const float4*)&Bs[kk][tx * 4];
            *(float4*)&bv[4] = *(const float4*)&Bs[kk][64 + tx * 4];
            #pragma unroll
            for (int i = 0; i < 8; i++)
                #pragma unroll
                for (int j = 0; j < 8; j++) acc[i][j] += av[i] * bv[j];
        }
        __syncthreads();
    }
    int which = n0 >> 9;
    float* outb = which == 0 ? Qh : (which == 1 ? Kh : Vh);
    #pragma unroll
    for (int jq = 0; jq < 2; jq++) {
        int colq = n0 + jq * 64;
        int h = (colq >> 6) & 7;
        float4 b4 = *(const float4*)&bias[colq + tx * 4];
        #pragma unroll
        for (int i = 0; i < 8; i++) {
            int m = m0 + (i >> 2) * 64 + ty * 4 + (i & 3);
            int b = m >> 11, row = m & (NN - 1);
            float4 c4;
            c4.x = acc[i][jq * 4 + 0] + b4.x;
            c4.y = acc[i][jq * 4 + 1] + b4.y;
            c4.z = acc[i][jq * 4 + 2] + b4.z;
            c4.w = acc[i][jq * 4 + 3] + b4.w;
            *(float4*)&outb[((size_t)((b << 3) + h) * NN + row) * DK + tx * 4] = c4;
        }
    }
}

// =============== mean of V over sequence ===============
__global__ void meanv_k(const float* __restrict__ Vh, float* __restrict__ meanv)
{
    int bh = blockIdx.x;
    int tid = threadIdx.x;
    int d = tid & 63, seg = tid >> 6;
    const float* vb = Vh + (size_t)bh * NN * DK;
    float s = 0.f;
    for (int m = seg * 512; m < seg * 512 + 512; m++) s += vb[(size_t)m * DK + d];
    __shared__ float red[256];
    red[tid] = s;
    __syncthreads();
    if (seg == 0)
        meanv[bh * DK + d] = (red[d] + red[64 + d] + red[128 + d] + red[192 + d]) * (1.0f / (float)NN);
}

// =============== rowstat: M = max - mean, outer-product form (fp32-exact) ===============
__global__ __launch_bounds__(256) void rowstat_k(const float* __restrict__ Qh,
    const float* __restrict__ Kh, float* __restrict__ Marr)
{
    int bh = blockIdx.y;
    int m0 = blockIdx.x * 128;
    __shared__ float Qs[64][132];   // [d][m]
    __shared__ float Ks[64][132];   // [d][n]
    int tid = threadIdx.x, tx = tid & 15, ty = tid >> 4;
    const float* qb = Qh + ((size_t)bh * NN + m0) * DK;
    const float* kb = Kh + (size_t)bh * NN * DK;
    #pragma unroll
    for (int i = 0; i < 8; i++) {
        int t = tid + i * 256;
        int m = t >> 4, dq = t & 15;
        float4 q4 = *(const float4*)&qb[(size_t)m * DK + dq * 4];
        Qs[dq * 4 + 0][m] = q4.x; Qs[dq * 4 + 1][m] = q4.y;
        Qs[dq * 4 + 2][m] = q4.z; Qs[dq * 4 + 3][m] = q4.w;
    }
    float rmax[8], rsum[8];
    #pragma unroll
    for (int i = 0; i < 8; i++) { rmax[i] = -INFINITY; rsum[i] = 0.f; }
    for (int nc = 0; nc < NN; nc += 128) {
        __syncthreads();
        #pragma unroll
        for (int i = 0; i < 8; i++) {
            int t = tid + i * 256;
            int n = t >> 4, dq = t & 15;
            float4 k4 = *(const float4*)&kb[(size_t)(nc + n) * DK + dq * 4];
            Ks[dq * 4 + 0][n] = k4.x; Ks[dq * 4 + 1][n] = k4.y;
            Ks[dq * 4 + 2][n] = k4.z; Ks[dq * 4 + 3][n] = k4.w;
        }
        __syncthreads();
        float S[8][8] = {};
        #pragma unroll 8
        for (int d = 0; d < 64; d++) {
            float av[8], bv[8];
            *(float4*)&av[0] = *(const float4*)&Qs[d][ty * 4];
            *(float4*)&av[4] = *(const float4*)&Qs[d][64 + ty * 4];
            *(float4*)&bv[0] = *(const float4*)&Ks[d][tx * 4];
            *(float4*)&bv[4] = *(const float4*)&Ks[d][64 + tx * 4];
            #pragma unroll
            for (int i = 0; i < 8; i++)
                #pragma unroll
                for (int j = 0; j < 8; j++) S[i][j] += av[i] * bv[j];
        }
        #pragma unroll
        for (int i = 0; i < 8; i++)
            #pragma unroll
            for (int j = 0; j < 8; j++) {
                rmax[i] = fmaxf(rmax[i], S[i][j]);
                rsum[i] += S[i][j];
            }
    }
    #pragma unroll
    for (int off = 1; off < 16; off <<= 1)
        #pragma unroll
        for (int i = 0; i < 8; i++) {
            rmax[i] = fmaxf(rmax[i], __shfl_xor(rmax[i], off));
            rsum[i] += __shfl_xor(rsum[i], off);
        }
    if (tx == 0)
        #pragma unroll
        for (int i = 0; i < 8; i++) {
            int m = m0 + (i >> 2) * 64 + ty * 4 + (i & 3);
            Marr[(size_t)bh * NN + m] =
                (rmax[i] - rsum[i] * (1.0f / (float)NN)) * 0.125f;
        }
}

// =============== top-512 per (b,h): sorted compact index list ===============
__global__ __launch_bounds__(256) void topk_k(const float* __restrict__ Marr,
                                              int* __restrict__ idx)
{
    int bh = blockIdx.x;
    const float* Mr = Marr + (size_t)bh * NN;
    int* idxr = idx + (size_t)bh * NTOP;
    __shared__ float s[NN];
    __shared__ int sg[256], se[256];
    int tid = threadIdx.x;
    for (int i = tid; i < NN; i += 256) s[i] = Mr[i];
    __syncthreads();
    for (int k = 2; k <= NN; k <<= 1)
        for (int j = k >> 1; j > 0; j >>= 1) {
            for (int t = tid; t < NN / 2; t += 256) {
                int i = ((t & ~(j - 1)) << 1) | (t & (j - 1));
                int ixj = i | j;
                float a = s[i], bb = s[ixj];
                bool up = ((i & k) == 0);
                if ((a > bb) == up) { s[i] = bb; s[ixj] = a; }
            }
            __syncthreads();
        }
    float thr = s[NN - NTOP];
    int lg = 0, le = 0;
    #pragma unroll
    for (int k = 0; k < 8; k++) {
        float v = Mr[tid * 8 + k];
        lg += (v > thr) ? 1 : 0;
        le += (v == thr) ? 1 : 0;
    }
    sg[tid] = lg; se[tid] = le;
    __syncthreads();
    for (int off = 1; off < 256; off <<= 1) {
        int ag = (tid >= off) ? sg[tid - off] : 0;
        int ae = (tid >= off) ? se[tid - off] : 0;
        __syncthreads();
        sg[tid] += ag; se[tid] += ae;
        __syncthreads();
    }
    int cnt_gt = sg[255];
    int needed = NTOP - cnt_gt;
    int gpre = sg[tid] - lg, epre = se[tid] - le;
    #pragma unroll
    for (int k = 0; k < 8; k++) {
        int p = tid * 8 + k;
        float v = Mr[p];
        bool isgt = v > thr, iseq = v == thr;
        bool selv = isgt || (iseq && epre < needed);
        if (selv) idxr[gpre + (epre < needed ? epre : needed)] = p;
        gpre += isgt ? 1 : 0;
        epre += iseq ? 1 : 0;
    }
}

// =============== fill ctx with uniform-attention result ===============
__global__ void fill_k(const float* __restrict__ meanv, float* __restrict__ ctx)
{
    int i = blockIdx.x * 256 + threadIdx.x;
    if (i >= NB * NN * NC) return;
    int c = i & (NC - 1);
    int m = i >> 9;
    int b = m >> 11;
    int h = c >> 6, d = c & 63;
    ctx[i] = meanv[(((b << 3) + h) << 6) + d];
}

// =============== flash attention, conflict-free layouts, 128-col K tiles ===============
__global__ __launch_bounds__(256) void attn_sel_k(const float* __restrict__ Qh,
    const float* __restrict__ Kh, const float* __restrict__ Vh,
    const int* __restrict__ idx, float* __restrict__ ctx)
{
    int bh = blockIdx.y;
    int t0 = blockIdx.x * QT;
    int h = bh & 7, b = bh >> 3;
    int tid = threadIdx.x, tx = tid & 15, ty = tid >> 4;
    __shared__ float Qs[QT][68];    // [m][d]
    __shared__ float Ks[64][132];   // [d][n]  (transposed)
    __shared__ float Vs[128][68];   // [n][d]
    __shared__ float Ps[QT][132];   // [m][n]
    __shared__ int rows[QT];
    if (tid < QT) rows[tid] = idx[bh * NTOP + t0 + tid];
    __syncthreads();
    #pragma unroll
    for (int i = 0; i < 2; i++) {
        int t = tid + i * 256;
        int r = t >> 4, dq = t & 15;
        *(float4*)&Qs[r][dq * 4] =
            *(const float4*)&Qh[((size_t)bh * NN + rows[r]) * DK + dq * 4];
    }
    float O[2][4] = {};
    float rmax[2] = {-INFINITY, -INFINITY};
    float rsum[2] = {0.f, 0.f};
    const float* kb = Kh + (size_t)bh * NN * DK;
    const float* vb = Vh + (size_t)bh * NN * DK;
    for (int nc = 0; nc < NN; nc += 128) {
        __syncthreads();
        #pragma unroll
        for (int i = 0; i < 8; i++) {
            int t = tid + i * 256;
            int n = t >> 4, dq = t & 15;
            float4 kv = *(const float4*)&kb[(size_t)(nc + n) * DK + dq * 4];
            Ks[dq * 4 + 0][n] = kv.x; Ks[dq * 4 + 1][n] = kv.y;
            Ks[dq * 4 + 2][n] = kv.z; Ks[dq * 4 + 3][n] = kv.w;
            *(float4*)&Vs[n][dq * 4] = *(const float4*)&vb[(size_t)(nc + n) * DK + dq * 4];
        }
        __syncthreads();
        float S[2][8] = {};
        #pragma unroll
        for (int dq = 0; dq < 16; dq++) {
            float4 q0 = *(const float4*)&Qs[ty * 2][dq * 4];
            float4 q1 = *(const float4*)&Qs[ty * 2 + 1][dq * 4];
            float qa[2][4] = {{q0.x, q0.y, q0.z, q0.w}, {q1.x, q1.y, q1.z, q1.w}};
            #pragma unroll
            for (int l = 0; l < 4; l++) {
                float4 k0 = *(const float4*)&Ks[dq * 4 + l][tx * 4];
                float4 k1 = *(const float4*)&Ks[dq * 4 + l][64 + tx * 4];
                float kn[8] = {k0.x, k0.y, k0.z, k0.w, k1.x, k1.y, k1.z, k1.w};
                #pragma unroll
                for (int i2 = 0; i2 < 2; i2++)
                    #pragma unroll
                    for (int j = 0; j < 8; j++) S[i2][j] += qa[i2][l] * kn[j];
            }
        }
        float mloc[2], ssum[2];
        #pragma unroll
        for (int i2 = 0; i2 < 2; i2++) {
            #pragma unroll
            for (int j = 0; j < 8; j++) S[i2][j] *= 0.125f;
            float m01 = fmaxf(fmaxf(S[i2][0], S[i2][1]), fmaxf(S[i2][2], S[i2][3]));
            float m23 = fmaxf(fmaxf(S[i2][4], S[i2][5]), fmaxf(S[i2][6], S[i2][7]));
            mloc[i2] = fmaxf(m01, m23);
        }
        #pragma unroll
        for (int off = 1; off < 16; off <<= 1)
            #pragma unroll
            for (int i2 = 0; i2 < 2; i2++)
                mloc[i2] = fmaxf(mloc[i2], __shfl_xor(mloc[i2], off));
        #pragma unroll
        for (int i2 = 0; i2 < 2; i2++) {
            float mnew = fmaxf(rmax[i2], mloc[i2]);
            float alpha = expf(rmax[i2] - mnew);
            rmax[i2] = mnew;
            ssum[i2] = 0.f;
            #pragma unroll
            for (int j = 0; j < 8; j++) {
                float p = expf(S[i2][j] - mnew);
                S[i2][j] = p;
                ssum[i2] += p;
            }
            #pragma unroll
            for (int j = 0; j < 4; j++) O[i2][j] *= alpha;
            rsum[i2] *= alpha;
        }
        #pragma unroll
        for (int off = 1; off < 16; off <<= 1)
            #pragma unroll
            for (int i2 = 0; i2 < 2; i2++) ssum[i2] += __shfl_xor(ssum[i2], off);
        #pragma unroll
        for (int i2 = 0; i2 < 2; i2++) {
            rsum[i2] += ssum[i2];
            *(float4*)&Ps[ty * 2 + i2][tx * 4] =
                make_float4(S[i2][0], S[i2][1], S[i2][2], S[i2][3]);
            *(float4*)&Ps[ty * 2 + i2][64 + tx * 4] =
                make_float4(S[i2][4], S[i2][5], S[i2][6], S[i2][7]);
        }
        // P rows written & read by the same wave (same ty group) -> no barrier
        #pragma unroll
        for (int nq = 0; nq < 32; nq++) {
            float4 p0 = *(const float4*)&Ps[ty * 2][nq * 4];
            float4 p1 = *(const float4*)&Ps[ty * 2 + 1][nq * 4];
            float pa[2][4] = {{p0.x, p0.y, p0.z, p0.w}, {p1.x, p1.y, p1.z, p1.w}};
            #pragma unroll
            for (int l = 0; l < 4; l++) {
                float4 vv = *(const float4*)&Vs[nq * 4 + l][tx * 4];
                #pragma unroll
                for (int i2 = 0; i2 < 2; i2++) {
                    O[i2][0] += pa[i2][l] * vv.x;
                    O[i2][1] += pa[i2][l] * vv.y;
                    O[i2][2] += pa[i2][l] * vv.z;
                    O[i2][3] += pa[i2][l] * vv.w;
                }
            }
        }
    }
    #pragma unroll
    for (int i2 = 0; i2 < 2; i2++) {
        int n = rows[ty * 2 + i2];
        float inv = 1.0f / rsum[i2];
        float4 o = make_float4(O[i2][0] * inv, O[i2][1] * inv, O[i2][2] * inv, O[i2][3] * inv);
        *(float4*)&ctx[((size_t)(b * NN + n)) * NC + h * DK + tx * 4] = o;
    }
}

// =============== layernorm over residual sum; fp32 and/or bf16 out ===============
__global__ __launch_bounds__(256) void ln_k(const float* __restrict__ A,
    const float* __restrict__ Bv, const float* __restrict__ g,
    const float* __restrict__ bb, float* __restrict__ out, u16* __restrict__ outb)
{
    int row = blockIdx.x;
    int tid = threadIdx.x;
    __shared__ float v[NC];
    __shared__ float red[256];
    size_t base = (size_t)row * NC;
    for (int i = tid; i < NC; i += 256) v[i] = A[base + i] + Bv[base + i];
    __syncthreads();
    float ls = 0.f;
    for (int i = tid; i < NC; i += 256) ls += v[i];
    red[tid] = ls; __syncthreads();
    for (int off = 128; off > 0; off >>= 1) {
        if (tid < off) red[tid] += red[tid + off];
        __syncthreads();
    }
    float mu = red[0] / (float)NC;
    __syncthreads();
    float lv = 0.f;
    for (int i = tid; i < NC; i += 256) { float d = v[i] - mu; lv += d * d; }
    red[tid] = lv; __syncthreads();
    for (int off = 128; off > 0; off >>= 1) {
        if (tid < off) red[tid] += red[tid + off];
        __syncthreads();
    }
    float rstd = rsqrtf(red[0] / (float)NC + 1e-5f);
    for (int i = tid; i < NC; i += 256) {
        float r = (v[i] - mu) * rstd * g[i] + bb[i];
        if (out) out[base + i] = r;
        if (outb) outb[base + i] = f2b(r);
    }
}

// =============== maxpool(3,2,1) + ELU + LN -> out ===============
__global__ __launch_bounds__(256) void pool_ln_k(const float* __restrict__ y,
    const float* __restrict__ g, const float* __restrict__ bb,
    float* __restrict__ outp)
{
    int row = blockIdx.x;
    int j = row & (NPOOL - 1), b = row / NPOOL;
    int tid = threadIdx.x;
    __shared__ float v[NC];
    __shared__ float red[256];
    const float* ybase = y + (size_t)b * NN * NC;
    for (int i = tid; i < NC; i += 256) {
        float m = -INFINITY;
        int p0 = 2 * j - 1;
        #pragma unroll
        for (int t = 0; t < 3; t++) {
            int p = p0 + t;
            if (p >= 0 && p < NN) m = fmaxf(m, ybase[(size_t)p * NC + i]);
        }
        v[i] = m > 0.f ? m : expm1f(m);
    }
    __syncthreads();
    float ls = 0.f;
    for (int i = tid; i < NC; i += 256) ls += v[i];
    red[tid] = ls; __syncthreads();
    for (int off = 128; off > 0; off >>= 1) {
        if (tid < off) red[tid] += red[tid + off];
        __syncthreads();
    }
    float mu = red[0] / (float)NC;
    __syncthreads();
    float lv = 0.f;
    for (int i = tid; i < NC; i += 256) { float d = v[i] - mu; lv += d * d; }
    red[tid] = lv; __syncthreads();
    for (int off = 128; off > 0; off >>= 1) {
        if (tid < off) red[tid] += red[tid + off];
        __syncthreads();
    }
    float rstd = rsqrtf(red[0] / (float)NC + 1e-5f);
    for (int i = tid; i < NC; i += 256)
        outp[(size_t)row * NC + i] = (v[i] - mu) * rstd * g[i] + bb[i];
}

extern "C" void kernel_launch(void* const* d_in, const int* in_sizes, int n_in,
                              void* d_out, int out_size, void* d_ws, size_t ws_size,
                              hipStream_t stream)
{
    (void)in_sizes; (void)n_in; (void)out_size; (void)ws_size;
    const float* x      = (const float*)d_in[0];
    const float* qkv_w  = (const float*)d_in[1];
    const float* qkv_b  = (const float*)d_in[2];
    const float* out_w  = (const float*)d_in[3];
    const float* out_b  = (const float*)d_in[4];
    const float* ffn_w1 = (const float*)d_in[5];
    const float* ffn_b1 = (const float*)d_in[6];
    const float* ffn_w2 = (const float*)d_in[7];
    const float* ffn_b2 = (const float*)d_in[8];
    const float* n1_g   = (const float*)d_in[9];
    const float* n1_b   = (const float*)d_in[10];
    const float* n2_g   = (const float*)d_in[11];
    const float* n2_b   = (const float*)d_in[12];
    const float* conv_w = (const float*)d_in[13];
    const float* conv_b = (const float*)d_in[14];
    const float* cn_g   = (const float*)d_in[15];
    const float* cn_b   = (const float*)d_in[16];

    const size_t R = (size_t)NB * NN * NC;     // 2097152
    float* ws = (float*)d_ws;
    float* x1    = ws;                // R : ln1 out fp32
    float* ctx   = ws + R;            // R : attn ctx; later ffn_out
    float* Qh    = ws + 2 * R;        // R : Q; later attn_out, convy
    float* Kh    = ws + 3 * R;        // R : K; later hb lo
    float* Vh    = ws + 4 * R;        // R : V; later hb hi
    // aux region
    size_t o = 5 * R;
    float* Marr  = ws + o;  o += 32768;
    float* meanv = ws + o;  o += 1024;
    int*   idx   = (int*)(ws + o);  o += 8192;
    u16*   ctxb  = (u16*)(ws + o);  o += R / 2;        // R bf16
    u16*   x1b   = (u16*)(ws + o);  o += R / 2;
    u16*   x2b   = (u16*)(ws + o);  o += R / 2;
    u16*   owT   = (u16*)(ws + o);  o += 131072;       // [512][512]
    u16*   w1T   = (u16*)(ws + o);  o += 524288;       // [2048][512]
    u16*   w2T   = (u16*)(ws + o);  o += 524288;       // [512][2048]
    u16*   cwT   = (u16*)(ws + o);  o += 393216;       // 3x[512][512]
    float* attn_out = Qh;
    u16*   hb       = (u16*)(ws + 3 * R);   // [4096][2048] bf16 (Kh+Vh)
    float* ffn_out  = ctx;
    float* convy    = Qh;

    // weight casts (independent of everything else)
    castw_t<<<dim3(16, 16), 256, 0, stream>>>(out_w, owT, 512, 512);
    castw_t<<<dim3(64, 16), 256, 0, stream>>>(ffn_w1, w1T, 512, 2048);
    castw_t<<<dim3(16, 64), 256, 0, stream>>>(ffn_w2, w2T, 2048, 512);
    castconvw_k<<<3072, 256, 0, stream>>>(conv_w, cwT);

    // qkv = x @ qkv_w + qkv_b -> head-major Q/K/V (fp32, selection-exact)
    gemm_qkv_k<<<dim3(12, 32), 256, 0, stream>>>(x, qkv_w, qkv_b, Qh, Kh, Vh);

    meanv_k<<<NB * NH, 256, 0, stream>>>(Vh, meanv);
    rowstat_k<<<dim3(NN / 128, NB * NH), 256, 0, stream>>>(Qh, Kh, Marr);
    topk_k<<<NB * NH, 256, 0, stream>>>(Marr, idx);
    fill_k<<<((int)R + 255) / 256, 256, 0, stream>>>(meanv, ctx);
    attn_sel_k<<<dim3(NTOP / QT, NB * NH), 256, 0, stream>>>(Qh, Kh, Vh, idx, ctx);

    // ctx -> bf16, then proj (MFMA): attn_out = ctx @ out_w + out_b
    castact_k<<<(int)(R / 4 / 256), 256, 0, stream>>>(ctx, ctxb, (int)(R / 4));
    mfma_gemm<false><<<dim3(4, 32), 256, 0, stream>>>(
        ctxb, NC, owT, out_b, attn_out, (u16*)nullptr, NC, NC, 0, 0, 0);

    // x1 = LN(x + attn_out), also bf16 copy
    ln_k<<<NB * NN, 256, 0, stream>>>(x, attn_out, n1_g, n1_b, x1, x1b);

    // FFN (MFMA): h = gelu(x1b @ W1) -> bf16 ; ffn_out = h @ W2 + b2
    mfma_gemm<false><<<dim3(16, 32), 256, 0, stream>>>(
        x1b, NC, w1T, ffn_b1, (float*)nullptr, hb, DFF, NC, 1, 0, 0);
    mfma_gemm<false><<<dim3(4, 32), 256, 0, stream>>>(
        hb, DFF, w2T, ffn_b2, ffn_out, (u16*)nullptr, NC, DFF, 0, 0, 0);

    // x2 = LN(x1 + ffn_out) -> bf16 only
    ln_k<<<NB * NN, 256, 0, stream>>>(x1, ffn_out, n2_g, n2_b, (float*)nullptr, x2b);

    // circular conv1d(k=3) as 3 accumulating MFMA GEMMs with shifted A-rows
    for (int t = 0; t < 3; t++) {
        mfma_gemm<true><<<dim3(4, 32), 256, 0, stream>>>(
            x2b, NC, cwT + (size_t)t * NC * NC,
            (t == 0 ? conv_b : (const float*)nullptr), convy, (u16*)nullptr, NC,
            NC, 0, (t == 0 ? 0 : 1), t - 1);
    }

    pool_ln_k<<<NB * NPOOL, 256, 0, stream>>>(convy, cn_g, cn_b, (float*)d_out);
}

// Round 7
// 807.436 us; speedup vs baseline: 1.8722x; 1.0878x over previous
//
#include <hip/hip_runtime.h>
#include <math.h>

#define NB 2
#define NN 2048
#define NC 512
#define NH 8
#define DK 64
#define DFF 2048
#define NTOP 512
#define NPOOL 1024
#define QT 32
#define KSPLIT 4

typedef unsigned short u16;
typedef __attribute__((ext_vector_type(8))) short frag8;
typedef __attribute__((ext_vector_type(4))) float f32x4;

static __device__ __forceinline__ u16 f2b(float f) {
    union { float f; unsigned int u; } v; v.f = f;
    unsigned int r = (v.u + 0x7fffu + ((v.u >> 16) & 1u)) >> 16;
    return (u16)r;
}

// =============== bf16 MFMA GEMM: C = A @ Bt^T (+bias)(+gelu)(+accum) ===============
template<bool CIRC>
__global__ __launch_bounds__(256) void mfma_gemm(const u16* __restrict__ A, int lda,
    const u16* __restrict__ Bt, const float* __restrict__ bias,
    float* __restrict__ C, u16* __restrict__ Cb, int ldc,
    int K, int act, int accum, int shift)
{
    __shared__ u16 As[128][72];
    __shared__ u16 Bs[128][72];
    int tid = threadIdx.x;
    int n0 = blockIdx.x * 128, m0 = blockIdx.y * 128;
    int wave = tid >> 6, lane = tid & 63;
    int ln = lane & 15, quad = lane >> 4;
    int wm = (wave >> 1) * 64, wn = (wave & 1) * 64;
    f32x4 acc[4][4] = {};
    for (int k0 = 0; k0 < K; k0 += 64) {
        #pragma unroll
        for (int i = 0; i < 4; i++) {
            int t = tid + i * 256;
            int m = t >> 3, kq = t & 7;
            int grow = m0 + m;
            int arow = CIRC ? ((grow & ~(NN - 1)) | ((grow + shift) & (NN - 1))) : grow;
            *(uint4*)&As[m][kq * 8] = *(const uint4*)&A[(size_t)arow * lda + k0 + kq * 8];
            *(uint4*)&Bs[m][kq * 8] = *(const uint4*)&Bt[(size_t)(n0 + m) * K + k0 + kq * 8];
        }
        __syncthreads();
        #pragma unroll
        for (int kk = 0; kk < 2; kk++) {
            frag8 af[4], bf[4];
            #pragma unroll
            for (int i = 0; i < 4; i++) {
                af[i] = *(const frag8*)&As[wm + i * 16 + ln][kk * 32 + quad * 8];
                bf[i] = *(const frag8*)&Bs[wn + i * 16 + ln][kk * 32 + quad * 8];
            }
            #pragma unroll
            for (int i = 0; i < 4; i++)
                #pragma unroll
                for (int j = 0; j < 4; j++)
                    acc[i][j] = __builtin_amdgcn_mfma_f32_16x16x32_bf16(
                        af[i], bf[j], acc[i][j], 0, 0, 0);
        }
        __syncthreads();
    }
    #pragma unroll
    for (int i = 0; i < 4; i++) {
        #pragma unroll
        for (int j = 0; j < 4; j++) {
            int col = n0 + wn + j * 16 + ln;
            float bv = bias ? bias[col] : 0.f;
            #pragma unroll
            for (int r = 0; r < 4; r++) {
                int row = m0 + wm + i * 16 + quad * 4 + r;
                float v = acc[i][j][r] + bv;
                if (act == 1) v = 0.5f * v * (1.0f + erff(v * 0.70710678118654752f));
                if (Cb) {
                    Cb[(size_t)row * ldc + col] = f2b(v);
                } else {
                    size_t co = (size_t)row * ldc + col;
                    if (accum) v += C[co];
                    C[co] = v;
                }
            }
        }
    }
}

// =============== weight cast+transpose: fp32 [R][C] -> bf16 [C][R] ===============
__global__ __launch_bounds__(256) void castw_t(const float* __restrict__ in,
    u16* __restrict__ out, int R, int C)
{
    __shared__ float t[32][33];
    int c0 = blockIdx.x * 32, r0 = blockIdx.y * 32;
    int lx = threadIdx.x & 31, ly = threadIdx.x >> 5;
    #pragma unroll
    for (int i = 0; i < 4; i++)
        t[ly + i * 8][lx] = in[(size_t)(r0 + ly + i * 8) * C + c0 + lx];
    __syncthreads();
    #pragma unroll
    for (int i = 0; i < 4; i++)
        out[(size_t)(c0 + ly + i * 8) * R + r0 + lx] = f2b(t[lx][ly + i * 8]);
}

// =============== conv weight cast: [co][ci][t] fp32 -> [t][co][ci] bf16 ===============
__global__ void castconvw_k(const float* __restrict__ cw, u16* __restrict__ out)
{
    int i = blockIdx.x * 256 + threadIdx.x;
    if (i >= 3 * NC * NC) return;
    int ci = i & (NC - 1), co = (i >> 9) & (NC - 1), t = i >> 18;
    out[i] = f2b(cw[(co * NC + ci) * 3 + t]);
}

// =============== elementwise fp32 -> bf16 ===============
__global__ void castact_k(const float* __restrict__ in, u16* __restrict__ out, int n4)
{
    int i = blockIdx.x * 256 + threadIdx.x;
    if (i >= n4) return;
    float4 v = ((const float4*)in)[i];
    ushort4 o;
    o.x = f2b(v.x); o.y = f2b(v.y); o.z = f2b(v.z); o.w = f2b(v.w);
    ((ushort4*)out)[i] = o;
}

// =============== QKV GEMM fp32 (128x128 tile) with head-major scatter ===============
__global__ __launch_bounds__(256) void gemm_qkv_k(const float* __restrict__ A,
    const float* __restrict__ B, const float* __restrict__ bias,
    float* __restrict__ Qh, float* __restrict__ Kh, float* __restrict__ Vh)
{
    __shared__ float As[16][132];
    __shared__ float Bs[16][132];
    int tid = threadIdx.x;
    int n0 = blockIdx.x * 128, m0 = blockIdx.y * 128;
    int tx = tid & 15, ty = tid >> 4;
    float acc[8][8] = {};
    for (int k0 = 0; k0 < NC; k0 += 16) {
        #pragma unroll
        for (int i = 0; i < 2; i++) {
            int t = tid + i * 256;
            int m = t >> 2, kq = t & 3;
            float4 a4 = *(const float4*)&A[(size_t)(m0 + m) * NC + k0 + kq * 4];
            As[kq * 4 + 0][m] = a4.x; As[kq * 4 + 1][m] = a4.y;
            As[kq * 4 + 2][m] = a4.z; As[kq * 4 + 3][m] = a4.w;
        }
        #pragma unroll
        for (int i = 0; i < 2; i++) {
            int t = tid + i * 256;
            int k = t >> 5, nq = t & 31;
            *(float4*)&Bs[k][nq * 4] = *(const float4*)&B[(size_t)(k0 + k) * 1536 + n0 + nq * 4];
        }
        __syncthreads();
        #pragma unroll
        for (int kk = 0; kk < 16; kk++) {
            float av[8], bv[8];
            *(float4*)&av[0] = *(const float4*)&As[kk][ty * 4];
            *(float4*)&av[4] = *(const float4*)&As[kk][64 + ty * 4];
            *(float4*)&bv[0] = *(const float4*)&Bs[kk][tx * 4];
            *(float4*)&bv[4] = *(const float4*)&Bs[kk][64 + tx * 4];
            #pragma unroll
            for (int i = 0; i < 8; i++)
                #pragma unroll
                for (int j = 0; j < 8; j++) acc[i][j] += av[i] * bv[j];
        }
        __syncthreads();
    }
    int which = n0 >> 9;
    float* outb = which == 0 ? Qh : (which == 1 ? Kh : Vh);
    #pragma unroll
    for (int jq = 0; jq < 2; jq++) {
        int colq = n0 + jq * 64;
        int h = (colq >> 6) & 7;
        float4 b4 = *(const float4*)&bias[colq + tx * 4];
        #pragma unroll
        for (int i = 0; i < 8; i++) {
            int m = m0 + (i >> 2) * 64 + ty * 4 + (i & 3);
            int b = m >> 11, row = m & (NN - 1);
            float4 c4;
            c4.x = acc[i][jq * 4 + 0] + b4.x;
            c4.y = acc[i][jq * 4 + 1] + b4.y;
            c4.z = acc[i][jq * 4 + 2] + b4.z;
            c4.w = acc[i][jq * 4 + 3] + b4.w;
            *(float4*)&outb[((size_t)((b << 3) + h) * NN + row) * DK + tx * 4] = c4;
        }
    }
}

// =============== mean of V over sequence ===============
__global__ void meanv_k(const float* __restrict__ Vh, float* __restrict__ meanv)
{
    int bh = blockIdx.x;
    int tid = threadIdx.x;
    int d = tid & 63, seg = tid >> 6;
    const float* vb = Vh + (size_t)bh * NN * DK;
    float s = 0.f;
    for (int m = seg * 512; m < seg * 512 + 512; m++) s += vb[(size_t)m * DK + d];
    __shared__ float red[256];
    red[tid] = s;
    __syncthreads();
    if (seg == 0)
        meanv[bh * DK + d] = (red[d] + red[64 + d] + red[128 + d] + red[192 + d]) * (1.0f / (float)NN);
}

// =============== rowstat: M = max - mean, outer-product form (fp32-exact) ===============
__global__ __launch_bounds__(256) void rowstat_k(const float* __restrict__ Qh,
    const float* __restrict__ Kh, float* __restrict__ Marr)
{
    int bh = blockIdx.y;
    int m0 = blockIdx.x * 128;
    __shared__ float Qs[64][132];   // [d][m]
    __shared__ float Ks[64][132];   // [d][n]
    int tid = threadIdx.x, tx = tid & 15, ty = tid >> 4;
    const float* qb = Qh + ((size_t)bh * NN + m0) * DK;
    const float* kb = Kh + (size_t)bh * NN * DK;
    #pragma unroll
    for (int i = 0; i < 8; i++) {
        int t = tid + i * 256;
        int m = t >> 4, dq = t & 15;
        float4 q4 = *(const float4*)&qb[(size_t)m * DK + dq * 4];
        Qs[dq * 4 + 0][m] = q4.x; Qs[dq * 4 + 1][m] = q4.y;
        Qs[dq * 4 + 2][m] = q4.z; Qs[dq * 4 + 3][m] = q4.w;
    }
    float rmax[8], rsum[8];
    #pragma unroll
    for (int i = 0; i < 8; i++) { rmax[i] = -INFINITY; rsum[i] = 0.f; }
    for (int nc = 0; nc < NN; nc += 128) {
        __syncthreads();
        #pragma unroll
        for (int i = 0; i < 8; i++) {
            int t = tid + i * 256;
            int n = t >> 4, dq = t & 15;
            float4 k4 = *(const float4*)&kb[(size_t)(nc + n) * DK + dq * 4];
            Ks[dq * 4 + 0][n] = k4.x; Ks[dq * 4 + 1][n] = k4.y;
            Ks[dq * 4 + 2][n] = k4.z; Ks[dq * 4 + 3][n] = k4.w;
        }
        __syncthreads();
        float S[8][8] = {};
        #pragma unroll 8
        for (int d = 0; d < 64; d++) {
            float av[8], bv[8];
            *(float4*)&av[0] = *(const float4*)&Qs[d][ty * 4];
            *(float4*)&av[4] = *(const float4*)&Qs[d][64 + ty * 4];
            *(float4*)&bv[0] = *(const float4*)&Ks[d][tx * 4];
            *(float4*)&bv[4] = *(const float4*)&Ks[d][64 + tx * 4];
            #pragma unroll
            for (int i = 0; i < 8; i++)
                #pragma unroll
                for (int j = 0; j < 8; j++) S[i][j] += av[i] * bv[j];
        }
        #pragma unroll
        for (int i = 0; i < 8; i++)
            #pragma unroll
            for (int j = 0; j < 8; j++) {
                rmax[i] = fmaxf(rmax[i], S[i][j]);
                rsum[i] += S[i][j];
            }
    }
    #pragma unroll
    for (int off = 1; off < 16; off <<= 1)
        #pragma unroll
        for (int i = 0; i < 8; i++) {
            rmax[i] = fmaxf(rmax[i], __shfl_xor(rmax[i], off));
            rsum[i] += __shfl_xor(rsum[i], off);
        }
    if (tx == 0)
        #pragma unroll
        for (int i = 0; i < 8; i++) {
            int m = m0 + (i >> 2) * 64 + ty * 4 + (i & 3);
            Marr[(size_t)bh * NN + m] =
                (rmax[i] - rsum[i] * (1.0f / (float)NN)) * 0.125f;
        }
}

// =============== top-512 per (b,h): sorted compact index list ===============
__global__ __launch_bounds__(256) void topk_k(const float* __restrict__ Marr,
                                              int* __restrict__ idx)
{
    int bh = blockIdx.x;
    const float* Mr = Marr + (size_t)bh * NN;
    int* idxr = idx + (size_t)bh * NTOP;
    __shared__ float s[NN];
    __shared__ int sg[256], se[256];
    int tid = threadIdx.x;
    for (int i = tid; i < NN; i += 256) s[i] = Mr[i];
    __syncthreads();
    for (int k = 2; k <= NN; k <<= 1)
        for (int j = k >> 1; j > 0; j >>= 1) {
            for (int t = tid; t < NN / 2; t += 256) {
                int i = ((t & ~(j - 1)) << 1) | (t & (j - 1));
                int ixj = i | j;
                float a = s[i], bb = s[ixj];
                bool up = ((i & k) == 0);
                if ((a > bb) == up) { s[i] = bb; s[ixj] = a; }
            }
            __syncthreads();
        }
    float thr = s[NN - NTOP];
    int lg = 0, le = 0;
    #pragma unroll
    for (int k = 0; k < 8; k++) {
        float v = Mr[tid * 8 + k];
        lg += (v > thr) ? 1 : 0;
        le += (v == thr) ? 1 : 0;
    }
    sg[tid] = lg; se[tid] = le;
    __syncthreads();
    for (int off = 1; off < 256; off <<= 1) {
        int ag = (tid >= off) ? sg[tid - off] : 0;
        int ae = (tid >= off) ? se[tid - off] : 0;
        __syncthreads();
        sg[tid] += ag; se[tid] += ae;
        __syncthreads();
    }
    int cnt_gt = sg[255];
    int needed = NTOP - cnt_gt;
    int gpre = sg[tid] - lg, epre = se[tid] - le;
    #pragma unroll
    for (int k = 0; k < 8; k++) {
        int p = tid * 8 + k;
        float v = Mr[p];
        bool isgt = v > thr, iseq = v == thr;
        bool selv = isgt || (iseq && epre < needed);
        if (selv) idxr[gpre + (epre < needed ? epre : needed)] = p;
        gpre += isgt ? 1 : 0;
        epre += iseq ? 1 : 0;
    }
}

// =============== fill ctx with uniform-attention result ===============
__global__ void fill_k(const float* __restrict__ meanv, float* __restrict__ ctx)
{
    int i = blockIdx.x * 256 + threadIdx.x;
    if (i >= NB * NN * NC) return;
    int c = i & (NC - 1);
    int m = i >> 9;
    int b = m >> 11;
    int h = c >> 6, d = c & 63;
    ctx[i] = meanv[(((b << 3) + h) << 6) + d];
}

// =============== flash attention, split-K, low-LDS (Ps aliased on Ks) ===============
// grid: (NTOP/QT, NB*NH*KSPLIT). Each block: 32 selected rows x 512 keys.
// Emits unnormalized partials Opart[(bh*NTOP+p)*KSPLIT+s][64] and ml[...][2].
__global__ __launch_bounds__(256) void attn_sel_k(const float* __restrict__ Qh,
    const float* __restrict__ Kh, const float* __restrict__ Vh,
    const int* __restrict__ idx, float* __restrict__ Opart, float* __restrict__ ml)
{
    int yy = blockIdx.y;
    int bh = yy >> 2, split = yy & (KSPLIT - 1);
    int t0 = blockIdx.x * QT;
    int tid = threadIdx.x, tx = tid & 15, ty = tid >> 4;
    __shared__ float Qs[QT][68];     // [m][d]
    __shared__ float KsPs[64][68];   // Ks: [d][n] transposed; Ps aliased: [m][n]
    __shared__ float Vs[64][68];     // [n][d]
    __shared__ int rows[QT];
    float (*Ks)[68] = KsPs;
    float (*Ps)[68] = KsPs;
    if (tid < QT) rows[tid] = idx[bh * NTOP + t0 + tid];
    __syncthreads();
    #pragma unroll
    for (int i = 0; i < 2; i++) {
        int t = tid + i * 256;
        int r = t >> 4, dq = t & 15;
        *(float4*)&Qs[r][dq * 4] =
            *(const float4*)&Qh[((size_t)bh * NN + rows[r]) * DK + dq * 4];
    }
    float O[2][4] = {};
    float rmax[2] = {-INFINITY, -INFINITY};
    float rsum[2] = {0.f, 0.f};
    const float* kb = Kh + (size_t)bh * NN * DK;
    const float* vb = Vh + (size_t)bh * NN * DK;
    int nc0 = split * (NN / KSPLIT);
    for (int nc = nc0; nc < nc0 + NN / KSPLIT; nc += 64) {
        __syncthreads();
        #pragma unroll
        for (int i = 0; i < 4; i++) {
            int t = tid + i * 256;          // 0..1023
            int n = t >> 4, dq = t & 15;
            float4 kv = *(const float4*)&kb[(size_t)(nc + n) * DK + dq * 4];
            Ks[dq * 4 + 0][n] = kv.x; Ks[dq * 4 + 1][n] = kv.y;
            Ks[dq * 4 + 2][n] = kv.z; Ks[dq * 4 + 3][n] = kv.w;
            *(float4*)&Vs[n][dq * 4] = *(const float4*)&vb[(size_t)(nc + n) * DK + dq * 4];
        }
        __syncthreads();
        float S[2][4] = {};
        #pragma unroll
        for (int dq = 0; dq < 16; dq++) {
            float4 q0 = *(const float4*)&Qs[ty * 2][dq * 4];
            float4 q1 = *(const float4*)&Qs[ty * 2 + 1][dq * 4];
            float qa[2][4] = {{q0.x, q0.y, q0.z, q0.w}, {q1.x, q1.y, q1.z, q1.w}};
            #pragma unroll
            for (int l = 0; l < 4; l++) {
                float4 kv = *(const float4*)&Ks[dq * 4 + l][tx * 4];
                float kn[4] = {kv.x, kv.y, kv.z, kv.w};
                #pragma unroll
                for (int i2 = 0; i2 < 2; i2++)
                    #pragma unroll
                    for (int j = 0; j < 4; j++) S[i2][j] += qa[i2][l] * kn[j];
            }
        }
        float mloc[2], ssum[2];
        #pragma unroll
        for (int i2 = 0; i2 < 2; i2++) {
            #pragma unroll
            for (int j = 0; j < 4; j++) S[i2][j] *= 0.125f;
            mloc[i2] = fmaxf(fmaxf(S[i2][0], S[i2][1]), fmaxf(S[i2][2], S[i2][3]));
        }
        #pragma unroll
        for (int off = 1; off < 16; off <<= 1)
            #pragma unroll
            for (int i2 = 0; i2 < 2; i2++)
                mloc[i2] = fmaxf(mloc[i2], __shfl_xor(mloc[i2], off));
        #pragma unroll
        for (int i2 = 0; i2 < 2; i2++) {
            float mnew = fmaxf(rmax[i2], mloc[i2]);
            float alpha = expf(rmax[i2] - mnew);
            rmax[i2] = mnew;
            ssum[i2] = 0.f;
            #pragma unroll
            for (int j = 0; j < 4; j++) {
                float p = expf(S[i2][j] - mnew);
                S[i2][j] = p;
                ssum[i2] += p;
            }
            #pragma unroll
            for (int j = 0; j < 4; j++) O[i2][j] *= alpha;
            rsum[i2] *= alpha;
        }
        #pragma unroll
        for (int off = 1; off < 16; off <<= 1)
            #pragma unroll
            for (int i2 = 0; i2 < 2; i2++) ssum[i2] += __shfl_xor(ssum[i2], off);
        // all waves must finish reading Ks before Ps (alias) is written
        __syncthreads();
        #pragma unroll
        for (int i2 = 0; i2 < 2; i2++) {
            rsum[i2] += ssum[i2];
            *(float4*)&Ps[ty * 2 + i2][tx * 4] =
                make_float4(S[i2][0], S[i2][1], S[i2][2], S[i2][3]);
        }
        // P rows written & read only by this wave -> no barrier needed here
        #pragma unroll
        for (int nq = 0; nq < 16; nq++) {
            float4 p0 = *(const float4*)&Ps[ty * 2][nq * 4];
            float4 p1 = *(const float4*)&Ps[ty * 2 + 1][nq * 4];
            float pa[2][4] = {{p0.x, p0.y, p0.z, p0.w}, {p1.x, p1.y, p1.z, p1.w}};
            #pragma unroll
            for (int l = 0; l < 4; l++) {
                float4 vv = *(const float4*)&Vs[nq * 4 + l][tx * 4];
                #pragma unroll
                for (int i2 = 0; i2 < 2; i2++) {
                    O[i2][0] += pa[i2][l] * vv.x;
                    O[i2][1] += pa[i2][l] * vv.y;
                    O[i2][2] += pa[i2][l] * vv.z;
                    O[i2][3] += pa[i2][l] * vv.w;
                }
            }
        }
    }
    #pragma unroll
    for (int i2 = 0; i2 < 2; i2++) {
        int p = t0 + ty * 2 + i2;
        size_t pb = ((size_t)bh * NTOP + p) * KSPLIT + split;
        *(float4*)&Opart[pb * 64 + tx * 4] =
            make_float4(O[i2][0], O[i2][1], O[i2][2], O[i2][3]);
        if (tx == 0) { ml[pb * 2] = rmax[i2]; ml[pb * 2 + 1] = rsum[i2]; }
    }
}

// =============== combine split-K partials -> ctx (one wave per selected row) =========
__global__ __launch_bounds__(256) void attn_comb_k(const float* __restrict__ Opart,
    const float* __restrict__ ml, const int* __restrict__ idx,
    float* __restrict__ ctx)
{
    int gid = blockIdx.x * 4 + (threadIdx.x >> 6);   // bh*NTOP + p
    int lane = threadIdx.x & 63;
    int bh = gid >> 9, p = gid & (NTOP - 1);
    int h = bh & 7, b = bh >> 3;
    size_t base = (size_t)gid * KSPLIT;
    float M = -INFINITY;
    #pragma unroll
    for (int s = 0; s < KSPLIT; s++) M = fmaxf(M, ml[(base + s) * 2]);
    float L = 0.f, O = 0.f;
    #pragma unroll
    for (int s = 0; s < KSPLIT; s++) {
        float w = expf(ml[(base + s) * 2] - M);
        L += ml[(base + s) * 2 + 1] * w;
        O += Opart[(base + s) * 64 + lane] * w;
    }
    int n = idx[gid];
    ctx[((size_t)(b * NN + n)) * NC + h * DK + lane] = O / L;
}

// =============== layernorm over residual sum; fp32 and/or bf16 out ===============
__global__ __launch_bounds__(256) void ln_k(const float* __restrict__ A,
    const float* __restrict__ Bv, const float* __restrict__ g,
    const float* __restrict__ bb, float* __restrict__ out, u16* __restrict__ outb)
{
    int row = blockIdx.x;
    int tid = threadIdx.x;
    __shared__ float v[NC];
    __shared__ float red[256];
    size_t base = (size_t)row * NC;
    for (int i = tid; i < NC; i += 256) v[i] = A[base + i] + Bv[base + i];
    __syncthreads();
    float ls = 0.f;
    for (int i = tid; i < NC; i += 256) ls += v[i];
    red[tid] = ls; __syncthreads();
    for (int off = 128; off > 0; off >>= 1) {
        if (tid < off) red[tid] += red[tid + off];
        __syncthreads();
    }
    float mu = red[0] / (float)NC;
    __syncthreads();
    float lv = 0.f;
    for (int i = tid; i < NC; i += 256) { float d = v[i] - mu; lv += d * d; }
    red[tid] = lv; __syncthreads();
    for (int off = 128; off > 0; off >>= 1) {
        if (tid < off) red[tid] += red[tid + off];
        __syncthreads();
    }
    float rstd = rsqrtf(red[0] / (float)NC + 1e-5f);
    for (int i = tid; i < NC; i += 256) {
        float r = (v[i] - mu) * rstd * g[i] + bb[i];
        if (out) out[base + i] = r;
        if (outb) outb[base + i] = f2b(r);
    }
}

// =============== maxpool(3,2,1) + ELU + LN -> out ===============
__global__ __launch_bounds__(256) void pool_ln_k(const float* __restrict__ y,
    const float* __restrict__ g, const float* __restrict__ bb,
    float* __restrict__ outp)
{
    int row = blockIdx.x;
    int j = row & (NPOOL - 1), b = row / NPOOL;
    int tid = threadIdx.x;
    __shared__ float v[NC];
    __shared__ float red[256];
    const float* ybase = y + (size_t)b * NN * NC;
    for (int i = tid; i < NC; i += 256) {
        float m = -INFINITY;
        int p0 = 2 * j - 1;
        #pragma unroll
        for (int t = 0; t < 3; t++) {
            int p = p0 + t;
            if (p >= 0 && p < NN) m = fmaxf(m, ybase[(size_t)p * NC + i]);
        }
        v[i] = m > 0.f ? m : expm1f(m);
    }
    __syncthreads();
    float ls = 0.f;
    for (int i = tid; i < NC; i += 256) ls += v[i];
    red[tid] = ls; __syncthreads();
    for (int off = 128; off > 0; off >>= 1) {
        if (tid < off) red[tid] += red[tid + off];
        __syncthreads();
    }
    float mu = red[0] / (float)NC;
    __syncthreads();
    float lv = 0.f;
    for (int i = tid; i < NC; i += 256) { float d = v[i] - mu; lv += d * d; }
    red[tid] = lv; __syncthreads();
    for (int off = 128; off > 0; off >>= 1) {
        if (tid < off) red[tid] += red[tid + off];
        __syncthreads();
    }
    float rstd = rsqrtf(red[0] / (float)NC + 1e-5f);
    for (int i = tid; i < NC; i += 256)
        outp[(size_t)row * NC + i] = (v[i] - mu) * rstd * g[i] + bb[i];
}

extern "C" void kernel_launch(void* const* d_in, const int* in_sizes, int n_in,
                              void* d_out, int out_size, void* d_ws, size_t ws_size,
                              hipStream_t stream)
{
    (void)in_sizes; (void)n_in; (void)out_size; (void)ws_size;
    const float* x      = (const float*)d_in[0];
    const float* qkv_w  = (const float*)d_in[1];
    const float* qkv_b  = (const float*)d_in[2];
    const float* out_w  = (const float*)d_in[3];
    const float* out_b  = (const float*)d_in[4];
    const float* ffn_w1 = (const float*)d_in[5];
    const float* ffn_b1 = (const float*)d_in[6];
    const float* ffn_w2 = (const float*)d_in[7];
    const float* ffn_b2 = (const float*)d_in[8];
    const float* n1_g   = (const float*)d_in[9];
    const float* n1_b   = (const float*)d_in[10];
    const float* n2_g   = (const float*)d_in[11];
    const float* n2_b   = (const float*)d_in[12];
    const float* conv_w = (const float*)d_in[13];
    const float* conv_b = (const float*)d_in[14];
    const float* cn_g   = (const float*)d_in[15];
    const float* cn_b   = (const float*)d_in[16];

    const size_t R = (size_t)NB * NN * NC;     // 2097152
    float* ws = (float*)d_ws;
    float* x1    = ws;                // R : Opart during attention; ln1-out fp32 after
    float* ctx   = ws + R;            // R : attn ctx; later ffn_out
    float* Qh    = ws + 2 * R;        // R : Q; later attn_out, convy
    float* Kh    = ws + 3 * R;        // R : K; later hb lo
    float* Vh    = ws + 4 * R;        // R : V; later hb hi
    // aux region
    size_t o = 5 * R;
    float* Marr  = ws + o;  o += 32768;
    float* meanv = ws + o;  o += 1024;
    int*   idx   = (int*)(ws + o);  o += 8192;
    float* ml    = ws + o;  o += (size_t)NB * NH * NTOP * KSPLIT * 2;  // 65536
    u16*   ctxb  = (u16*)(ws + o);  o += R / 2;
    u16*   x1b   = (u16*)(ws + o);  o += R / 2;
    u16*   x2b   = (u16*)(ws + o);  o += R / 2;
    u16*   owT   = (u16*)(ws + o);  o += 131072;       // [512][512]
    u16*   w1T   = (u16*)(ws + o);  o += 524288;       // [2048][512]
    u16*   w2T   = (u16*)(ws + o);  o += 524288;       // [512][2048]
    u16*   cwT   = (u16*)(ws + o);  o += 393216;       // 3x[512][512]
    float* Opart    = x1;             // R floats, dead before ln1 writes x1
    float* attn_out = Qh;
    u16*   hb       = (u16*)(ws + 3 * R);   // [4096][2048] bf16 (Kh+Vh)
    float* ffn_out  = ctx;
    float* convy    = Qh;

    // weight casts (independent of everything else)
    castw_t<<<dim3(16, 16), 256, 0, stream>>>(out_w, owT, 512, 512);
    castw_t<<<dim3(64, 16), 256, 0, stream>>>(ffn_w1, w1T, 512, 2048);
    castw_t<<<dim3(16, 64), 256, 0, stream>>>(ffn_w2, w2T, 2048, 512);
    castconvw_k<<<3072, 256, 0, stream>>>(conv_w, cwT);

    // qkv = x @ qkv_w + qkv_b -> head-major Q/K/V (fp32, selection-exact)
    gemm_qkv_k<<<dim3(12, 32), 256, 0, stream>>>(x, qkv_w, qkv_b, Qh, Kh, Vh);

    meanv_k<<<NB * NH, 256, 0, stream>>>(Vh, meanv);
    rowstat_k<<<dim3(NN / 128, NB * NH), 256, 0, stream>>>(Qh, Kh, Marr);
    topk_k<<<NB * NH, 256, 0, stream>>>(Marr, idx);
    fill_k<<<((int)R + 255) / 256, 256, 0, stream>>>(meanv, ctx);
    attn_sel_k<<<dim3(NTOP / QT, NB * NH * KSPLIT), 256, 0, stream>>>(
        Qh, Kh, Vh, idx, Opart, ml);
    attn_comb_k<<<NB * NH * NTOP / 4, 256, 0, stream>>>(Opart, ml, idx, ctx);

    // ctx -> bf16, then proj (MFMA): attn_out = ctx @ out_w + out_b
    castact_k<<<(int)(R / 4 / 256), 256, 0, stream>>>(ctx, ctxb, (int)(R / 4));
    mfma_gemm<false><<<dim3(4, 32), 256, 0, stream>>>(
        ctxb, NC, owT, out_b, attn_out, (u16*)nullptr, NC, NC, 0, 0, 0);

    // x1 = LN(x + attn_out), also bf16 copy
    ln_k<<<NB * NN, 256, 0, stream>>>(x, attn_out, n1_g, n1_b, x1, x1b);

    // FFN (MFMA): h = gelu(x1b @ W1) -> bf16 ; ffn_out = h @ W2 + b2
    mfma_gemm<false><<<dim3(16, 32), 256, 0, stream>>>(
        x1b, NC, w1T, ffn_b1, (float*)nullptr, hb, DFF, NC, 1, 0, 0);
    mfma_gemm<false><<<dim3(4, 32), 256, 0, stream>>>(
        hb, DFF, w2T, ffn_b2, ffn_out, (u16*)nullptr, NC, DFF, 0, 0, 0);

    // x2 = LN(x1 + ffn_out) -> bf16 only
    ln_k<<<NB * NN, 256, 0, stream>>>(x1, ffn_out, n2_g, n2_b, (float*)nullptr, x2b);

    // circular conv1d(k=3) as 3 accumulating MFMA GEMMs with shifted A-rows
    for (int t = 0; t < 3; t++) {
        mfma_gemm<true><<<dim3(4, 32), 256, 0, stream>>>(
            x2b, NC, cwT + (size_t)t * NC * NC,
            (t == 0 ? conv_b : (const float*)nullptr), convy, (u16*)nullptr, NC,
            NC, 0, (t == 0 ? 0 : 1), t - 1);
    }

    pool_ln_k<<<NB * NPOOL, 256, 0, stream>>>(convy, cn_g, cn_b, (float*)d_out);
}

// Round 8
// 709.895 us; speedup vs baseline: 2.1294x; 1.1374x over previous
//
#include <hip/hip_runtime.h>
#include <math.h>

#define NB 2
#define NN 2048
#define NC 512
#define NH 8
#define DK 64
#define DFF 2048
#define NTOP 512
#define NPOOL 1024
#define KSPLIT 4

typedef unsigned short u16;
typedef __attribute__((ext_vector_type(8))) short frag8;
typedef __attribute__((ext_vector_type(4))) float f32x4;

static __device__ __forceinline__ u16 f2b(float f) {
    union { float f; unsigned int u; } v; v.f = f;
    unsigned int r = (v.u + 0x7fffu + ((v.u >> 16) & 1u)) >> 16;
    return (u16)r;
}

// =============== bf16 MFMA GEMM: C = A @ Bt^T (+bias)(+gelu)(+accum) ===============
template<bool CIRC>
__global__ __launch_bounds__(256) void mfma_gemm(const u16* __restrict__ A, int lda,
    const u16* __restrict__ Bt, const float* __restrict__ bias,
    float* __restrict__ C, u16* __restrict__ Cb, int ldc,
    int K, int act, int accum, int shift)
{
    __shared__ u16 As[128][72];
    __shared__ u16 Bs[128][72];
    int tid = threadIdx.x;
    int n0 = blockIdx.x * 128, m0 = blockIdx.y * 128;
    int wave = tid >> 6, lane = tid & 63;
    int ln = lane & 15, quad = lane >> 4;
    int wm = (wave >> 1) * 64, wn = (wave & 1) * 64;
    f32x4 acc[4][4] = {};
    for (int k0 = 0; k0 < K; k0 += 64) {
        #pragma unroll
        for (int i = 0; i < 4; i++) {
            int t = tid + i * 256;
            int m = t >> 3, kq = t & 7;
            int grow = m0 + m;
            int arow = CIRC ? ((grow & ~(NN - 1)) | ((grow + shift) & (NN - 1))) : grow;
            *(uint4*)&As[m][kq * 8] = *(const uint4*)&A[(size_t)arow * lda + k0 + kq * 8];
            *(uint4*)&Bs[m][kq * 8] = *(const uint4*)&Bt[(size_t)(n0 + m) * K + k0 + kq * 8];
        }
        __syncthreads();
        #pragma unroll
        for (int kk = 0; kk < 2; kk++) {
            frag8 af[4], bf[4];
            #pragma unroll
            for (int i = 0; i < 4; i++) {
                af[i] = *(const frag8*)&As[wm + i * 16 + ln][kk * 32 + quad * 8];
                bf[i] = *(const frag8*)&Bs[wn + i * 16 + ln][kk * 32 + quad * 8];
            }
            #pragma unroll
            for (int i = 0; i < 4; i++)
                #pragma unroll
                for (int j = 0; j < 4; j++)
                    acc[i][j] = __builtin_amdgcn_mfma_f32_16x16x32_bf16(
                        af[i], bf[j], acc[i][j], 0, 0, 0);
        }
        __syncthreads();
    }
    #pragma unroll
    for (int i = 0; i < 4; i++) {
        #pragma unroll
        for (int j = 0; j < 4; j++) {
            int col = n0 + wn + j * 16 + ln;
            float bv = bias ? bias[col] : 0.f;
            #pragma unroll
            for (int r = 0; r < 4; r++) {
                int row = m0 + wm + i * 16 + quad * 4 + r;
                float v = acc[i][j][r] + bv;
                if (act == 1) v = 0.5f * v * (1.0f + erff(v * 0.70710678118654752f));
                if (Cb) {
                    Cb[(size_t)row * ldc + col] = f2b(v);
                } else {
                    size_t co = (size_t)row * ldc + col;
                    if (accum) v += C[co];
                    C[co] = v;
                }
            }
        }
    }
}

// =============== weight cast+transpose: fp32 [R][C] -> bf16 [C][R] ===============
__global__ __launch_bounds__(256) void castw_t(const float* __restrict__ in,
    u16* __restrict__ out, int R, int C)
{
    __shared__ float t[32][33];
    int c0 = blockIdx.x * 32, r0 = blockIdx.y * 32;
    int lx = threadIdx.x & 31, ly = threadIdx.x >> 5;
    #pragma unroll
    for (int i = 0; i < 4; i++)
        t[ly + i * 8][lx] = in[(size_t)(r0 + ly + i * 8) * C + c0 + lx];
    __syncthreads();
    #pragma unroll
    for (int i = 0; i < 4; i++)
        out[(size_t)(c0 + ly + i * 8) * R + r0 + lx] = f2b(t[lx][ly + i * 8]);
}

// =============== conv weight cast: [co][ci][t] fp32 -> [t][co][ci] bf16 ===============
__global__ void castconvw_k(const float* __restrict__ cw, u16* __restrict__ out)
{
    int i = blockIdx.x * 256 + threadIdx.x;
    if (i >= 3 * NC * NC) return;
    int ci = i & (NC - 1), co = (i >> 9) & (NC - 1), t = i >> 18;
    out[i] = f2b(cw[(co * NC + ci) * 3 + t]);
}

// =============== elementwise fp32 -> bf16 ===============
__global__ void castact_k(const float* __restrict__ in, u16* __restrict__ out, int n4)
{
    int i = blockIdx.x * 256 + threadIdx.x;
    if (i >= n4) return;
    float4 v = ((const float4*)in)[i];
    ushort4 o;
    o.x = f2b(v.x); o.y = f2b(v.y); o.z = f2b(v.z); o.w = f2b(v.w);
    ((ushort4*)out)[i] = o;
}

// =============== QKV GEMM fp32 (128x128 tile) with head-major scatter ===============
__global__ __launch_bounds__(256) void gemm_qkv_k(const float* __restrict__ A,
    const float* __restrict__ B, const float* __restrict__ bias,
    float* __restrict__ Qh, float* __restrict__ Kh, float* __restrict__ Vh)
{
    __shared__ float As[16][132];
    __shared__ float Bs[16][132];
    int tid = threadIdx.x;
    int n0 = blockIdx.x * 128, m0 = blockIdx.y * 128;
    int tx = tid & 15, ty = tid >> 4;
    float acc[8][8] = {};
    for (int k0 = 0; k0 < NC; k0 += 16) {
        #pragma unroll
        for (int i = 0; i < 2; i++) {
            int t = tid + i * 256;
            int m = t >> 2, kq = t & 3;
            float4 a4 = *(const float4*)&A[(size_t)(m0 + m) * NC + k0 + kq * 4];
            As[kq * 4 + 0][m] = a4.x; As[kq * 4 + 1][m] = a4.y;
            As[kq * 4 + 2][m] = a4.z; As[kq * 4 + 3][m] = a4.w;
        }
        #pragma unroll
        for (int i = 0; i < 2; i++) {
            int t = tid + i * 256;
            int k = t >> 5, nq = t & 31;
            *(float4*)&Bs[k][nq * 4] = *(const float4*)&B[(size_t)(k0 + k) * 1536 + n0 + nq * 4];
        }
        __syncthreads();
        #pragma unroll
        for (int kk = 0; kk < 16; kk++) {
            float av[8], bv[8];
            *(float4*)&av[0] = *(const float4*)&As[kk][ty * 4];
            *(float4*)&av[4] = *(const float4*)&As[kk][64 + ty * 4];
            *(float4*)&bv[0] = *(const float4*)&Bs[kk][tx * 4];
            *(float4*)&bv[4] = *(const float4*)&Bs[kk][64 + tx * 4];
            #pragma unroll
            for (int i = 0; i < 8; i++)
                #pragma unroll
                for (int j = 0; j < 8; j++) acc[i][j] += av[i] * bv[j];
        }
        __syncthreads();
    }
    int which = n0 >> 9;
    float* outb = which == 0 ? Qh : (which == 1 ? Kh : Vh);
    #pragma unroll
    for (int jq = 0; jq < 2; jq++) {
        int colq = n0 + jq * 64;
        int h = (colq >> 6) & 7;
        float4 b4 = *(const float4*)&bias[colq + tx * 4];
        #pragma unroll
        for (int i = 0; i < 8; i++) {
            int m = m0 + (i >> 2) * 64 + ty * 4 + (i & 3);
            int b = m >> 11, row = m & (NN - 1);
            float4 c4;
            c4.x = acc[i][jq * 4 + 0] + b4.x;
            c4.y = acc[i][jq * 4 + 1] + b4.y;
            c4.z = acc[i][jq * 4 + 2] + b4.z;
            c4.w = acc[i][jq * 4 + 3] + b4.w;
            *(float4*)&outb[((size_t)((b << 3) + h) * NN + row) * DK + tx * 4] = c4;
        }
    }
}

// =============== mean of V over sequence ===============
__global__ void meanv_k(const float* __restrict__ Vh, float* __restrict__ meanv)
{
    int bh = blockIdx.x;
    int tid = threadIdx.x;
    int d = tid & 63, seg = tid >> 6;
    const float* vb = Vh + (size_t)bh * NN * DK;
    float s = 0.f;
    for (int m = seg * 512; m < seg * 512 + 512; m++) s += vb[(size_t)m * DK + d];
    __shared__ float red[256];
    red[tid] = s;
    __syncthreads();
    if (seg == 0)
        meanv[bh * DK + d] = (red[d] + red[64 + d] + red[128 + d] + red[192 + d]) * (1.0f / (float)NN);
}

// =============== rowstat: M = max - mean, outer-product form (fp32-exact) ===============
__global__ __launch_bounds__(256) void rowstat_k(const float* __restrict__ Qh,
    const float* __restrict__ Kh, float* __restrict__ Marr)
{
    int bh = blockIdx.y;
    int m0 = blockIdx.x * 128;
    __shared__ float Qs[64][132];   // [d][m]
    __shared__ float Ks[64][132];   // [d][n]
    int tid = threadIdx.x, tx = tid & 15, ty = tid >> 4;
    const float* qb = Qh + ((size_t)bh * NN + m0) * DK;
    const float* kb = Kh + (size_t)bh * NN * DK;
    #pragma unroll
    for (int i = 0; i < 8; i++) {
        int t = tid + i * 256;
        int m = t >> 4, dq = t & 15;
        float4 q4 = *(const float4*)&qb[(size_t)m * DK + dq * 4];
        Qs[dq * 4 + 0][m] = q4.x; Qs[dq * 4 + 1][m] = q4.y;
        Qs[dq * 4 + 2][m] = q4.z; Qs[dq * 4 + 3][m] = q4.w;
    }
    float rmax[8], rsum[8];
    #pragma unroll
    for (int i = 0; i < 8; i++) { rmax[i] = -INFINITY; rsum[i] = 0.f; }
    for (int nc = 0; nc < NN; nc += 128) {
        __syncthreads();
        #pragma unroll
        for (int i = 0; i < 8; i++) {
            int t = tid + i * 256;
            int n = t >> 4, dq = t & 15;
            float4 k4 = *(const float4*)&kb[(size_t)(nc + n) * DK + dq * 4];
            Ks[dq * 4 + 0][n] = k4.x; Ks[dq * 4 + 1][n] = k4.y;
            Ks[dq * 4 + 2][n] = k4.z; Ks[dq * 4 + 3][n] = k4.w;
        }
        __syncthreads();
        float S[8][8] = {};
        #pragma unroll 8
        for (int d = 0; d < 64; d++) {
            float av[8], bv[8];
            *(float4*)&av[0] = *(const float4*)&Qs[d][ty * 4];
            *(float4*)&av[4] = *(const float4*)&Qs[d][64 + ty * 4];
            *(float4*)&bv[0] = *(const float4*)&Ks[d][tx * 4];
            *(float4*)&bv[4] = *(const float4*)&Ks[d][64 + tx * 4];
            #pragma unroll
            for (int i = 0; i < 8; i++)
                #pragma unroll
                for (int j = 0; j < 8; j++) S[i][j] += av[i] * bv[j];
        }
        #pragma unroll
        for (int i = 0; i < 8; i++)
            #pragma unroll
            for (int j = 0; j < 8; j++) {
                rmax[i] = fmaxf(rmax[i], S[i][j]);
                rsum[i] += S[i][j];
            }
    }
    #pragma unroll
    for (int off = 1; off < 16; off <<= 1)
        #pragma unroll
        for (int i = 0; i < 8; i++) {
            rmax[i] = fmaxf(rmax[i], __shfl_xor(rmax[i], off));
            rsum[i] += __shfl_xor(rsum[i], off);
        }
    if (tx == 0)
        #pragma unroll
        for (int i = 0; i < 8; i++) {
            int m = m0 + (i >> 2) * 64 + ty * 4 + (i & 3);
            Marr[(size_t)bh * NN + m] =
                (rmax[i] - rsum[i] * (1.0f / (float)NN)) * 0.125f;
        }
}

// =============== top-512 per (b,h): sorted compact index list ===============
__global__ __launch_bounds__(256) void topk_k(const float* __restrict__ Marr,
                                              int* __restrict__ idx)
{
    int bh = blockIdx.x;
    const float* Mr = Marr + (size_t)bh * NN;
    int* idxr = idx + (size_t)bh * NTOP;
    __shared__ float s[NN];
    __shared__ int sg[256], se[256];
    int tid = threadIdx.x;
    for (int i = tid; i < NN; i += 256) s[i] = Mr[i];
    __syncthreads();
    for (int k = 2; k <= NN; k <<= 1)
        for (int j = k >> 1; j > 0; j >>= 1) {
            for (int t = tid; t < NN / 2; t += 256) {
                int i = ((t & ~(j - 1)) << 1) | (t & (j - 1));
                int ixj = i | j;
                float a = s[i], bb = s[ixj];
                bool up = ((i & k) == 0);
                if ((a > bb) == up) { s[i] = bb; s[ixj] = a; }
            }
            __syncthreads();
        }
    float thr = s[NN - NTOP];
    int lg = 0, le = 0;
    #pragma unroll
    for (int k = 0; k < 8; k++) {
        float v = Mr[tid * 8 + k];
        lg += (v > thr) ? 1 : 0;
        le += (v == thr) ? 1 : 0;
    }
    sg[tid] = lg; se[tid] = le;
    __syncthreads();
    for (int off = 1; off < 256; off <<= 1) {
        int ag = (tid >= off) ? sg[tid - off] : 0;
        int ae = (tid >= off) ? se[tid - off] : 0;
        __syncthreads();
        sg[tid] += ag; se[tid] += ae;
        __syncthreads();
    }
    int cnt_gt = sg[255];
    int needed = NTOP - cnt_gt;
    int gpre = sg[tid] - lg, epre = se[tid] - le;
    #pragma unroll
    for (int k = 0; k < 8; k++) {
        int p = tid * 8 + k;
        float v = Mr[p];
        bool isgt = v > thr, iseq = v == thr;
        bool selv = isgt || (iseq && epre < needed);
        if (selv) idxr[gpre + (epre < needed ? epre : needed)] = p;
        gpre += isgt ? 1 : 0;
        epre += iseq ? 1 : 0;
    }
}

// =============== fill ctx with uniform-attention result ===============
__global__ void fill_k(const float* __restrict__ meanv, float* __restrict__ ctx)
{
    int i = blockIdx.x * 256 + threadIdx.x;
    if (i >= NB * NN * NC) return;
    int c = i & (NC - 1);
    int m = i >> 9;
    int b = m >> 11;
    int h = c >> 6, d = c & 63;
    ctx[i] = meanv[(((b << 3) + h) << 6) + d];
}

// =============== MFMA flash attention over selected rows, split-K ===============
// grid (NTOP/64, NB*NH*KSPLIT). Block: 64 q-rows x 512 keys; wave owns 16 q-rows.
// Q scaled by 0.125 at load (exact). Emits unnormalized partials + (m,l).
__global__ __launch_bounds__(256) void attn_mfma_k(const float* __restrict__ Qh,
    const float* __restrict__ Kh, const float* __restrict__ Vh,
    const int* __restrict__ idx, float* __restrict__ Opart, float* __restrict__ ml)
{
    int yy = blockIdx.y;
    int bh = yy >> 2, split = yy & (KSPLIT - 1);
    int t0 = blockIdx.x * 64;
    int tid = threadIdx.x;
    int wave = tid >> 6, lane = tid & 63;
    int ln = lane & 15, quad = lane >> 4;
    __shared__ u16 Ks[128][72];     // [key][d]  (B-frag native for QK^T)
    __shared__ u16 Vt[64][136];     // [d][key]  (B-frag native for PV)
    __shared__ u16 Ps[4][16][136];  // per-wave P: [q][key]  (A-frag native)
    __shared__ int rows[64];
    if (tid < 64) rows[tid] = idx[bh * NTOP + t0 + tid];
    __syncthreads();
    // Q fragments direct to registers: A[m=ln][k=quad*8+j], pre-scaled by 1/8
    frag8 qf[2];
    {
        const float* qp = &Qh[((size_t)bh * NN + rows[wave * 16 + ln]) * DK];
        #pragma unroll
        for (int ks = 0; ks < 2; ks++) {
            float4 a = *(const float4*)&qp[ks * 32 + quad * 8];
            float4 b = *(const float4*)&qp[ks * 32 + quad * 8 + 4];
            union { frag8 f; u16 s[8]; } u;
            u.s[0] = f2b(a.x * 0.125f); u.s[1] = f2b(a.y * 0.125f);
            u.s[2] = f2b(a.z * 0.125f); u.s[3] = f2b(a.w * 0.125f);
            u.s[4] = f2b(b.x * 0.125f); u.s[5] = f2b(b.y * 0.125f);
            u.s[6] = f2b(b.z * 0.125f); u.s[7] = f2b(b.w * 0.125f);
            qf[ks] = u.f;
        }
    }
    f32x4 accO[4] = {};                 // O: col d = nt*16+ln, row q = quad*4+r
    float mrun[4] = {-INFINITY, -INFINITY, -INFINITY, -INFINITY};
    float lrun[4] = {};
    const float* kb = Kh + (size_t)bh * NN * DK;
    const float* vb = Vh + (size_t)bh * NN * DK;
    int nc0 = split * (NN / KSPLIT);
    for (int nc = nc0; nc < nc0 + NN / KSPLIT; nc += 128) {
        __syncthreads();
        #pragma unroll
        for (int i = 0; i < 8; i++) {
            int e = tid + i * 256;      // 0..2047
            int n = e >> 4, dq = e & 15;
            float4 k4 = *(const float4*)&kb[(size_t)(nc + n) * DK + dq * 4];
            ushort4 ko;
            ko.x = f2b(k4.x); ko.y = f2b(k4.y); ko.z = f2b(k4.z); ko.w = f2b(k4.w);
            *(ushort4*)&Ks[n][dq * 4] = ko;
            float4 v4 = *(const float4*)&vb[(size_t)(nc + n) * DK + dq * 4];
            Vt[dq * 4 + 0][n] = f2b(v4.x); Vt[dq * 4 + 1][n] = f2b(v4.y);
            Vt[dq * 4 + 2][n] = f2b(v4.z); Vt[dq * 4 + 3][n] = f2b(v4.w);
        }
        __syncthreads();
        // S = Q @ K^T : 8 n-tiles of 16 keys, 2 k-steps of 32 d
        f32x4 accS[8] = {};
        #pragma unroll
        for (int nt = 0; nt < 8; nt++) {
            frag8 b0 = *(const frag8*)&Ks[nt * 16 + ln][quad * 8];
            frag8 b1 = *(const frag8*)&Ks[nt * 16 + ln][32 + quad * 8];
            accS[nt] = __builtin_amdgcn_mfma_f32_16x16x32_bf16(qf[0], b0, accS[nt], 0, 0, 0);
            accS[nt] = __builtin_amdgcn_mfma_f32_16x16x32_bf16(qf[1], b1, accS[nt], 0, 0, 0);
        }
        // online softmax per q-row (row = quad*4+r, cols spread over ln and nt)
        #pragma unroll
        for (int r = 0; r < 4; r++) {
            float m = -INFINITY;
            #pragma unroll
            for (int nt = 0; nt < 8; nt++) m = fmaxf(m, accS[nt][r]);
            #pragma unroll
            for (int off = 1; off < 16; off <<= 1) m = fmaxf(m, __shfl_xor(m, off));
            float mnew = fmaxf(mrun[r], m);
            float alpha = expf(mrun[r] - mnew);
            mrun[r] = mnew;
            float ls = 0.f;
            #pragma unroll
            for (int nt = 0; nt < 8; nt++) {
                float p = expf(accS[nt][r] - mnew);
                accS[nt][r] = p;
                ls += p;
            }
            #pragma unroll
            for (int off = 1; off < 16; off <<= 1) ls += __shfl_xor(ls, off);
            lrun[r] = lrun[r] * alpha + ls;
            #pragma unroll
            for (int nt2 = 0; nt2 < 4; nt2++) accO[nt2][r] *= alpha;
        }
        // write P (wave-private region; C-layout -> A-layout via LDS)
        #pragma unroll
        for (int nt = 0; nt < 8; nt++)
            #pragma unroll
            for (int r = 0; r < 4; r++)
                Ps[wave][quad * 4 + r][nt * 16 + ln] = f2b(accS[nt][r]);
        // O += P @ V : 4 k-steps of 32 keys, 4 n-tiles of 16 d
        #pragma unroll
        for (int ks = 0; ks < 4; ks++) {
            frag8 pf = *(const frag8*)&Ps[wave][ln][ks * 32 + quad * 8];
            #pragma unroll
            for (int nt2 = 0; nt2 < 4; nt2++) {
                frag8 vf = *(const frag8*)&Vt[nt2 * 16 + ln][ks * 32 + quad * 8];
                accO[nt2] = __builtin_amdgcn_mfma_f32_16x16x32_bf16(pf, vf, accO[nt2], 0, 0, 0);
            }
        }
    }
    // emit partials
    #pragma unroll
    for (int r = 0; r < 4; r++) {
        int p = t0 + wave * 16 + quad * 4 + r;
        size_t pb = ((size_t)bh * NTOP + p) * KSPLIT + split;
        #pragma unroll
        for (int nt2 = 0; nt2 < 4; nt2++)
            Opart[pb * 64 + nt2 * 16 + ln] = accO[nt2][r];
        if (ln == 0) { ml[pb * 2] = mrun[r]; ml[pb * 2 + 1] = lrun[r]; }
    }
}

// =============== combine split-K partials -> ctx (one wave per selected row) =========
__global__ __launch_bounds__(256) void attn_comb_k(const float* __restrict__ Opart,
    const float* __restrict__ ml, const int* __restrict__ idx,
    float* __restrict__ ctx)
{
    int gid = blockIdx.x * 4 + (threadIdx.x >> 6);   // bh*NTOP + p
    int lane = threadIdx.x & 63;
    int bh = gid >> 9;
    int h = bh & 7, b = bh >> 3;
    size_t base = (size_t)gid * KSPLIT;
    float M = -INFINITY;
    #pragma unroll
    for (int s = 0; s < KSPLIT; s++) M = fmaxf(M, ml[(base + s) * 2]);
    float L = 0.f, O = 0.f;
    #pragma unroll
    for (int s = 0; s < KSPLIT; s++) {
        float w = expf(ml[(base + s) * 2] - M);
        L += ml[(base + s) * 2 + 1] * w;
        O += Opart[(base + s) * 64 + lane] * w;
    }
    int n = idx[gid];
    ctx[((size_t)(b * NN + n)) * NC + h * DK + lane] = O / L;
}

// =============== layernorm over residual sum; fp32 and/or bf16 out ===============
__global__ __launch_bounds__(256) void ln_k(const float* __restrict__ A,
    const float* __restrict__ Bv, const float* __restrict__ g,
    const float* __restrict__ bb, float* __restrict__ out, u16* __restrict__ outb)
{
    int row = blockIdx.x;
    int tid = threadIdx.x;
    __shared__ float v[NC];
    __shared__ float red[256];
    size_t base = (size_t)row * NC;
    for (int i = tid; i < NC; i += 256) v[i] = A[base + i] + Bv[base + i];
    __syncthreads();
    float ls = 0.f;
    for (int i = tid; i < NC; i += 256) ls += v[i];
    red[tid] = ls; __syncthreads();
    for (int off = 128; off > 0; off >>= 1) {
        if (tid < off) red[tid] += red[tid + off];
        __syncthreads();
    }
    float mu = red[0] / (float)NC;
    __syncthreads();
    float lv = 0.f;
    for (int i = tid; i < NC; i += 256) { float d = v[i] - mu; lv += d * d; }
    red[tid] = lv; __syncthreads();
    for (int off = 128; off > 0; off >>= 1) {
        if (tid < off) red[tid] += red[tid + off];
        __syncthreads();
    }
    float rstd = rsqrtf(red[0] / (float)NC + 1e-5f);
    for (int i = tid; i < NC; i += 256) {
        float r = (v[i] - mu) * rstd * g[i] + bb[i];
        if (out) out[base + i] = r;
        if (outb) outb[base + i] = f2b(r);
    }
}

// =============== maxpool(3,2,1) + ELU + LN -> out ===============
__global__ __launch_bounds__(256) void pool_ln_k(const float* __restrict__ y,
    const float* __restrict__ g, const float* __restrict__ bb,
    float* __restrict__ outp)
{
    int row = blockIdx.x;
    int j = row & (NPOOL - 1), b = row / NPOOL;
    int tid = threadIdx.x;
    __shared__ float v[NC];
    __shared__ float red[256];
    const float* ybase = y + (size_t)b * NN * NC;
    for (int i = tid; i < NC; i += 256) {
        float m = -INFINITY;
        int p0 = 2 * j - 1;
        #pragma unroll
        for (int t = 0; t < 3; t++) {
            int p = p0 + t;
            if (p >= 0 && p < NN) m = fmaxf(m, ybase[(size_t)p * NC + i]);
        }
        v[i] = m > 0.f ? m : expm1f(m);
    }
    __syncthreads();
    float ls = 0.f;
    for (int i = tid; i < NC; i += 256) ls += v[i];
    red[tid] = ls; __syncthreads();
    for (int off = 128; off > 0; off >>= 1) {
        if (tid < off) red[tid] += red[tid + off];
        __syncthreads();
    }
    float mu = red[0] / (float)NC;
    __syncthreads();
    float lv = 0.f;
    for (int i = tid; i < NC; i += 256) { float d = v[i] - mu; lv += d * d; }
    red[tid] = lv; __syncthreads();
    for (int off = 128; off > 0; off >>= 1) {
        if (tid < off) red[tid] += red[tid + off];
        __syncthreads();
    }
    float rstd = rsqrtf(red[0] / (float)NC + 1e-5f);
    for (int i = tid; i < NC; i += 256)
        outp[(size_t)row * NC + i] = (v[i] - mu) * rstd * g[i] + bb[i];
}

extern "C" void kernel_launch(void* const* d_in, const int* in_sizes, int n_in,
                              void* d_out, int out_size, void* d_ws, size_t ws_size,
                              hipStream_t stream)
{
    (void)in_sizes; (void)n_in; (void)out_size; (void)ws_size;
    const float* x      = (const float*)d_in[0];
    const float* qkv_w  = (const float*)d_in[1];
    const float* qkv_b  = (const float*)d_in[2];
    const float* out_w  = (const float*)d_in[3];
    const float* out_b  = (const float*)d_in[4];
    const float* ffn_w1 = (const float*)d_in[5];
    const float* ffn_b1 = (const float*)d_in[6];
    const float* ffn_w2 = (const float*)d_in[7];
    const float* ffn_b2 = (const float*)d_in[8];
    const float* n1_g   = (const float*)d_in[9];
    const float* n1_b   = (const float*)d_in[10];
    const float* n2_g   = (const float*)d_in[11];
    const float* n2_b   = (const float*)d_in[12];
    const float* conv_w = (const float*)d_in[13];
    const float* conv_b = (const float*)d_in[14];
    const float* cn_g   = (const float*)d_in[15];
    const float* cn_b   = (const float*)d_in[16];

    const size_t R = (size_t)NB * NN * NC;     // 2097152
    float* ws = (float*)d_ws;
    float* x1    = ws;                // R : Opart during attention; ln1-out fp32 after
    float* ctx   = ws + R;            // R : attn ctx; later ffn_out
    float* Qh    = ws + 2 * R;        // R : Q; later attn_out, convy
    float* Kh    = ws + 3 * R;        // R : K; later hb lo
    float* Vh    = ws + 4 * R;        // R : V; later hb hi
    size_t o = 5 * R;
    float* Marr  = ws + o;  o += 32768;
    float* meanv = ws + o;  o += 1024;
    int*   idx   = (int*)(ws + o);  o += 8192;
    float* ml    = ws + o;  o += (size_t)NB * NH * NTOP * KSPLIT * 2;  // 65536
    u16*   ctxb  = (u16*)(ws + o);  o += R / 2;
    u16*   x1b   = (u16*)(ws + o);  o += R / 2;
    u16*   x2b   = (u16*)(ws + o);  o += R / 2;
    u16*   owT   = (u16*)(ws + o);  o += 131072;       // [512][512]
    u16*   w1T   = (u16*)(ws + o);  o += 524288;       // [2048][512]
    u16*   w2T   = (u16*)(ws + o);  o += 524288;       // [512][2048]
    u16*   cwT   = (u16*)(ws + o);  o += 393216;       // 3x[512][512]
    float* Opart    = x1;             // R floats, dead before ln1 writes x1
    float* attn_out = Qh;
    u16*   hb       = (u16*)(ws + 3 * R);   // [4096][2048] bf16 (Kh+Vh)
    float* ffn_out  = ctx;
    float* convy    = Qh;

    // weight casts (independent of everything else)
    castw_t<<<dim3(16, 16), 256, 0, stream>>>(out_w, owT, 512, 512);
    castw_t<<<dim3(64, 16), 256, 0, stream>>>(ffn_w1, w1T, 512, 2048);
    castw_t<<<dim3(16, 64), 256, 0, stream>>>(ffn_w2, w2T, 2048, 512);
    castconvw_k<<<3072, 256, 0, stream>>>(conv_w, cwT);

    // qkv = x @ qkv_w + qkv_b -> head-major Q/K/V (fp32, selection-exact)
    gemm_qkv_k<<<dim3(12, 32), 256, 0, stream>>>(x, qkv_w, qkv_b, Qh, Kh, Vh);

    meanv_k<<<NB * NH, 256, 0, stream>>>(Vh, meanv);
    rowstat_k<<<dim3(NN / 128, NB * NH), 256, 0, stream>>>(Qh, Kh, Marr);
    topk_k<<<NB * NH, 256, 0, stream>>>(Marr, idx);
    fill_k<<<((int)R + 255) / 256, 256, 0, stream>>>(meanv, ctx);
    attn_mfma_k<<<dim3(NTOP / 64, NB * NH * KSPLIT), 256, 0, stream>>>(
        Qh, Kh, Vh, idx, Opart, ml);
    attn_comb_k<<<NB * NH * NTOP / 4, 256, 0, stream>>>(Opart, ml, idx, ctx);

    // ctx -> bf16, then proj (MFMA): attn_out = ctx @ out_w + out_b
    castact_k<<<(int)(R / 4 / 256), 256, 0, stream>>>(ctx, ctxb, (int)(R / 4));
    mfma_gemm<false><<<dim3(4, 32), 256, 0, stream>>>(
        ctxb, NC, owT, out_b, attn_out, (u16*)nullptr, NC, NC, 0, 0, 0);

    // x1 = LN(x + attn_out), also bf16 copy
    ln_k<<<NB * NN, 256, 0, stream>>>(x, attn_out, n1_g, n1_b, x1, x1b);

    // FFN (MFMA): h = gelu(x1b @ W1) -> bf16 ; ffn_out = h @ W2 + b2
    mfma_gemm<false><<<dim3(16, 32), 256, 0, stream>>>(
        x1b, NC, w1T, ffn_b1, (float*)nullptr, hb, DFF, NC, 1, 0, 0);
    mfma_gemm<false><<<dim3(4, 32), 256, 0, stream>>>(
        hb, DFF, w2T, ffn_b2, ffn_out, (u16*)nullptr, NC, DFF, 0, 0, 0);

    // x2 = LN(x1 + ffn_out) -> bf16 only
    ln_k<<<NB * NN, 256, 0, stream>>>(x1, ffn_out, n2_g, n2_b, (float*)nullptr, x2b);

    // circular conv1d(k=3) as 3 accumulating MFMA GEMMs with shifted A-rows
    for (int t = 0; t < 3; t++) {
        mfma_gemm<true><<<dim3(4, 32), 256, 0, stream>>>(
            x2b, NC, cwT + (size_t)t * NC * NC,
            (t == 0 ? conv_b : (const float*)nullptr), convy, (u16*)nullptr, NC,
            NC, 0, (t == 0 ? 0 : 1), t - 1);
    }

    pool_ln_k<<<NB * NPOOL, 256, 0, stream>>>(convy, cn_g, cn_b, (float*)d_out);
}

// Round 9
// 694.983 us; speedup vs baseline: 2.1751x; 1.0215x over previous
//
#include <hip/hip_runtime.h>
#include <math.h>

#define NB 2
#define NN 2048
#define NC 512
#define NH 8
#define DK 64
#define DFF 2048
#define NTOP 512
#define NPOOL 1024
#define KSPLIT 4

typedef unsigned short u16;
typedef __attribute__((ext_vector_type(8))) short frag8;
typedef __attribute__((ext_vector_type(4))) float f32x4;

static __device__ __forceinline__ u16 f2b(float f) {
    union { float f; unsigned int u; } v; v.f = f;
    unsigned int r = (v.u + 0x7fffu + ((v.u >> 16) & 1u)) >> 16;
    return (u16)r;
}

// =============== bf16 MFMA GEMM: C = A @ Bt^T (+bias)(+gelu) ===============
// MODE 0: A [4096][lda]. MODE 1 (conv): K=1536, A [4096][512], k-chunk t=k0>>9
// selects circular row shift t-1 within each batch of 2048 rows.
template<int MODE>
__global__ __launch_bounds__(256) void mfma_gemm(const u16* __restrict__ A, int lda,
    const u16* __restrict__ Bt, const float* __restrict__ bias,
    float* __restrict__ C, u16* __restrict__ Cb, int ldc, int K, int act)
{
    __shared__ u16 As[128][72];
    __shared__ u16 Bs[128][72];
    int tid = threadIdx.x;
    int n0 = blockIdx.x * 128, m0 = blockIdx.y * 128;
    int wave = tid >> 6, lane = tid & 63;
    int ln = lane & 15, quad = lane >> 4;
    int wm = (wave >> 1) * 64, wn = (wave & 1) * 64;
    f32x4 acc[4][4] = {};
    for (int k0 = 0; k0 < K; k0 += 64) {
        #pragma unroll
        for (int i = 0; i < 4; i++) {
            int t = tid + i * 256;
            int m = t >> 3, kq = t & 7;
            size_t aoff;
            if (MODE == 1) {
                int grow = m0 + m;
                int shift = (k0 >> 9) - 1;
                int arow = (grow & ~(NN - 1)) | ((grow + shift) & (NN - 1));
                aoff = (size_t)arow * NC + ((k0 & 511) + kq * 8);
            } else {
                aoff = (size_t)(m0 + m) * lda + k0 + kq * 8;
            }
            *(uint4*)&As[m][kq * 8] = *(const uint4*)&A[aoff];
            *(uint4*)&Bs[m][kq * 8] = *(const uint4*)&Bt[(size_t)(n0 + m) * K + k0 + kq * 8];
        }
        __syncthreads();
        #pragma unroll
        for (int kk = 0; kk < 2; kk++) {
            frag8 af[4], bf[4];
            #pragma unroll
            for (int i = 0; i < 4; i++) {
                af[i] = *(const frag8*)&As[wm + i * 16 + ln][kk * 32 + quad * 8];
                bf[i] = *(const frag8*)&Bs[wn + i * 16 + ln][kk * 32 + quad * 8];
            }
            #pragma unroll
            for (int i = 0; i < 4; i++)
                #pragma unroll
                for (int j = 0; j < 4; j++)
                    acc[i][j] = __builtin_amdgcn_mfma_f32_16x16x32_bf16(
                        af[i], bf[j], acc[i][j], 0, 0, 0);
        }
        __syncthreads();
    }
    #pragma unroll
    for (int i = 0; i < 4; i++) {
        #pragma unroll
        for (int j = 0; j < 4; j++) {
            int col = n0 + wn + j * 16 + ln;
            float bv = bias ? bias[col] : 0.f;
            #pragma unroll
            for (int r = 0; r < 4; r++) {
                int row = m0 + wm + i * 16 + quad * 4 + r;
                float v = acc[i][j][r] + bv;
                if (act == 1) v = 0.5f * v * (1.0f + erff(v * 0.70710678118654752f));
                if (Cb) Cb[(size_t)row * ldc + col] = f2b(v);
                else    C[(size_t)row * ldc + col] = v;
            }
        }
    }
}

// =============== V-projection MFMA with head-major scatter: Vh[bh][n][d] fp32 ========
__global__ __launch_bounds__(256) void mfma_v(const u16* __restrict__ A,
    const u16* __restrict__ Bt, const float* __restrict__ bias, float* __restrict__ Vh)
{
    __shared__ u16 As[128][72];
    __shared__ u16 Bs[128][72];
    int tid = threadIdx.x;
    int n0 = blockIdx.x * 128, m0 = blockIdx.y * 128;
    int wave = tid >> 6, lane = tid & 63;
    int ln = lane & 15, quad = lane >> 4;
    int wm = (wave >> 1) * 64, wn = (wave & 1) * 64;
    f32x4 acc[4][4] = {};
    for (int k0 = 0; k0 < NC; k0 += 64) {
        #pragma unroll
        for (int i = 0; i < 4; i++) {
            int t = tid + i * 256;
            int m = t >> 3, kq = t & 7;
            *(uint4*)&As[m][kq * 8] = *(const uint4*)&A[(size_t)(m0 + m) * NC + k0 + kq * 8];
            *(uint4*)&Bs[m][kq * 8] = *(const uint4*)&Bt[(size_t)(n0 + m) * NC + k0 + kq * 8];
        }
        __syncthreads();
        #pragma unroll
        for (int kk = 0; kk < 2; kk++) {
            frag8 af[4], bf[4];
            #pragma unroll
            for (int i = 0; i < 4; i++) {
                af[i] = *(const frag8*)&As[wm + i * 16 + ln][kk * 32 + quad * 8];
                bf[i] = *(const frag8*)&Bs[wn + i * 16 + ln][kk * 32 + quad * 8];
            }
            #pragma unroll
            for (int i = 0; i < 4; i++)
                #pragma unroll
                for (int j = 0; j < 4; j++)
                    acc[i][j] = __builtin_amdgcn_mfma_f32_16x16x32_bf16(
                        af[i], bf[j], acc[i][j], 0, 0, 0);
        }
        __syncthreads();
    }
    #pragma unroll
    for (int i = 0; i < 4; i++) {
        #pragma unroll
        for (int j = 0; j < 4; j++) {
            int col = n0 + wn + j * 16 + ln;
            int h = col >> 6, d = col & 63;
            float bv = bias[col];
            #pragma unroll
            for (int r = 0; r < 4; r++) {
                int row = m0 + wm + i * 16 + quad * 4 + r;
                int b = row >> 11, n = row & (NN - 1);
                Vh[((size_t)((b << 3) + h) * NN + n) * DK + d] = acc[i][j][r] + bv;
            }
        }
    }
}

// =============== weight cast+transpose: fp32 [R][ldi] cols [coff,coff+C) -> bf16 [C][R]
__global__ __launch_bounds__(256) void castw_t(const float* __restrict__ in,
    u16* __restrict__ out, int R, int C, int ldi, int coff)
{
    __shared__ float t[32][33];
    int c0 = blockIdx.x * 32, r0 = blockIdx.y * 32;
    int lx = threadIdx.x & 31, ly = threadIdx.x >> 5;
    #pragma unroll
    for (int i = 0; i < 4; i++)
        t[ly + i * 8][lx] = in[(size_t)(r0 + ly + i * 8) * ldi + coff + c0 + lx];
    __syncthreads();
    #pragma unroll
    for (int i = 0; i < 4; i++)
        out[(size_t)(c0 + ly + i * 8) * R + r0 + lx] = f2b(t[lx][ly + i * 8]);
}

// =============== conv weight cast: [co][ci][t] fp32 -> [co][t*512+ci] bf16 ===========
__global__ void castconvw_k(const float* __restrict__ cw, u16* __restrict__ out)
{
    int i = blockIdx.x * 256 + threadIdx.x;
    if (i >= 3 * NC * NC) return;
    int t = i % 3, ci = (i / 3) & (NC - 1), co = i / (3 * NC);
    out[(size_t)co * 1536 + t * NC + ci] = f2b(cw[i]);
}

// =============== elementwise fp32 -> bf16 ===============
__global__ void castact_k(const float* __restrict__ in, u16* __restrict__ out, int n4)
{
    int i = blockIdx.x * 256 + threadIdx.x;
    if (i >= n4) return;
    float4 v = ((const float4*)in)[i];
    ushort4 o;
    o.x = f2b(v.x); o.y = f2b(v.y); o.z = f2b(v.z); o.w = f2b(v.w);
    ((ushort4*)out)[i] = o;
}

// =============== Q/K GEMM fp32 (128x64 tile, N=1024) with head-major scatter =========
__global__ __launch_bounds__(256) void gemm_qk(const float* __restrict__ A,
    const float* __restrict__ B, const float* __restrict__ bias,
    float* __restrict__ Qh, float* __restrict__ Kh)
{
    __shared__ float As[16][132];
    __shared__ float Bs[16][68];
    int tid = threadIdx.x;
    int n0 = blockIdx.x * 64, m0 = blockIdx.y * 128;
    int tx = tid & 15, ty = tid >> 4;
    float acc[8][4] = {};
    for (int k0 = 0; k0 < NC; k0 += 16) {
        #pragma unroll
        for (int i = 0; i < 2; i++) {
            int t = tid + i * 256;
            int m = t >> 2, kq = t & 3;
            float4 a4 = *(const float4*)&A[(size_t)(m0 + m) * NC + k0 + kq * 4];
            As[kq * 4 + 0][m] = a4.x; As[kq * 4 + 1][m] = a4.y;
            As[kq * 4 + 2][m] = a4.z; As[kq * 4 + 3][m] = a4.w;
        }
        {
            int k = tid >> 4, nq = tid & 15;
            *(float4*)&Bs[k][nq * 4] = *(const float4*)&B[(size_t)(k0 + k) * 1536 + n0 + nq * 4];
        }
        __syncthreads();
        #pragma unroll
        for (int kk = 0; kk < 16; kk++) {
            float av[8], bv[4];
            *(float4*)&av[0] = *(const float4*)&As[kk][ty * 4];
            *(float4*)&av[4] = *(const float4*)&As[kk][64 + ty * 4];
            *(float4*)&bv[0] = *(const float4*)&Bs[kk][tx * 4];
            #pragma unroll
            for (int i = 0; i < 8; i++)
                #pragma unroll
                for (int j = 0; j < 4; j++) acc[i][j] += av[i] * bv[j];
        }
        __syncthreads();
    }
    int which = n0 >> 9, h = (n0 >> 6) & 7;
    float* outb = which ? Kh : Qh;
    float4 b4 = *(const float4*)&bias[n0 + tx * 4];
    #pragma unroll
    for (int i = 0; i < 8; i++) {
        int m = m0 + (i >> 2) * 64 + ty * 4 + (i & 3);
        int b = m >> 11, row = m & (NN - 1);
        float4 c4;
        c4.x = acc[i][0] + b4.x; c4.y = acc[i][1] + b4.y;
        c4.z = acc[i][2] + b4.z; c4.w = acc[i][3] + b4.w;
        *(float4*)&outb[((size_t)((b << 3) + h) * NN + row) * DK + tx * 4] = c4;
    }
}

// =============== mean of V over sequence ===============
__global__ void meanv_k(const float* __restrict__ Vh, float* __restrict__ meanv)
{
    int bh = blockIdx.x;
    int tid = threadIdx.x;
    int d = tid & 63, seg = tid >> 6;
    const float* vb = Vh + (size_t)bh * NN * DK;
    float s = 0.f;
    for (int m = seg * 512; m < seg * 512 + 512; m++) s += vb[(size_t)m * DK + d];
    __shared__ float red[256];
    red[tid] = s;
    __syncthreads();
    if (seg == 0)
        meanv[bh * DK + d] = (red[d] + red[64 + d] + red[128 + d] + red[192 + d]) * (1.0f / (float)NN);
}

// =============== rowstat split-K: partial max/sum over 1024 keys (fp32-exact) ========
__global__ __launch_bounds__(256) void rowstat_k(const float* __restrict__ Qh,
    const float* __restrict__ Kh, float* __restrict__ pmax, float* __restrict__ psum)
{
    int by = blockIdx.y;
    int bh = by >> 1, split = by & 1;
    int m0 = blockIdx.x * 128;
    __shared__ float Qs[64][132];   // [d][m]
    __shared__ float Ks[64][132];   // [d][n]
    int tid = threadIdx.x, tx = tid & 15, ty = tid >> 4;
    const float* qb = Qh + ((size_t)bh * NN + m0) * DK;
    const float* kb = Kh + (size_t)bh * NN * DK;
    #pragma unroll
    for (int i = 0; i < 8; i++) {
        int t = tid + i * 256;
        int m = t >> 4, dq = t & 15;
        float4 q4 = *(const float4*)&qb[(size_t)m * DK + dq * 4];
        Qs[dq * 4 + 0][m] = q4.x; Qs[dq * 4 + 1][m] = q4.y;
        Qs[dq * 4 + 2][m] = q4.z; Qs[dq * 4 + 3][m] = q4.w;
    }
    float rmax[8], rsum[8];
    #pragma unroll
    for (int i = 0; i < 8; i++) { rmax[i] = -INFINITY; rsum[i] = 0.f; }
    int nc0 = split * (NN / 2);
    for (int nc = nc0; nc < nc0 + NN / 2; nc += 128) {
        __syncthreads();
        #pragma unroll
        for (int i = 0; i < 8; i++) {
            int t = tid + i * 256;
            int n = t >> 4, dq = t & 15;
            float4 k4 = *(const float4*)&kb[(size_t)(nc + n) * DK + dq * 4];
            Ks[dq * 4 + 0][n] = k4.x; Ks[dq * 4 + 1][n] = k4.y;
            Ks[dq * 4 + 2][n] = k4.z; Ks[dq * 4 + 3][n] = k4.w;
        }
        __syncthreads();
        float S[8][8] = {};
        #pragma unroll 8
        for (int d = 0; d < 64; d++) {
            float av[8], bv[8];
            *(float4*)&av[0] = *(const float4*)&Qs[d][ty * 4];
            *(float4*)&av[4] = *(const float4*)&Qs[d][64 + ty * 4];
            *(float4*)&bv[0] = *(const float4*)&Ks[d][tx * 4];
            *(float4*)&bv[4] = *(const float4*)&Ks[d][64 + tx * 4];
            #pragma unroll
            for (int i = 0; i < 8; i++)
                #pragma unroll
                for (int j = 0; j < 8; j++) S[i][j] += av[i] * bv[j];
        }
        #pragma unroll
        for (int i = 0; i < 8; i++)
            #pragma unroll
            for (int j = 0; j < 8; j++) {
                rmax[i] = fmaxf(rmax[i], S[i][j]);
                rsum[i] += S[i][j];
            }
    }
    #pragma unroll
    for (int off = 1; off < 16; off <<= 1)
        #pragma unroll
        for (int i = 0; i < 8; i++) {
            rmax[i] = fmaxf(rmax[i], __shfl_xor(rmax[i], off));
            rsum[i] += __shfl_xor(rsum[i], off);
        }
    if (tx == 0)
        #pragma unroll
        for (int i = 0; i < 8; i++) {
            int m = m0 + (i >> 2) * 64 + ty * 4 + (i & 3);
            pmax[(size_t)by * NN + m] = rmax[i];
            psum[(size_t)by * NN + m] = rsum[i];
        }
}

// =============== combine rowstat partials -> Marr ===============
__global__ void rowcomb_k(const float* __restrict__ pmax,
    const float* __restrict__ psum, float* __restrict__ Marr)
{
    int i = blockIdx.x * 256 + threadIdx.x;
    if (i >= NB * NH * NN) return;
    int bh = i >> 11, n = i & (NN - 1);
    float mx = fmaxf(pmax[(size_t)(bh * 2) * NN + n], pmax[(size_t)(bh * 2 + 1) * NN + n]);
    float sm = psum[(size_t)(bh * 2) * NN + n] + psum[(size_t)(bh * 2 + 1) * NN + n];
    Marr[i] = (mx - sm * (1.0f / (float)NN)) * 0.125f;
}

// =============== top-512 per (b,h): sorted compact index list ===============
__global__ __launch_bounds__(256) void topk_k(const float* __restrict__ Marr,
                                              int* __restrict__ idx)
{
    int bh = blockIdx.x;
    const float* Mr = Marr + (size_t)bh * NN;
    int* idxr = idx + (size_t)bh * NTOP;
    __shared__ float s[NN];
    __shared__ int sg[256], se[256];
    int tid = threadIdx.x;
    for (int i = tid; i < NN; i += 256) s[i] = Mr[i];
    __syncthreads();
    for (int k = 2; k <= NN; k <<= 1)
        for (int j = k >> 1; j > 0; j >>= 1) {
            for (int t = tid; t < NN / 2; t += 256) {
                int i = ((t & ~(j - 1)) << 1) | (t & (j - 1));
                int ixj = i | j;
                float a = s[i], bb = s[ixj];
                bool up = ((i & k) == 0);
                if ((a > bb) == up) { s[i] = bb; s[ixj] = a; }
            }
            __syncthreads();
        }
    float thr = s[NN - NTOP];
    int lg = 0, le = 0;
    #pragma unroll
    for (int k = 0; k < 8; k++) {
        float v = Mr[tid * 8 + k];
        lg += (v > thr) ? 1 : 0;
        le += (v == thr) ? 1 : 0;
    }
    sg[tid] = lg; se[tid] = le;
    __syncthreads();
    for (int off = 1; off < 256; off <<= 1) {
        int ag = (tid >= off) ? sg[tid - off] : 0;
        int ae = (tid >= off) ? se[tid - off] : 0;
        __syncthreads();
        sg[tid] += ag; se[tid] += ae;
        __syncthreads();
    }
    int cnt_gt = sg[255];
    int needed = NTOP - cnt_gt;
    int gpre = sg[tid] - lg, epre = se[tid] - le;
    #pragma unroll
    for (int k = 0; k < 8; k++) {
        int p = tid * 8 + k;
        float v = Mr[p];
        bool isgt = v > thr, iseq = v == thr;
        bool selv = isgt || (iseq && epre < needed);
        if (selv) idxr[gpre + (epre < needed ? epre : needed)] = p;
        gpre += isgt ? 1 : 0;
        epre += iseq ? 1 : 0;
    }
}

// =============== fill ctx (bf16) with uniform-attention result ===============
__global__ void fill_k(const float* __restrict__ meanv, u16* __restrict__ ctxb)
{
    int i = blockIdx.x * 256 + threadIdx.x;
    if (i >= NB * NN * NC) return;
    int c = i & (NC - 1);
    int m = i >> 9;
    int b = m >> 11;
    int h = c >> 6, d = c & 63;
    ctxb[i] = f2b(meanv[(((b << 3) + h) << 6) + d]);
}

// =============== MFMA flash attention over selected rows, split-K ===============
__global__ __launch_bounds__(256) void attn_mfma_k(const float* __restrict__ Qh,
    const float* __restrict__ Kh, const float* __restrict__ Vh,
    const int* __restrict__ idx, float* __restrict__ Opart, float* __restrict__ ml)
{
    int yy = blockIdx.y;
    int bh = yy >> 2, split = yy & (KSPLIT - 1);
    int t0 = blockIdx.x * 64;
    int tid = threadIdx.x;
    int wave = tid >> 6, lane = tid & 63;
    int ln = lane & 15, quad = lane >> 4;
    __shared__ u16 Ks[128][72];
    __shared__ u16 Vt[64][136];
    __shared__ u16 Ps[4][16][136];
    __shared__ int rows[64];
    if (tid < 64) rows[tid] = idx[bh * NTOP + t0 + tid];
    __syncthreads();
    frag8 qf[2];
    {
        const float* qp = &Qh[((size_t)bh * NN + rows[wave * 16 + ln]) * DK];
        #pragma unroll
        for (int ks = 0; ks < 2; ks++) {
            float4 a = *(const float4*)&qp[ks * 32 + quad * 8];
            float4 b = *(const float4*)&qp[ks * 32 + quad * 8 + 4];
            union { frag8 f; u16 s[8]; } u;
            u.s[0] = f2b(a.x * 0.125f); u.s[1] = f2b(a.y * 0.125f);
            u.s[2] = f2b(a.z * 0.125f); u.s[3] = f2b(a.w * 0.125f);
            u.s[4] = f2b(b.x * 0.125f); u.s[5] = f2b(b.y * 0.125f);
            u.s[6] = f2b(b.z * 0.125f); u.s[7] = f2b(b.w * 0.125f);
            qf[ks] = u.f;
        }
    }
    f32x4 accO[4] = {};
    float mrun[4] = {-INFINITY, -INFINITY, -INFINITY, -INFINITY};
    float lrun[4] = {};
    const float* kb = Kh + (size_t)bh * NN * DK;
    const float* vb = Vh + (size_t)bh * NN * DK;
    int nc0 = split * (NN / KSPLIT);
    for (int nc = nc0; nc < nc0 + NN / KSPLIT; nc += 128) {
        __syncthreads();
        #pragma unroll
        for (int i = 0; i < 8; i++) {
            int e = tid + i * 256;
            int n = e >> 4, dq = e & 15;
            float4 k4 = *(const float4*)&kb[(size_t)(nc + n) * DK + dq * 4];
            ushort4 ko;
            ko.x = f2b(k4.x); ko.y = f2b(k4.y); ko.z = f2b(k4.z); ko.w = f2b(k4.w);
            *(ushort4*)&Ks[n][dq * 4] = ko;
            float4 v4 = *(const float4*)&vb[(size_t)(nc + n) * DK + dq * 4];
            Vt[dq * 4 + 0][n] = f2b(v4.x); Vt[dq * 4 + 1][n] = f2b(v4.y);
            Vt[dq * 4 + 2][n] = f2b(v4.z); Vt[dq * 4 + 3][n] = f2b(v4.w);
        }
        __syncthreads();
        f32x4 accS[8] = {};
        #pragma unroll
        for (int nt = 0; nt < 8; nt++) {
            frag8 b0 = *(const frag8*)&Ks[nt * 16 + ln][quad * 8];
            frag8 b1 = *(const frag8*)&Ks[nt * 16 + ln][32 + quad * 8];
            accS[nt] = __builtin_amdgcn_mfma_f32_16x16x32_bf16(qf[0], b0, accS[nt], 0, 0, 0);
            accS[nt] = __builtin_amdgcn_mfma_f32_16x16x32_bf16(qf[1], b1, accS[nt], 0, 0, 0);
        }
        #pragma unroll
        for (int r = 0; r < 4; r++) {
            float m = -INFINITY;
            #pragma unroll
            for (int nt = 0; nt < 8; nt++) m = fmaxf(m, accS[nt][r]);
            #pragma unroll
            for (int off = 1; off < 16; off <<= 1) m = fmaxf(m, __shfl_xor(m, off));
            float mnew = fmaxf(mrun[r], m);
            float alpha = expf(mrun[r] - mnew);
            mrun[r] = mnew;
            float ls = 0.f;
            #pragma unroll
            for (int nt = 0; nt < 8; nt++) {
                float p = expf(accS[nt][r] - mnew);
                accS[nt][r] = p;
                ls += p;
            }
            #pragma unroll
            for (int off = 1; off < 16; off <<= 1) ls += __shfl_xor(ls, off);
            lrun[r] = lrun[r] * alpha + ls;
            #pragma unroll
            for (int nt2 = 0; nt2 < 4; nt2++) accO[nt2][r] *= alpha;
        }
        #pragma unroll
        for (int nt = 0; nt < 8; nt++)
            #pragma unroll
            for (int r = 0; r < 4; r++)
                Ps[wave][quad * 4 + r][nt * 16 + ln] = f2b(accS[nt][r]);
        #pragma unroll
        for (int ks = 0; ks < 4; ks++) {
            frag8 pf = *(const frag8*)&Ps[wave][ln][ks * 32 + quad * 8];
            #pragma unroll
            for (int nt2 = 0; nt2 < 4; nt2++) {
                frag8 vf = *(const frag8*)&Vt[nt2 * 16 + ln][ks * 32 + quad * 8];
                accO[nt2] = __builtin_amdgcn_mfma_f32_16x16x32_bf16(pf, vf, accO[nt2], 0, 0, 0);
            }
        }
    }
    #pragma unroll
    for (int r = 0; r < 4; r++) {
        int p = t0 + wave * 16 + quad * 4 + r;
        size_t pb = ((size_t)bh * NTOP + p) * KSPLIT + split;
        #pragma unroll
        for (int nt2 = 0; nt2 < 4; nt2++)
            Opart[pb * 64 + nt2 * 16 + ln] = accO[nt2][r];
        if (ln == 0) { ml[pb * 2] = mrun[r]; ml[pb * 2 + 1] = lrun[r]; }
    }
}

// =============== combine split-K partials -> ctxb (bf16) ===============
__global__ __launch_bounds__(256) void attn_comb_k(const float* __restrict__ Opart,
    const float* __restrict__ ml, const int* __restrict__ idx,
    u16* __restrict__ ctxb)
{
    int gid = blockIdx.x * 4 + (threadIdx.x >> 6);
    int lane = threadIdx.x & 63;
    int bh = gid >> 9;
    int h = bh & 7, b = bh >> 3;
    size_t base = (size_t)gid * KSPLIT;
    float M = -INFINITY;
    #pragma unroll
    for (int s = 0; s < KSPLIT; s++) M = fmaxf(M, ml[(base + s) * 2]);
    float L = 0.f, O = 0.f;
    #pragma unroll
    for (int s = 0; s < KSPLIT; s++) {
        float w = expf(ml[(base + s) * 2] - M);
        L += ml[(base + s) * 2 + 1] * w;
        O += Opart[(base + s) * 64 + lane] * w;
    }
    int n = idx[gid];
    ctxb[((size_t)(b * NN + n)) * NC + h * DK + lane] = f2b(O / L);
}

// =============== layernorm over residual sum; fp32 and/or bf16 out ===============
__global__ __launch_bounds__(256) void ln_k(const float* __restrict__ A,
    const float* __restrict__ Bv, const float* __restrict__ g,
    const float* __restrict__ bb, float* __restrict__ out, u16* __restrict__ outb)
{
    int row = blockIdx.x;
    int tid = threadIdx.x;
    __shared__ float v[NC];
    __shared__ float red[256];
    size_t base = (size_t)row * NC;
    for (int i = tid; i < NC; i += 256) v[i] = A[base + i] + Bv[base + i];
    __syncthreads();
    float ls = 0.f;
    for (int i = tid; i < NC; i += 256) ls += v[i];
    red[tid] = ls; __syncthreads();
    for (int off = 128; off > 0; off >>= 1) {
        if (tid < off) red[tid] += red[tid + off];
        __syncthreads();
    }
    float mu = red[0] / (float)NC;
    __syncthreads();
    float lv = 0.f;
    for (int i = tid; i < NC; i += 256) { float d = v[i] - mu; lv += d * d; }
    red[tid] = lv; __syncthreads();
    for (int off = 128; off > 0; off >>= 1) {
        if (tid < off) red[tid] += red[tid + off];
        __syncthreads();
    }
    float rstd = rsqrtf(red[0] / (float)NC + 1e-5f);
    for (int i = tid; i < NC; i += 256) {
        float r = (v[i] - mu) * rstd * g[i] + bb[i];
        if (out) out[base + i] = r;
        if (outb) outb[base + i] = f2b(r);
    }
}

// =============== maxpool(3,2,1) + ELU + LN -> out ===============
__global__ __launch_bounds__(256) void pool_ln_k(const float* __restrict__ y,
    const float* __restrict__ g, const float* __restrict__ bb,
    float* __restrict__ outp)
{
    int row = blockIdx.x;
    int j = row & (NPOOL - 1), b = row / NPOOL;
    int tid = threadIdx.x;
    __shared__ float v[NC];
    __shared__ float red[256];
    const float* ybase = y + (size_t)b * NN * NC;
    for (int i = tid; i < NC; i += 256) {
        float m = -INFINITY;
        int p0 = 2 * j - 1;
        #pragma unroll
        for (int t = 0; t < 3; t++) {
            int p = p0 + t;
            if (p >= 0 && p < NN) m = fmaxf(m, ybase[(size_t)p * NC + i]);
        }
        v[i] = m > 0.f ? m : expm1f(m);
    }
    __syncthreads();
    float ls = 0.f;
    for (int i = tid; i < NC; i += 256) ls += v[i];
    red[tid] = ls; __syncthreads();
    for (int off = 128; off > 0; off >>= 1) {
        if (tid < off) red[tid] += red[tid + off];
        __syncthreads();
    }
    float mu = red[0] / (float)NC;
    __syncthreads();
    float lv = 0.f;
    for (int i = tid; i < NC; i += 256) { float d = v[i] - mu; lv += d * d; }
    red[tid] = lv; __syncthreads();
    for (int off = 128; off > 0; off >>= 1) {
        if (tid < off) red[tid] += red[tid + off];
        __syncthreads();
    }
    float rstd = rsqrtf(red[0] / (float)NC + 1e-5f);
    for (int i = tid; i < NC; i += 256)
        outp[(size_t)row * NC + i] = (v[i] - mu) * rstd * g[i] + bb[i];
}

extern "C" void kernel_launch(void* const* d_in, const int* in_sizes, int n_in,
                              void* d_out, int out_size, void* d_ws, size_t ws_size,
                              hipStream_t stream)
{
    (void)in_sizes; (void)n_in; (void)out_size; (void)ws_size;
    const float* x      = (const float*)d_in[0];
    const float* qkv_w  = (const float*)d_in[1];
    const float* qkv_b  = (const float*)d_in[2];
    const float* out_w  = (const float*)d_in[3];
    const float* out_b  = (const float*)d_in[4];
    const float* ffn_w1 = (const float*)d_in[5];
    const float* ffn_b1 = (const float*)d_in[6];
    const float* ffn_w2 = (const float*)d_in[7];
    const float* ffn_b2 = (const float*)d_in[8];
    const float* n1_g   = (const float*)d_in[9];
    const float* n1_b   = (const float*)d_in[10];
    const float* n2_g   = (const float*)d_in[11];
    const float* n2_b   = (const float*)d_in[12];
    const float* conv_w = (const float*)d_in[13];
    const float* conv_b = (const float*)d_in[14];
    const float* cn_g   = (const float*)d_in[15];
    const float* cn_b   = (const float*)d_in[16];

    const size_t R = (size_t)NB * NN * NC;     // 2097152
    float* ws = (float*)d_ws;
    float* x1   = ws;                 // R : Opart early, LN1 fp32 out later
    float* reg2 = ws + R;             // R : xb + vwT early; ffn_out later
    float* Qh   = ws + 2 * R;         // R : Q; later attn_out, convy
    float* Kh   = ws + 3 * R;         // R : K; later hb lo
    float* Vh   = ws + 4 * R;         // R : V; later hb hi
    size_t o = 5 * R;
    float* pmax  = ws + o;  o += 65536;
    float* psum  = ws + o;  o += 65536;
    float* Marr  = ws + o;  o += 32768;
    float* meanv = ws + o;  o += 1024;
    int*   idx   = (int*)(ws + o);  o += 8192;
    float* ml    = ws + o;  o += 65536;
    u16*   ctxb  = (u16*)(ws + o);  o += R / 2;
    u16*   x1b   = (u16*)(ws + o);  o += R / 2;
    u16*   x2b   = (u16*)(ws + o);  o += R / 2;
    u16*   owT   = (u16*)(ws + o);  o += 131072;       // [512][512]
    u16*   w1T   = (u16*)(ws + o);  o += 524288;       // [2048][512]
    u16*   w2T   = (u16*)(ws + o);  o += 524288;       // [512][2048]
    u16*   cwT   = (u16*)(ws + o);  o += 393216;       // [512][1536]
    u16*   xb    = (u16*)reg2;                // R u16
    u16*   vwT   = (u16*)(ws + R + R / 2);    // [512][512] u16
    float* Opart    = x1;
    float* attn_out = Qh;
    u16*   hb       = (u16*)(ws + 3 * R);     // [4096][2048] bf16
    float* ffn_out  = reg2;
    float* convy    = Qh;

    // weight / activation casts
    castw_t<<<dim3(16, 16), 256, 0, stream>>>(out_w, owT, 512, 512, 512, 0);
    castw_t<<<dim3(64, 16), 256, 0, stream>>>(ffn_w1, w1T, 512, 2048, 2048, 0);
    castw_t<<<dim3(16, 64), 256, 0, stream>>>(ffn_w2, w2T, 2048, 512, 512, 0);
    castw_t<<<dim3(16, 16), 256, 0, stream>>>(qkv_w, vwT, 512, 512, 1536, 1024);
    castconvw_k<<<3072, 256, 0, stream>>>(conv_w, cwT);
    castact_k<<<(int)(R / 4 / 256), 256, 0, stream>>>(x, xb, (int)(R / 4));

    // Q,K fp32 (selection-exact); V via bf16 MFMA
    gemm_qk<<<dim3(16, 32), 256, 0, stream>>>(x, qkv_w, qkv_b, Qh, Kh);
    mfma_v<<<dim3(4, 32), 256, 0, stream>>>(xb, vwT, qkv_b + 1024, Vh);

    meanv_k<<<NB * NH, 256, 0, stream>>>(Vh, meanv);
    rowstat_k<<<dim3(NN / 128, NB * NH * 2), 256, 0, stream>>>(Qh, Kh, pmax, psum);
    rowcomb_k<<<(NB * NH * NN) / 256, 256, 0, stream>>>(pmax, psum, Marr);
    topk_k<<<NB * NH, 256, 0, stream>>>(Marr, idx);
    fill_k<<<((int)R + 255) / 256, 256, 0, stream>>>(meanv, ctxb);
    attn_mfma_k<<<dim3(NTOP / 64, NB * NH * KSPLIT), 256, 0, stream>>>(
        Qh, Kh, Vh, idx, Opart, ml);
    attn_comb_k<<<NB * NH * NTOP / 4, 256, 0, stream>>>(Opart, ml, idx, ctxb);

    // proj (MFMA): attn_out = ctx @ out_w + out_b
    mfma_gemm<0><<<dim3(4, 32), 256, 0, stream>>>(
        ctxb, NC, owT, out_b, attn_out, (u16*)nullptr, NC, NC, 0);

    // x1 = LN(x + attn_out), also bf16 copy
    ln_k<<<NB * NN, 256, 0, stream>>>(x, attn_out, n1_g, n1_b, x1, x1b);

    // FFN (MFMA)
    mfma_gemm<0><<<dim3(16, 32), 256, 0, stream>>>(
        x1b, NC, w1T, ffn_b1, (float*)nullptr, hb, DFF, NC, 1);
    mfma_gemm<0><<<dim3(4, 32), 256, 0, stream>>>(
        hb, DFF, w2T, ffn_b2, ffn_out, (u16*)nullptr, NC, DFF, 0);

    // x2 = LN(x1 + ffn_out) -> bf16 only
    ln_k<<<NB * NN, 256, 0, stream>>>(x1, ffn_out, n2_g, n2_b, (float*)nullptr, x2b);

    // fused circular conv1d(k=3): single MFMA GEMM over K=1536
    mfma_gemm<1><<<dim3(4, 32), 256, 0, stream>>>(
        x2b, NC, cwT, conv_b, convy, (u16*)nullptr, NC, 1536, 0);

    pool_ln_k<<<NB * NPOOL, 256, 0, stream>>>(convy, cn_g, cn_b, (float*)d_out);
}

// Round 10
// 636.304 us; speedup vs baseline: 2.3757x; 1.0922x over previous
//
#include <hip/hip_runtime.h>
#include <math.h>

#define NB 2
#define NN 2048
#define NC 512
#define NH 8
#define DK 64
#define DFF 2048
#define NTOP 512
#define NPOOL 1024
#define KSPLIT 4

typedef unsigned short u16;
typedef __attribute__((ext_vector_type(8))) short frag8;
typedef __attribute__((ext_vector_type(4))) float f32x4;

static __device__ __forceinline__ u16 f2b(float f) {
    union { float f; unsigned int u; } v; v.f = f;
    unsigned int r = (v.u + 0x7fffu + ((v.u >> 16) & 1u)) >> 16;
    return (u16)r;
}

// =============== bf16 MFMA GEMM: C = A @ Bt^T (+bias)(+gelu) ===============
template<int MODE>
__global__ __launch_bounds__(256) void mfma_gemm(const u16* __restrict__ A, int lda,
    const u16* __restrict__ Bt, const float* __restrict__ bias,
    float* __restrict__ C, u16* __restrict__ Cb, int ldc, int K, int act)
{
    __shared__ u16 As[128][72];
    __shared__ u16 Bs[128][72];
    int tid = threadIdx.x;
    int n0 = blockIdx.x * 128, m0 = blockIdx.y * 128;
    int wave = tid >> 6, lane = tid & 63;
    int ln = lane & 15, quad = lane >> 4;
    int wm = (wave >> 1) * 64, wn = (wave & 1) * 64;
    f32x4 acc[4][4] = {};
    for (int k0 = 0; k0 < K; k0 += 64) {
        #pragma unroll
        for (int i = 0; i < 4; i++) {
            int t = tid + i * 256;
            int m = t >> 3, kq = t & 7;
            size_t aoff;
            if (MODE == 1) {
                int grow = m0 + m;
                int shift = (k0 >> 9) - 1;
                int arow = (grow & ~(NN - 1)) | ((grow + shift) & (NN - 1));
                aoff = (size_t)arow * NC + ((k0 & 511) + kq * 8);
            } else {
                aoff = (size_t)(m0 + m) * lda + k0 + kq * 8;
            }
            *(uint4*)&As[m][kq * 8] = *(const uint4*)&A[aoff];
            *(uint4*)&Bs[m][kq * 8] = *(const uint4*)&Bt[(size_t)(n0 + m) * K + k0 + kq * 8];
        }
        __syncthreads();
        #pragma unroll
        for (int kk = 0; kk < 2; kk++) {
            frag8 af[4], bf[4];
            #pragma unroll
            for (int i = 0; i < 4; i++) {
                af[i] = *(const frag8*)&As[wm + i * 16 + ln][kk * 32 + quad * 8];
                bf[i] = *(const frag8*)&Bs[wn + i * 16 + ln][kk * 32 + quad * 8];
            }
            #pragma unroll
            for (int i = 0; i < 4; i++)
                #pragma unroll
                for (int j = 0; j < 4; j++)
                    acc[i][j] = __builtin_amdgcn_mfma_f32_16x16x32_bf16(
                        af[i], bf[j], acc[i][j], 0, 0, 0);
        }
        __syncthreads();
    }
    #pragma unroll
    for (int i = 0; i < 4; i++) {
        #pragma unroll
        for (int j = 0; j < 4; j++) {
            int col = n0 + wn + j * 16 + ln;
            float bv = bias ? bias[col] : 0.f;
            #pragma unroll
            for (int r = 0; r < 4; r++) {
                int row = m0 + wm + i * 16 + quad * 4 + r;
                float v = acc[i][j][r] + bv;
                if (act == 1) v = 0.5f * v * (1.0f + erff(v * 0.70710678118654752f));
                if (Cb) Cb[(size_t)row * ldc + col] = f2b(v);
                else    C[(size_t)row * ldc + col] = v;
            }
        }
    }
}

// =============== V-projection MFMA with head-major scatter ===============
__global__ __launch_bounds__(256) void mfma_v(const u16* __restrict__ A,
    const u16* __restrict__ Bt, const float* __restrict__ bias, float* __restrict__ Vh)
{
    __shared__ u16 As[128][72];
    __shared__ u16 Bs[128][72];
    int tid = threadIdx.x;
    int n0 = blockIdx.x * 128, m0 = blockIdx.y * 128;
    int wave = tid >> 6, lane = tid & 63;
    int ln = lane & 15, quad = lane >> 4;
    int wm = (wave >> 1) * 64, wn = (wave & 1) * 64;
    f32x4 acc[4][4] = {};
    for (int k0 = 0; k0 < NC; k0 += 64) {
        #pragma unroll
        for (int i = 0; i < 4; i++) {
            int t = tid + i * 256;
            int m = t >> 3, kq = t & 7;
            *(uint4*)&As[m][kq * 8] = *(const uint4*)&A[(size_t)(m0 + m) * NC + k0 + kq * 8];
            *(uint4*)&Bs[m][kq * 8] = *(const uint4*)&Bt[(size_t)(n0 + m) * NC + k0 + kq * 8];
        }
        __syncthreads();
        #pragma unroll
        for (int kk = 0; kk < 2; kk++) {
            frag8 af[4], bf[4];
            #pragma unroll
            for (int i = 0; i < 4; i++) {
                af[i] = *(const frag8*)&As[wm + i * 16 + ln][kk * 32 + quad * 8];
                bf[i] = *(const frag8*)&Bs[wn + i * 16 + ln][kk * 32 + quad * 8];
            }
            #pragma unroll
            for (int i = 0; i < 4; i++)
                #pragma unroll
                for (int j = 0; j < 4; j++)
                    acc[i][j] = __builtin_amdgcn_mfma_f32_16x16x32_bf16(
                        af[i], bf[j], acc[i][j], 0, 0, 0);
        }
        __syncthreads();
    }
    #pragma unroll
    for (int i = 0; i < 4; i++) {
        #pragma unroll
        for (int j = 0; j < 4; j++) {
            int col = n0 + wn + j * 16 + ln;
            int h = col >> 6, d = col & 63;
            float bv = bias[col];
            #pragma unroll
            for (int r = 0; r < 4; r++) {
                int row = m0 + wm + i * 16 + quad * 4 + r;
                int b = row >> 11, n = row & (NN - 1);
                Vh[((size_t)((b << 3) + h) * NN + n) * DK + d] = acc[i][j][r] + bv;
            }
        }
    }
}

// =============== weight cast+transpose ===============
__global__ __launch_bounds__(256) void castw_t(const float* __restrict__ in,
    u16* __restrict__ out, int R, int C, int ldi, int coff)
{
    __shared__ float t[32][33];
    int c0 = blockIdx.x * 32, r0 = blockIdx.y * 32;
    int lx = threadIdx.x & 31, ly = threadIdx.x >> 5;
    #pragma unroll
    for (int i = 0; i < 4; i++)
        t[ly + i * 8][lx] = in[(size_t)(r0 + ly + i * 8) * ldi + coff + c0 + lx];
    __syncthreads();
    #pragma unroll
    for (int i = 0; i < 4; i++)
        out[(size_t)(c0 + ly + i * 8) * R + r0 + lx] = f2b(t[lx][ly + i * 8]);
}

// =============== conv weight cast: [co][ci][t] -> [co][t*512+ci] bf16 ===============
__global__ void castconvw_k(const float* __restrict__ cw, u16* __restrict__ out)
{
    int i = blockIdx.x * 256 + threadIdx.x;
    if (i >= 3 * NC * NC) return;
    int t = i % 3, ci = (i / 3) & (NC - 1), co = i / (3 * NC);
    out[(size_t)co * 1536 + t * NC + ci] = f2b(cw[i]);
}

// =============== elementwise fp32 -> bf16 ===============
__global__ void castact_k(const float* __restrict__ in, u16* __restrict__ out, int n4)
{
    int i = blockIdx.x * 256 + threadIdx.x;
    if (i >= n4) return;
    float4 v = ((const float4*)in)[i];
    ushort4 o;
    o.x = f2b(v.x); o.y = f2b(v.y); o.z = f2b(v.z); o.w = f2b(v.w);
    ((ushort4*)out)[i] = o;
}

// =============== Q/K GEMM fp32: 128x128 tile, 8x8/lane, BK=32, head-major ==========
__global__ __launch_bounds__(256) void gemm_qk(const float* __restrict__ A,
    const float* __restrict__ B, const float* __restrict__ bias,
    float* __restrict__ Qh, float* __restrict__ Kh)
{
    __shared__ float As[32][132];
    __shared__ float Bs[32][132];
    int tid = threadIdx.x;
    int n0 = blockIdx.x * 128, m0 = blockIdx.y * 128;
    int tx = tid & 15, ty = tid >> 4;
    float acc[8][8] = {};
    for (int k0 = 0; k0 < NC; k0 += 32) {
        #pragma unroll
        for (int i = 0; i < 4; i++) {
            int t = tid + i * 256;
            int m = t >> 3, kq = t & 7;
            float4 a4 = *(const float4*)&A[(size_t)(m0 + m) * NC + k0 + kq * 4];
            As[kq * 4 + 0][m] = a4.x; As[kq * 4 + 1][m] = a4.y;
            As[kq * 4 + 2][m] = a4.z; As[kq * 4 + 3][m] = a4.w;
        }
        #pragma unroll
        for (int i = 0; i < 4; i++) {
            int t = tid + i * 256;
            int k = t >> 5, nq = t & 31;
            *(float4*)&Bs[k][nq * 4] = *(const float4*)&B[(size_t)(k0 + k) * 1536 + n0 + nq * 4];
        }
        __syncthreads();
        #pragma unroll 4
        for (int kk = 0; kk < 32; kk++) {
            float av[8], bv[8];
            *(float4*)&av[0] = *(const float4*)&As[kk][ty * 4];
            *(float4*)&av[4] = *(const float4*)&As[kk][64 + ty * 4];
            *(float4*)&bv[0] = *(const float4*)&Bs[kk][tx * 4];
            *(float4*)&bv[4] = *(const float4*)&Bs[kk][64 + tx * 4];
            #pragma unroll
            for (int i = 0; i < 8; i++)
                #pragma unroll
                for (int j = 0; j < 8; j++) acc[i][j] += av[i] * bv[j];
        }
        __syncthreads();
    }
    int which = n0 >> 9;              // Q/K boundary (512) is 128-tile aligned
    float* outb = which ? Kh : Qh;
    #pragma unroll
    for (int jq = 0; jq < 2; jq++) {
        int colq = n0 + jq * 64;
        int h = (colq >> 6) & 7;
        float4 b4 = *(const float4*)&bias[colq + tx * 4];
        #pragma unroll
        for (int i = 0; i < 8; i++) {
            int m = m0 + (i >> 2) * 64 + ty * 4 + (i & 3);
            int b = m >> 11, row = m & (NN - 1);
            float4 c4;
            c4.x = acc[i][jq * 4 + 0] + b4.x;
            c4.y = acc[i][jq * 4 + 1] + b4.y;
            c4.z = acc[i][jq * 4 + 2] + b4.z;
            c4.w = acc[i][jq * 4 + 3] + b4.w;
            *(float4*)&outb[((size_t)((b << 3) + h) * NN + row) * DK + tx * 4] = c4;
        }
    }
}

// =============== K,V -> bf16 (V transposed per bh) ===============
__global__ __launch_bounds__(256) void castkv_k(const float* __restrict__ Kh,
    const float* __restrict__ Vh, u16* __restrict__ Kb, u16* __restrict__ Vtb)
{
    int bh = blockIdx.y;
    int n0 = blockIdx.x * 64;
    __shared__ float vt[64][68];
    int tid = threadIdx.x;
    const float* kin = Kh + ((size_t)bh * NN + n0) * DK;
    u16* kout = Kb + ((size_t)bh * NN + n0) * DK;
    const float* vin = Vh + ((size_t)bh * NN + n0) * DK;
    #pragma unroll
    for (int i = 0; i < 4; i++) {
        int t = tid + i * 256;
        int n = t >> 4, dq = t & 15;
        float4 v = *(const float4*)&kin[(size_t)n * DK + dq * 4];
        ushort4 o;
        o.x = f2b(v.x); o.y = f2b(v.y); o.z = f2b(v.z); o.w = f2b(v.w);
        *(ushort4*)&kout[(size_t)n * DK + dq * 4] = o;
        float4 w = *(const float4*)&vin[(size_t)n * DK + dq * 4];
        vt[dq * 4 + 0][n] = w.x; vt[dq * 4 + 1][n] = w.y;
        vt[dq * 4 + 2][n] = w.z; vt[dq * 4 + 3][n] = w.w;
    }
    __syncthreads();
    #pragma unroll
    for (int i = 0; i < 4; i++) {
        int t = tid + i * 256;
        int d = t >> 4, nq = t & 15;
        float4 v = *(const float4*)&vt[d][nq * 4];
        ushort4 o;
        o.x = f2b(v.x); o.y = f2b(v.y); o.z = f2b(v.z); o.w = f2b(v.w);
        *(ushort4*)&Vtb[((size_t)bh * DK + d) * NN + n0 + nq * 4] = o;
    }
}

// =============== mean of V over sequence ===============
__global__ void meanv_k(const float* __restrict__ Vh, float* __restrict__ meanv)
{
    int bh = blockIdx.x;
    int tid = threadIdx.x;
    int d = tid & 63, seg = tid >> 6;
    const float* vb = Vh + (size_t)bh * NN * DK;
    float s = 0.f;
    for (int m = seg * 512; m < seg * 512 + 512; m++) s += vb[(size_t)m * DK + d];
    __shared__ float red[256];
    red[tid] = s;
    __syncthreads();
    if (seg == 0)
        meanv[bh * DK + d] = (red[d] + red[64 + d] + red[128 + d] + red[192 + d]) * (1.0f / (float)NN);
}

// =============== rowstat split-K (fp32-exact) ===============
__global__ __launch_bounds__(256) void rowstat_k(const float* __restrict__ Qh,
    const float* __restrict__ Kh, float* __restrict__ pmax, float* __restrict__ psum)
{
    int by = blockIdx.y;
    int bh = by >> 1, split = by & 1;
    int m0 = blockIdx.x * 128;
    __shared__ float Qs[64][132];
    __shared__ float Ks[64][132];
    int tid = threadIdx.x, tx = tid & 15, ty = tid >> 4;
    const float* qb = Qh + ((size_t)bh * NN + m0) * DK;
    const float* kb = Kh + (size_t)bh * NN * DK;
    #pragma unroll
    for (int i = 0; i < 8; i++) {
        int t = tid + i * 256;
        int m = t >> 4, dq = t & 15;
        float4 q4 = *(const float4*)&qb[(size_t)m * DK + dq * 4];
        Qs[dq * 4 + 0][m] = q4.x; Qs[dq * 4 + 1][m] = q4.y;
        Qs[dq * 4 + 2][m] = q4.z; Qs[dq * 4 + 3][m] = q4.w;
    }
    float rmax[8], rsum[8];
    #pragma unroll
    for (int i = 0; i < 8; i++) { rmax[i] = -INFINITY; rsum[i] = 0.f; }
    int nc0 = split * (NN / 2);
    for (int nc = nc0; nc < nc0 + NN / 2; nc += 128) {
        __syncthreads();
        #pragma unroll
        for (int i = 0; i < 8; i++) {
            int t = tid + i * 256;
            int n = t >> 4, dq = t & 15;
            float4 k4 = *(const float4*)&kb[(size_t)(nc + n) * DK + dq * 4];
            Ks[dq * 4 + 0][n] = k4.x; Ks[dq * 4 + 1][n] = k4.y;
            Ks[dq * 4 + 2][n] = k4.z; Ks[dq * 4 + 3][n] = k4.w;
        }
        __syncthreads();
        float S[8][8] = {};
        #pragma unroll 8
        for (int d = 0; d < 64; d++) {
            float av[8], bv[8];
            *(float4*)&av[0] = *(const float4*)&Qs[d][ty * 4];
            *(float4*)&av[4] = *(const float4*)&Qs[d][64 + ty * 4];
            *(float4*)&bv[0] = *(const float4*)&Ks[d][tx * 4];
            *(float4*)&bv[4] = *(const float4*)&Ks[d][64 + tx * 4];
            #pragma unroll
            for (int i = 0; i < 8; i++)
                #pragma unroll
                for (int j = 0; j < 8; j++) S[i][j] += av[i] * bv[j];
        }
        #pragma unroll
        for (int i = 0; i < 8; i++)
            #pragma unroll
            for (int j = 0; j < 8; j++) {
                rmax[i] = fmaxf(rmax[i], S[i][j]);
                rsum[i] += S[i][j];
            }
    }
    #pragma unroll
    for (int off = 1; off < 16; off <<= 1)
        #pragma unroll
        for (int i = 0; i < 8; i++) {
            rmax[i] = fmaxf(rmax[i], __shfl_xor(rmax[i], off));
            rsum[i] += __shfl_xor(rsum[i], off);
        }
    if (tx == 0)
        #pragma unroll
        for (int i = 0; i < 8; i++) {
            int m = m0 + (i >> 2) * 64 + ty * 4 + (i & 3);
            pmax[(size_t)by * NN + m] = rmax[i];
            psum[(size_t)by * NN + m] = rsum[i];
        }
}

// =============== combine rowstat partials -> Marr ===============
__global__ void rowcomb_k(const float* __restrict__ pmax,
    const float* __restrict__ psum, float* __restrict__ Marr)
{
    int i = blockIdx.x * 256 + threadIdx.x;
    if (i >= NB * NH * NN) return;
    int bh = i >> 11, n = i & (NN - 1);
    float mx = fmaxf(pmax[(size_t)(bh * 2) * NN + n], pmax[(size_t)(bh * 2 + 1) * NN + n]);
    float sm = psum[(size_t)(bh * 2) * NN + n] + psum[(size_t)(bh * 2 + 1) * NN + n];
    Marr[i] = (mx - sm * (1.0f / (float)NN)) * 0.125f;
}

// =============== top-512 per (b,h): exact radix-select threshold + emission =========
__global__ __launch_bounds__(256) void topk_k(const float* __restrict__ Marr,
                                              int* __restrict__ idx)
{
    int bh = blockIdx.x;
    const float* Mr = Marr + (size_t)bh * NN;
    int* idxr = idx + (size_t)bh * NTOP;
    __shared__ int hist[256];
    __shared__ int suf[256];
    __shared__ int sg[256], se[256];
    __shared__ int bin_sh, rank_sh;
    int tid = threadIdx.x;
    unsigned prefix = 0;
    int rank = NTOP;
    for (int pass = 0; pass < 4; pass++) {
        int shift = 24 - pass * 8;
        unsigned mask_hi = (pass == 0) ? 0u : (0xFFFFFFFFu << (shift + 8));
        hist[tid] = 0;
        __syncthreads();
        for (int i = tid; i < NN; i += 256) {
            union { float f; unsigned u; } v; v.f = Mr[i];
            unsigned k = (v.u & 0x80000000u) ? ~v.u : (v.u | 0x80000000u);
            if ((k & mask_hi) == prefix)
                atomicAdd(&hist[(k >> shift) & 255], 1);
        }
        __syncthreads();
        suf[tid] = hist[tid];
        __syncthreads();
        for (int off = 1; off < 256; off <<= 1) {
            int v2 = (tid + off < 256) ? suf[tid + off] : 0;
            __syncthreads();
            suf[tid] += v2;
            __syncthreads();
        }
        int nxt = (tid < 255) ? suf[tid + 1] : 0;
        if (suf[tid] >= rank && nxt < rank) { bin_sh = tid; rank_sh = rank - nxt; }
        __syncthreads();
        prefix |= ((unsigned)bin_sh << shift);
        rank = rank_sh;
        __syncthreads();
    }
    union { unsigned u; float f; } tv;
    tv.u = (prefix & 0x80000000u) ? (prefix & 0x7FFFFFFFu) : ~prefix;
    float thr = tv.f;
    // emission: > thr all selected; == thr lowest-index-first up to quota
    int lg = 0, le = 0;
    #pragma unroll
    for (int k = 0; k < 8; k++) {
        float v = Mr[tid * 8 + k];
        lg += (v > thr) ? 1 : 0;
        le += (v == thr) ? 1 : 0;
    }
    sg[tid] = lg; se[tid] = le;
    __syncthreads();
    for (int off = 1; off < 256; off <<= 1) {
        int ag = (tid >= off) ? sg[tid - off] : 0;
        int ae = (tid >= off) ? se[tid - off] : 0;
        __syncthreads();
        sg[tid] += ag; se[tid] += ae;
        __syncthreads();
    }
    int cnt_gt = sg[255];
    int needed = NTOP - cnt_gt;
    int gpre = sg[tid] - lg, epre = se[tid] - le;
    #pragma unroll
    for (int k = 0; k < 8; k++) {
        int p = tid * 8 + k;
        float v = Mr[p];
        bool isgt = v > thr, iseq = v == thr;
        bool selv = isgt || (iseq && epre < needed);
        if (selv) idxr[gpre + (epre < needed ? epre : needed)] = p;
        gpre += isgt ? 1 : 0;
        epre += iseq ? 1 : 0;
    }
}

// =============== fill ctx (bf16) with uniform-attention result ===============
__global__ void fill_k(const float* __restrict__ meanv, u16* __restrict__ ctxb)
{
    int i = blockIdx.x * 256 + threadIdx.x;
    if (i >= NB * NN * NC) return;
    int c = i & (NC - 1);
    int m = i >> 9;
    int b = m >> 11;
    int h = c >> 6, d = c & 63;
    ctxb[i] = f2b(meanv[(((b << 3) + h) << 6) + d]);
}

// =============== MFMA flash attention (pre-cast K/V), split-K ===============
__global__ __launch_bounds__(256) void attn_mfma_k(const float* __restrict__ Qh,
    const u16* __restrict__ Kb, const u16* __restrict__ Vtb,
    const int* __restrict__ idx, float* __restrict__ Opart, float* __restrict__ ml)
{
    int yy = blockIdx.y;
    int bh = yy >> 2, split = yy & (KSPLIT - 1);
    int t0 = blockIdx.x * 64;
    int tid = threadIdx.x;
    int wave = tid >> 6, lane = tid & 63;
    int ln = lane & 15, quad = lane >> 4;
    __shared__ u16 Ks[128][72];
    __shared__ u16 Vt[64][136];
    __shared__ u16 Ps[4][16][136];
    __shared__ int rows[64];
    if (tid < 64) rows[tid] = idx[bh * NTOP + t0 + tid];
    __syncthreads();
    frag8 qf[2];
    {
        const float* qp = &Qh[((size_t)bh * NN + rows[wave * 16 + ln]) * DK];
        #pragma unroll
        for (int ks = 0; ks < 2; ks++) {
            float4 a = *(const float4*)&qp[ks * 32 + quad * 8];
            float4 b = *(const float4*)&qp[ks * 32 + quad * 8 + 4];
            union { frag8 f; u16 s[8]; } u;
            u.s[0] = f2b(a.x * 0.125f); u.s[1] = f2b(a.y * 0.125f);
            u.s[2] = f2b(a.z * 0.125f); u.s[3] = f2b(a.w * 0.125f);
            u.s[4] = f2b(b.x * 0.125f); u.s[5] = f2b(b.y * 0.125f);
            u.s[6] = f2b(b.z * 0.125f); u.s[7] = f2b(b.w * 0.125f);
            qf[ks] = u.f;
        }
    }
    f32x4 accO[4] = {};
    float mrun[4] = {-INFINITY, -INFINITY, -INFINITY, -INFINITY};
    float lrun[4] = {};
    const u16* kbB = Kb + (size_t)bh * NN * DK;
    const u16* vtB = Vtb + (size_t)bh * DK * NN;
    int nc0 = split * (NN / KSPLIT);
    for (int nc = nc0; nc < nc0 + NN / KSPLIT; nc += 128) {
        __syncthreads();
        #pragma unroll
        for (int i = 0; i < 4; i++) {
            int e = tid + i * 256;          // 0..1023
            int n = e >> 3, kq = e & 7;
            *(uint4*)&Ks[n][kq * 8] = *(const uint4*)&kbB[(size_t)(nc + n) * DK + kq * 8];
        }
        #pragma unroll
        for (int i = 0; i < 4; i++) {
            int e = tid + i * 256;
            int d = e >> 4, nq = e & 15;
            *(uint4*)&Vt[d][nq * 8] = *(const uint4*)&vtB[(size_t)d * NN + nc + nq * 8];
        }
        __syncthreads();
        f32x4 accS[8] = {};
        #pragma unroll
        for (int nt = 0; nt < 8; nt++) {
            frag8 b0 = *(const frag8*)&Ks[nt * 16 + ln][quad * 8];
            frag8 b1 = *(const frag8*)&Ks[nt * 16 + ln][32 + quad * 8];
            accS[nt] = __builtin_amdgcn_mfma_f32_16x16x32_bf16(qf[0], b0, accS[nt], 0, 0, 0);
            accS[nt] = __builtin_amdgcn_mfma_f32_16x16x32_bf16(qf[1], b1, accS[nt], 0, 0, 0);
        }
        #pragma unroll
        for (int r = 0; r < 4; r++) {
            float m = -INFINITY;
            #pragma unroll
            for (int nt = 0; nt < 8; nt++) m = fmaxf(m, accS[nt][r]);
            #pragma unroll
            for (int off = 1; off < 16; off <<= 1) m = fmaxf(m, __shfl_xor(m, off));
            float mnew = fmaxf(mrun[r], m);
            float alpha = expf(mrun[r] - mnew);
            mrun[r] = mnew;
            float ls = 0.f;
            #pragma unroll
            for (int nt = 0; nt < 8; nt++) {
                float p = expf(accS[nt][r] - mnew);
                accS[nt][r] = p;
                ls += p;
            }
            #pragma unroll
            for (int off = 1; off < 16; off <<= 1) ls += __shfl_xor(ls, off);
            lrun[r] = lrun[r] * alpha + ls;
            #pragma unroll
            for (int nt2 = 0; nt2 < 4; nt2++) accO[nt2][r] *= alpha;
        }
        #pragma unroll
        for (int nt = 0; nt < 8; nt++)
            #pragma unroll
            for (int r = 0; r < 4; r++)
                Ps[wave][quad * 4 + r][nt * 16 + ln] = f2b(accS[nt][r]);
        #pragma unroll
        for (int ks = 0; ks < 4; ks++) {
            frag8 pf = *(const frag8*)&Ps[wave][ln][ks * 32 + quad * 8];
            #pragma unroll
            for (int nt2 = 0; nt2 < 4; nt2++) {
                frag8 vf = *(const frag8*)&Vt[nt2 * 16 + ln][ks * 32 + quad * 8];
                accO[nt2] = __builtin_amdgcn_mfma_f32_16x16x32_bf16(pf, vf, accO[nt2], 0, 0, 0);
            }
        }
    }
    #pragma unroll
    for (int r = 0; r < 4; r++) {
        int p = t0 + wave * 16 + quad * 4 + r;
        size_t pb = ((size_t)bh * NTOP + p) * KSPLIT + split;
        #pragma unroll
        for (int nt2 = 0; nt2 < 4; nt2++)
            Opart[pb * 64 + nt2 * 16 + ln] = accO[nt2][r];
        if (ln == 0) { ml[pb * 2] = mrun[r]; ml[pb * 2 + 1] = lrun[r]; }
    }
}

// =============== combine split-K partials -> ctxb (bf16) ===============
__global__ __launch_bounds__(256) void attn_comb_k(const float* __restrict__ Opart,
    const float* __restrict__ ml, const int* __restrict__ idx,
    u16* __restrict__ ctxb)
{
    int gid = blockIdx.x * 4 + (threadIdx.x >> 6);
    int lane = threadIdx.x & 63;
    int bh = gid >> 9;
    int h = bh & 7, b = bh >> 3;
    size_t base = (size_t)gid * KSPLIT;
    float M = -INFINITY;
    #pragma unroll
    for (int s = 0; s < KSPLIT; s++) M = fmaxf(M, ml[(base + s) * 2]);
    float L = 0.f, O = 0.f;
    #pragma unroll
    for (int s = 0; s < KSPLIT; s++) {
        float w = expf(ml[(base + s) * 2] - M);
        L += ml[(base + s) * 2 + 1] * w;
        O += Opart[(base + s) * 64 + lane] * w;
    }
    int n = idx[gid];
    ctxb[((size_t)(b * NN + n)) * NC + h * DK + lane] = f2b(O / L);
}

// =============== layernorm; fp32 and/or bf16 out ===============
__global__ __launch_bounds__(256) void ln_k(const float* __restrict__ A,
    const float* __restrict__ Bv, const float* __restrict__ g,
    const float* __restrict__ bb, float* __restrict__ out, u16* __restrict__ outb)
{
    int row = blockIdx.x;
    int tid = threadIdx.x;
    __shared__ float v[NC];
    __shared__ float red[256];
    size_t base = (size_t)row * NC;
    for (int i = tid; i < NC; i += 256) v[i] = A[base + i] + Bv[base + i];
    __syncthreads();
    float ls = 0.f;
    for (int i = tid; i < NC; i += 256) ls += v[i];
    red[tid] = ls; __syncthreads();
    for (int off = 128; off > 0; off >>= 1) {
        if (tid < off) red[tid] += red[tid + off];
        __syncthreads();
    }
    float mu = red[0] / (float)NC;
    __syncthreads();
    float lv = 0.f;
    for (int i = tid; i < NC; i += 256) { float d = v[i] - mu; lv += d * d; }
    red[tid] = lv; __syncthreads();
    for (int off = 128; off > 0; off >>= 1) {
        if (tid < off) red[tid] += red[tid + off];
        __syncthreads();
    }
    float rstd = rsqrtf(red[0] / (float)NC + 1e-5f);
    for (int i = tid; i < NC; i += 256) {
        float r = (v[i] - mu) * rstd * g[i] + bb[i];
        if (out) out[base + i] = r;
        if (outb) outb[base + i] = f2b(r);
    }
}

// =============== maxpool(3,2,1) + ELU + LN -> out ===============
__global__ __launch_bounds__(256) void pool_ln_k(const float* __restrict__ y,
    const float* __restrict__ g, const float* __restrict__ bb,
    float* __restrict__ outp)
{
    int row = blockIdx.x;
    int j = row & (NPOOL - 1), b = row / NPOOL;
    int tid = threadIdx.x;
    __shared__ float v[NC];
    __shared__ float red[256];
    const float* ybase = y + (size_t)b * NN * NC;
    for (int i = tid; i < NC; i += 256) {
        float m = -INFINITY;
        int p0 = 2 * j - 1;
        #pragma unroll
        for (int t = 0; t < 3; t++) {
            int p = p0 + t;
            if (p >= 0 && p < NN) m = fmaxf(m, ybase[(size_t)p * NC + i]);
        }
        v[i] = m > 0.f ? m : expm1f(m);
    }
    __syncthreads();
    float ls = 0.f;
    for (int i = tid; i < NC; i += 256) ls += v[i];
    red[tid] = ls; __syncthreads();
    for (int off = 128; off > 0; off >>= 1) {
        if (tid < off) red[tid] += red[tid + off];
        __syncthreads();
    }
    float mu = red[0] / (float)NC;
    __syncthreads();
    float lv = 0.f;
    for (int i = tid; i < NC; i += 256) { float d = v[i] - mu; lv += d * d; }
    red[tid] = lv; __syncthreads();
    for (int off = 128; off > 0; off >>= 1) {
        if (tid < off) red[tid] += red[tid + off];
        __syncthreads();
    }
    float rstd = rsqrtf(red[0] / (float)NC + 1e-5f);
    for (int i = tid; i < NC; i += 256)
        outp[(size_t)row * NC + i] = (v[i] - mu) * rstd * g[i] + bb[i];
}

extern "C" void kernel_launch(void* const* d_in, const int* in_sizes, int n_in,
                              void* d_out, int out_size, void* d_ws, size_t ws_size,
                              hipStream_t stream)
{
    (void)in_sizes; (void)n_in; (void)out_size; (void)ws_size;
    const float* x      = (const float*)d_in[0];
    const float* qkv_w  = (const float*)d_in[1];
    const float* qkv_b  = (const float*)d_in[2];
    const float* out_w  = (const float*)d_in[3];
    const float* out_b  = (const float*)d_in[4];
    const float* ffn_w1 = (const float*)d_in[5];
    const float* ffn_b1 = (const float*)d_in[6];
    const float* ffn_w2 = (const float*)d_in[7];
    const float* ffn_b2 = (const float*)d_in[8];
    const float* n1_g   = (const float*)d_in[9];
    const float* n1_b   = (const float*)d_in[10];
    const float* n2_g   = (const float*)d_in[11];
    const float* n2_b   = (const float*)d_in[12];
    const float* conv_w = (const float*)d_in[13];
    const float* conv_b = (const float*)d_in[14];
    const float* cn_g   = (const float*)d_in[15];
    const float* cn_b   = (const float*)d_in[16];

    const size_t R = (size_t)NB * NN * NC;     // 2097152
    float* ws = (float*)d_ws;
    float* x1   = ws;                 // R : Opart early, LN1 fp32 out later
    float* reg2 = ws + R;             // R : xb+vwT -> Kb+Vtb -> ffn_out
    float* Qh   = ws + 2 * R;         // R : Q; later attn_out, convy
    float* Kh   = ws + 3 * R;         // R : K; later hb lo
    float* Vh   = ws + 4 * R;         // R : V; later hb hi
    size_t o = 5 * R;
    float* pmax  = ws + o;  o += 65536;
    float* psum  = ws + o;  o += 65536;
    float* Marr  = ws + o;  o += 32768;
    float* meanv = ws + o;  o += 1024;
    int*   idx   = (int*)(ws + o);  o += 8192;
    float* ml    = ws + o;  o += 65536;
    u16*   ctxb  = (u16*)(ws + o);  o += R / 2;
    u16*   x1b   = (u16*)(ws + o);  o += R / 2;
    u16*   x2b   = (u16*)(ws + o);  o += R / 2;
    u16*   owT   = (u16*)(ws + o);  o += 131072;
    u16*   w1T   = (u16*)(ws + o);  o += 524288;
    u16*   w2T   = (u16*)(ws + o);  o += 524288;
    u16*   cwT   = (u16*)(ws + o);  o += 393216;
    u16*   xb    = (u16*)reg2;                      // R u16 (dead after mfma_v)
    u16*   vwT   = (u16*)(ws + R + R / 2);          // 256K u16 (dead after mfma_v)
    u16*   Kb    = (u16*)reg2;                      // [16][2048][64] u16
    u16*   Vtb   = (u16*)(ws + R + R / 2);          // [16][64][2048] u16
    float* Opart    = x1;
    float* attn_out = Qh;
    u16*   hb       = (u16*)(ws + 3 * R);
    float* ffn_out  = reg2;
    float* convy    = Qh;

    // weight / activation casts
    castw_t<<<dim3(16, 16), 256, 0, stream>>>(out_w, owT, 512, 512, 512, 0);
    castw_t<<<dim3(64, 16), 256, 0, stream>>>(ffn_w1, w1T, 512, 2048, 2048, 0);
    castw_t<<<dim3(16, 64), 256, 0, stream>>>(ffn_w2, w2T, 2048, 512, 512, 0);
    castw_t<<<dim3(16, 16), 256, 0, stream>>>(qkv_w, vwT, 512, 512, 1536, 1024);
    castconvw_k<<<3072, 256, 0, stream>>>(conv_w, cwT);
    castact_k<<<(int)(R / 4 / 256), 256, 0, stream>>>(x, xb, (int)(R / 4));

    // Q,K fp32 (selection-exact); V via bf16 MFMA
    gemm_qk<<<dim3(8, 32), 256, 0, stream>>>(x, qkv_w, qkv_b, Qh, Kh);
    mfma_v<<<dim3(4, 32), 256, 0, stream>>>(xb, vwT, qkv_b + 1024, Vh);

    // pre-cast K/V for MFMA attention (overwrites xb/vwT region)
    castkv_k<<<dim3(NN / 64, NB * NH), 256, 0, stream>>>(Kh, Vh, Kb, Vtb);

    meanv_k<<<NB * NH, 256, 0, stream>>>(Vh, meanv);
    rowstat_k<<<dim3(NN / 128, NB * NH * 2), 256, 0, stream>>>(Qh, Kh, pmax, psum);
    rowcomb_k<<<(NB * NH * NN) / 256, 256, 0, stream>>>(pmax, psum, Marr);
    topk_k<<<NB * NH, 256, 0, stream>>>(Marr, idx);
    fill_k<<<((int)R + 255) / 256, 256, 0, stream>>>(meanv, ctxb);
    attn_mfma_k<<<dim3(NTOP / 64, NB * NH * KSPLIT), 256, 0, stream>>>(
        Qh, Kb, Vtb, idx, Opart, ml);
    attn_comb_k<<<NB * NH * NTOP / 4, 256, 0, stream>>>(Opart, ml, idx, ctxb);

    // proj (MFMA)
    mfma_gemm<0><<<dim3(4, 32), 256, 0, stream>>>(
        ctxb, NC, owT, out_b, attn_out, (u16*)nullptr, NC, NC, 0);

    // x1 = LN(x + attn_out)
    ln_k<<<NB * NN, 256, 0, stream>>>(x, attn_out, n1_g, n1_b, x1, x1b);

    // FFN (MFMA)
    mfma_gemm<0><<<dim3(16, 32), 256, 0, stream>>>(
        x1b, NC, w1T, ffn_b1, (float*)nullptr, hb, DFF, NC, 1);
    mfma_gemm<0><<<dim3(4, 32), 256, 0, stream>>>(
        hb, DFF, w2T, ffn_b2, ffn_out, (u16*)nullptr, NC, DFF, 0);

    // x2 = LN(x1 + ffn_out) -> bf16
    ln_k<<<NB * NN, 256, 0, stream>>>(x1, ffn_out, n2_g, n2_b, (float*)nullptr, x2b);

    // fused circular conv1d(k=3): one MFMA GEMM, K=1536
    mfma_gemm<1><<<dim3(4, 32), 256, 0, stream>>>(
        x2b, NC, cwT, conv_b, convy, (u16*)nullptr, NC, 1536, 0);

    pool_ln_k<<<NB * NPOOL, 256, 0, stream>>>(convy, cn_g, cn_b, (float*)d_out);
}